// Round 7
// baseline (6400.314 us; speedup 1.0000x reference)
//
#include <hip/hip_runtime.h>
#include <hip/hip_fp16.h>

#define DEVINL __device__ __forceinline__

static constexpr int Bn = 2048;
static constexpr int Sn = 256;
static constexpr long long BSn = (long long)Bn * Sn;  // 524288

typedef _Float16 h2v __attribute__((ext_vector_type(2)));
typedef _Float16 half8 __attribute__((ext_vector_type(8)));
typedef float floatx4 __attribute__((ext_vector_type(4)));

DEVINL float dot2(unsigned int a, unsigned int b, float c) {
#if __has_builtin(__builtin_amdgcn_fdot2)
    return __builtin_amdgcn_fdot2(__builtin_bit_cast(h2v, a), __builtin_bit_cast(h2v, b), c, false);
#else
    __half2 ha = __builtin_bit_cast(__half2, a);
    __half2 hb = __builtin_bit_cast(__half2, b);
    return c + __low2float(ha) * __low2float(hb) + __high2float(ha) * __high2float(hb);
#endif
}
DEVINL unsigned int packh2(float a, float b) {
    __half2 h = __floats2half2_rn(a, b);
    return __builtin_bit_cast(unsigned int, h);
}
DEVINL unsigned short f2h16(float f) { return __builtin_bit_cast(unsigned short, (_Float16)f); }
DEVINL float sigmoidf_(float x) { return 1.0f / (1.0f + __expf(-x)); }
DEVINL float tanhf_(float x) { return 2.0f / (1.0f + __expf(-2.0f * x)) - 1.0f; }

// encoder-weight LDS map (u32 offsets)
enum {
    O_PE1 = 0,        // [64][12]  pe_w1^T pairs (21 pad 24)
    O_PE2 = 768,      // [64][32]  pe_w2^T pairs
    O_EE1 = 2816,     // [32][8]   ee_w1^T pairs (13 pad 16)
    O_EE2 = 3072,     // [16][16]  ee_w2^T pairs
    O_CB1 = 3328,     // [128][32] cb_w1^T pairs (63 pad 64)
    O_CB2 = 7424,     // [64][64]  cb_w2^T pairs
    O_BIAS = 11520,   // 400 floats
    N_K1 = 11968
};

// ================= k1: encoders -> X[BS][128] f16 in workspace =================
__global__ __launch_bounds__(512) void k1_encode(
    const float* __restrict__ self_obs, const float* __restrict__ tm_obs,
    const float* __restrict__ en_obs, const float* __restrict__ cp_obs,
    const int* __restrict__ role_ids,
    const float* __restrict__ pe_w1, const float* __restrict__ pe_b1,
    const float* __restrict__ pe_w2, const float* __restrict__ pe_b2,
    const float* __restrict__ role_emb,
    const float* __restrict__ ee_w1, const float* __restrict__ ee_b1,
    const float* __restrict__ ee_w2, const float* __restrict__ ee_b2,
    const float* __restrict__ cb_w1, const float* __restrict__ cb_b1,
    const float* __restrict__ cb_w2, const float* __restrict__ cb_b2,
    unsigned int* __restrict__ Xg)
{
    __shared__ __align__(16) unsigned int s_tile[N_K1];  // ~48 KB
    const int t = threadIdx.x;
    const int b = blockIdx.x;

    for (int i = t; i < 768; i += 512) {
        int o = i / 12, m = i % 12, k0 = 2 * m, k1 = k0 + 1;
        float a = (k0 < 21) ? pe_w1[k0 * 64 + o] : 0.f;
        float c = (k1 < 21) ? pe_w1[k1 * 64 + o] : 0.f;
        s_tile[O_PE1 + i] = packh2(a, c);
    }
    for (int i = t; i < 2048; i += 512) {
        int o = i >> 5, m = i & 31;
        s_tile[O_PE2 + i] = packh2(pe_w2[(2 * m) * 64 + o], pe_w2[(2 * m + 1) * 64 + o]);
    }
    if (t < 256) {
        int i = t;
        int o = i >> 3, m = i & 7, k0 = 2 * m, k1 = k0 + 1;
        float a = (k0 < 13) ? ee_w1[k0 * 32 + o] : 0.f;
        float c = (k1 < 13) ? ee_w1[k1 * 32 + o] : 0.f;
        s_tile[O_EE1 + i] = packh2(a, c);
    } else {
        int i = t - 256;
        int o = i >> 4, m = i & 15;
        s_tile[O_EE2 + i] = packh2(ee_w2[(2 * m) * 16 + o], ee_w2[(2 * m + 1) * 16 + o]);
    }
    for (int i = t; i < 4096; i += 512) {
        int o = i >> 5, m = i & 31, k0 = 2 * m, k1 = k0 + 1;
        float a = (k0 < 63) ? cb_w1[k0 * 128 + o] : 0.f;
        float c = (k1 < 63) ? cb_w1[k1 * 128 + o] : 0.f;
        s_tile[O_CB1 + i] = packh2(a, c);
    }
    for (int i = t; i < 4096; i += 512) {
        int o = i >> 6, m = i & 63;
        s_tile[O_CB2 + i] = packh2(cb_w2[(2 * m) * 64 + o], cb_w2[(2 * m + 1) * 64 + o]);
    }
    float* bias = (float*)(s_tile + O_BIAS);
    if (t < 64) bias[t] = pe_b1[t];
    if (t < 64) bias[64 + t] = pe_b2[t];
    if (t < 32) bias[128 + t] = ee_b1[t];
    if (t < 16) bias[160 + t] = ee_b2[t];
    if (t < 128) bias[176 + t] = cb_b1[t];
    if (t < 64) bias[304 + t] = cb_b2[t];
    if (t < 32) bias[368 + t] = role_emb[t];
    __syncthreads();

    const int s = t >> 1;
    const int e = t & 1;
    const long long row = (long long)b * Sn + s;

    unsigned int cpp[32];
    if (e == 0) {
        float lat[32];
        #pragma unroll 1
        for (int src = 0; src < 3; src++) {
            const float* xp = (src == 0) ? (tm_obs + row * 13) : (en_obs + row * 26 + (src - 1) * 13);
            unsigned int xpr[8];
            #pragma unroll
            for (int m = 0; m < 8; m++) {
                int k0 = 2 * m, k1 = k0 + 1;
                xpr[m] = packh2((k0 < 13) ? xp[k0] : 0.f, (k1 < 13) ? xp[k1] : 0.f);
            }
            unsigned int e1[16];
            #pragma unroll
            for (int o2 = 0; o2 < 16; o2++) {
                float a0 = bias[128 + 2 * o2], a1 = bias[128 + 2 * o2 + 1];
                const unsigned int* w0 = s_tile + O_EE1 + (2 * o2) * 8;
                #pragma unroll
                for (int m = 0; m < 8; m++) { a0 = dot2(xpr[m], w0[m], a0); a1 = dot2(xpr[m], w0[8 + m], a1); }
                e1[o2] = packh2(fmaxf(a0, 0.f), fmaxf(a1, 0.f));
            }
            #pragma unroll
            for (int o = 0; o < 16; o++) {
                float a0 = bias[160 + o];
                const unsigned int* w0 = s_tile + O_EE2 + o * 16;
                #pragma unroll
                for (int m = 0; m < 16; m++) a0 = dot2(e1[m], w0[m], a0);
                if (src == 0) lat[o] = a0;
                else if (src == 1) lat[16 + o] = a0;
                else lat[16 + o] = fmaxf(lat[16 + o], a0);
            }
        }
        const float* sp = self_obs + row * 15;
        const int rid = role_ids[row];
        const float* rvec = bias + 368 + rid * 16;
        #pragma unroll
        for (int m = 0; m < 32; m++) {
            int k0 = 2 * m, k1 = k0 + 1;
            float a = (k0 < 15) ? sp[k0] : (k0 < 31) ? lat[k0 - 15] : (k0 < 47) ? lat[16 + k0 - 31] : rvec[k0 - 47];
            float c = (k1 < 15) ? sp[k1] : (k1 < 31) ? lat[k1 - 15] : (k1 < 47) ? lat[16 + k1 - 31]
                                                                   : (k1 < 63) ? rvec[k1 - 47] : 0.f;
            cpp[m] = packh2(a, c);
        }
    }
    #pragma unroll
    for (int m = 0; m < 32; m++) {
        unsigned int v = __shfl_xor(cpp[m], 1);
        if (e) cpp[m] = v;
    }
    unsigned int c1h[32];
    #pragma unroll
    for (int o2 = 0; o2 < 32; o2++) {
        const int o2g = e * 32 + o2;
        float a0 = bias[176 + 2 * o2g], a1 = bias[176 + 2 * o2g + 1];
        const unsigned int* w0 = s_tile + O_CB1 + (2 * o2g) * 32;
        #pragma unroll
        for (int m = 0; m < 32; m++) { a0 = dot2(cpp[m], w0[m], a0); a1 = dot2(cpp[m], w0[32 + m], a1); }
        c1h[o2] = packh2(fmaxf(a0, 0.f), fmaxf(a1, 0.f));
    }
    unsigned int c1o[32];
    #pragma unroll
    for (int m = 0; m < 32; m++) c1o[m] = __shfl_xor(c1h[m], 1);
    unsigned int resc[16];
    {
        const int ob = e * 32;
        const int tb = 32 - ob;
        #pragma unroll
        for (int o2 = 0; o2 < 16; o2++) {
            const int o2g = e * 16 + o2;
            float a0 = bias[304 + 2 * o2g], a1 = bias[304 + 2 * o2g + 1];
            const unsigned int* w0 = s_tile + O_CB2 + (2 * o2g) * 64;
            #pragma unroll
            for (int m = 0; m < 32; m++) { a0 = dot2(c1h[m], w0[ob + m], a0); a1 = dot2(c1h[m], w0[64 + ob + m], a1); }
            #pragma unroll
            for (int m = 0; m < 32; m++) { a0 = dot2(c1o[m], w0[tb + m], a0); a1 = dot2(c1o[m], w0[64 + tb + m], a1); }
            resc[o2] = packh2(fmaxf(a0, 0.f), fmaxf(a1, 0.f));
        }
    }
    unsigned int resp[32];
    if (e == 1) {
        unsigned int inp[12];
        {
            const float* sp = self_obs + row * 15;
            const float* cp = cp_obs + row * 6;
            #pragma unroll
            for (int m = 0; m < 12; m++) {
                int k0 = 2 * m, k1 = k0 + 1;
                float a = (k0 < 15) ? sp[k0] : ((k0 < 21) ? cp[k0 - 15] : 0.f);
                float c = (k1 < 15) ? sp[k1] : ((k1 < 21) ? cp[k1 - 15] : 0.f);
                inp[m] = packh2(a, c);
            }
        }
        unsigned int r1p[32];
        #pragma unroll
        for (int o2 = 0; o2 < 32; o2++) {
            float a0 = bias[2 * o2], a1 = bias[2 * o2 + 1];
            const unsigned int* w0 = s_tile + O_PE1 + (2 * o2) * 12;
            #pragma unroll
            for (int m = 0; m < 12; m++) { a0 = dot2(inp[m], w0[m], a0); a1 = dot2(inp[m], w0[12 + m], a1); }
            r1p[o2] = packh2(fmaxf(a0, 0.f), fmaxf(a1, 0.f));
        }
        #pragma unroll
        for (int o2 = 0; o2 < 32; o2++) {
            float a0 = bias[64 + 2 * o2], a1 = bias[64 + 2 * o2 + 1];
            const unsigned int* w0 = s_tile + O_PE2 + (2 * o2) * 32;
            #pragma unroll
            for (int m = 0; m < 32; m++) { a0 = dot2(r1p[m], w0[m], a0); a1 = dot2(r1p[m], w0[32 + m], a1); }
            resp[o2] = packh2(fmaxf(a0, 0.f), fmaxf(a1, 0.f));
        }
    }
    // write X row: [pilot 32 u32 | cmd 32 u32]
    unsigned int* xr = Xg + row * 64;
    uint4* xr4 = reinterpret_cast<uint4*>(xr);
    if (e == 0) {
        #pragma unroll
        for (int q = 0; q < 4; q++)
            xr4[8 + q] = make_uint4(resc[4 * q], resc[4 * q + 1], resc[4 * q + 2], resc[4 * q + 3]);
    } else {
        #pragma unroll
        for (int q = 0; q < 8; q++)
            xr4[q] = make_uint4(resp[4 * q], resp[4 * q + 1], resp[4 * q + 2], resp[4 * q + 3]);
        #pragma unroll
        for (int q = 0; q < 4; q++)
            xr4[12 + q] = make_uint4(resc[4 * q], resc[4 * q + 1], resc[4 * q + 2], resc[4 * q + 3]);
    }
}

// ================= k2: batch-tiled MFMA LSTM (8 rows/block) =================
DEVINL void store_heads(float v0, float v1, float v2, float v3, int lane, int bb, int spos,
                        const float* s_misc, float* __restrict__ out)
{
    const int hc = lane & 15;
    const int rgrp = lane >> 4;
    if (hc >= 6 || rgrp >= 2) return;
    float vv[4] = {v0, v1, v2, v3};
    #pragma unroll
    for (int r = 0; r < 4; r++) {
        long long gr = (long long)bb * 8 + rgrp * 4 + r;
        long long idx = gr * Sn + spos;
        float v = vv[r];
        if (hc == 0)      out[idx] = sigmoidf_(v + s_misc[0]);
        else if (hc == 1) out[BSn + idx] = tanhf_(v + s_misc[1]);
        else if (hc == 2) out[4 * BSn + 2 * idx] = v + s_misc[2];
        else if (hc == 3) out[4 * BSn + 2 * idx + 1] = v + s_misc[3];
        else if (hc == 4) out[6 * BSn + 2 * idx] = v + s_misc[4];
        else              out[6 * BSn + 2 * idx + 1] = v + s_misc[5];
    }
}

__global__ __launch_bounds__(1024) void k2_lstm(
    const float* __restrict__ ih_w, const float* __restrict__ ih_b,
    const float* __restrict__ hh_w, const float* __restrict__ hh_b,
    const float* __restrict__ th_w, const float* __restrict__ th_b,
    const float* __restrict__ an_w, const float* __restrict__ an_b,
    const float* __restrict__ sh_w, const float* __restrict__ sh_b,
    const float* __restrict__ bo_w, const float* __restrict__ bo_b,
    const unsigned int* __restrict__ Xg, float* __restrict__ out)
{
    __shared__ __align__(16) unsigned short s_h[16][72];     // h (rows 8-15 zero)
    __shared__ __align__(16) unsigned short s_x[2][16][136]; // X dbuf (rows 8-15 zero)
    __shared__ float s_misc[8];

    const int t = threadIdx.x;
    const int bb = blockIdx.x;        // rows 8bb..8bb+7
    const int l = t & 63;
    const int w = t >> 6;             // wave 0..15

    // zero LDS
    {
        unsigned int* hz = (unsigned int*)&s_h[0][0];
        for (int i = t; i < 576; i += 1024) hz[i] = 0;
        unsigned int* xz = (unsigned int*)&s_x[0][0][0];
        for (int i = t; i < 2176; i += 1024) xz[i] = 0;
    }
    if (t == 0) {
        s_misc[0] = th_b[0]; s_misc[1] = an_b[0];
        s_misc[2] = sh_b[0]; s_misc[3] = sh_b[1];
        s_misc[4] = bo_b[0]; s_misc[5] = bo_b[1];
    }
    // weight fragments: wave w owns cols 16w..16w+15 (gate-interleaved: col = 4u+gt)
    const int col = w * 16 + (l & 15);
    const int origc = (col & 3) * 64 + (col >> 2);
    const int kof = (l >> 4) * 8;
    half8 bx[4], bh[2];
    #pragma unroll
    for (int kt = 0; kt < 4; kt++) {
        half8 v;
        #pragma unroll
        for (int j = 0; j < 8; j++) v[j] = (_Float16)ih_w[(kt * 32 + kof + j) * 256 + origc];
        bx[kt] = v;
    }
    #pragma unroll
    for (int kt = 0; kt < 2; kt++) {
        half8 v;
        #pragma unroll
        for (int j = 0; j < 8; j++) v[j] = (_Float16)hh_w[(kt * 32 + kof + j) * 256 + origc];
        bh[kt] = v;
    }
    const float bias_c = ih_b[origc] + hh_b[origc];
    half8 bhd[2];
    if (w == 15) {
        const int hc = l & 15;
        #pragma unroll
        for (int kt = 0; kt < 2; kt++) {
            half8 v;
            #pragma unroll
            for (int j = 0; j < 8; j++) {
                int k = kt * 32 + kof + j;
                float wv = 0.f;
                if (hc == 0) wv = th_w[k];
                else if (hc == 1) wv = an_w[k];
                else if (hc == 2) wv = sh_w[2 * k];
                else if (hc == 3) wv = sh_w[2 * k + 1];
                else if (hc == 4) wv = bo_w[2 * k];
                else if (hc == 5) wv = bo_w[2 * k + 1];
                v[j] = (_Float16)wv;
            }
            bhd[kt] = v;
        }
    }
    __syncthreads();  // zeros done
    // stage X_0
    const long long xrow0 = (long long)bb * 8 * Sn;
    if (t < 256) {
        int r = t >> 5, seg = t & 31;
        const unsigned int* src = Xg + (xrow0 + (long long)r * Sn + 0) * 64 + seg * 2;
        unsigned int v0 = src[0], v1 = src[1];
        unsigned int* dst = (unsigned int*)&s_x[0][r][seg * 4];
        dst[0] = v0; dst[1] = v1;
    }
    __syncthreads();

    float cs[4] = {0.f, 0.f, 0.f, 0.f};
    float hv[4] = {0.f, 0.f, 0.f, 0.f};
    const int gt = l & 3;
    const int arow = l & 15;
    int cur = 0;

    #pragma unroll 1
    for (int s = 0; s < Sn; s++) {
        // prefetch X_{s+1}
        unsigned int p0 = 0, p1 = 0;
        const bool pf = (t < 256) && (s + 1 < Sn);
        if (pf) {
            int r = t >> 5, seg = t & 31;
            const unsigned int* src = Xg + (xrow0 + (long long)r * Sn + (s + 1)) * 64 + seg * 2;
            p0 = src[0]; p1 = src[1];
        }
        // A-fragments
        half8 xa[4], ha[2];
        #pragma unroll
        for (int kt = 0; kt < 4; kt++) xa[kt] = *(const half8*)&s_x[cur][arow][kt * 32 + kof];
        #pragma unroll
        for (int kt = 0; kt < 2; kt++) ha[kt] = *(const half8*)&s_h[arow][kt * 32 + kof];
        // gates = X@Wih + h@Whh + b
        floatx4 acc = {bias_c, bias_c, bias_c, bias_c};
        #pragma unroll
        for (int kt = 0; kt < 4; kt++) acc = __builtin_amdgcn_mfma_f32_16x16x32_f16(xa[kt], bx[kt], acc, 0, 0, 0);
        #pragma unroll
        for (int kt = 0; kt < 2; kt++) acc = __builtin_amdgcn_mfma_f32_16x16x32_f16(ha[kt], bh[kt], acc, 0, 0, 0);
        // heads for step s-1 on wave 15 (h_lds currently = h_{s-1})
        if (w == 15) {
            floatx4 hacc = {0.f, 0.f, 0.f, 0.f};
            hacc = __builtin_amdgcn_mfma_f32_16x16x32_f16(ha[0], bhd[0], hacc, 0, 0, 0);
            hacc = __builtin_amdgcn_mfma_f32_16x16x32_f16(ha[1], bhd[1], hacc, 0, 0, 0);
            if (s >= 1) store_heads(hacc[0], hacc[1], hacc[2], hacc[3], l, bb, s - 1, s_misc, out);
        }
        // cell update (quad: lanes gt=0..3 hold i,f,g,o of one (unit, row-group))
        float av[4], x1[4], x2[4], x3[4];
        #pragma unroll
        for (int r = 0; r < 4; r++) av[r] = (gt == 2) ? tanhf_(acc[r]) : sigmoidf_(acc[r]);
        #pragma unroll
        for (int r = 0; r < 4; r++) {
            x1[r] = __shfl_xor(av[r], 1);
            x2[r] = __shfl_xor(av[r], 2);
            x3[r] = __shfl_xor(x1[r], 2);
        }
        #pragma unroll
        for (int r = 0; r < 4; r++) {
            cs[r] = x1[r] * cs[r] + av[r] * x2[r];   // valid on gt==0 lanes
            hv[r] = x3[r] * tanhf_(cs[r]);
        }
        __syncthreads();  // all reads of s_h / s_x[cur] complete
        // write new h (gt==0 lanes, rows 0..7)
        if (gt == 0 && (l >> 4) < 2) {
            const int uu = w * 4 + ((l & 15) >> 2);
            #pragma unroll
            for (int r = 0; r < 4; r++) s_h[(l >> 4) * 4 + r][uu] = f2h16(hv[r]);
        }
        // write prefetched X
        if (pf) {
            int r = t >> 5, seg = t & 31;
            unsigned int* dst = (unsigned int*)&s_x[cur ^ 1][r][seg * 4];
            dst[0] = p0; dst[1] = p1;
        }
        __syncthreads();
        cur ^= 1;
    }
    // final heads (s = 255; h_lds = h_255)
    if (w == 15) {
        half8 ha0 = *(const half8*)&s_h[arow][kof];
        half8 ha1 = *(const half8*)&s_h[arow][32 + kof];
        floatx4 hacc = {0.f, 0.f, 0.f, 0.f};
        hacc = __builtin_amdgcn_mfma_f32_16x16x32_f16(ha0, bhd[0], hacc, 0, 0, 0);
        hacc = __builtin_amdgcn_mfma_f32_16x16x32_f16(ha1, bhd[1], hacc, 0, 0, 0);
        store_heads(hacc[0], hacc[1], hacc[2], hacc[3], l, bb, Sn - 1, s_misc, out);
    }
    // hn / cn
    if (gt == 0 && (l >> 4) < 2) {
        float* hn = out + 8 * BSn;
        float* cn = hn + (long long)Bn * 64;
        const int uu = w * 4 + ((l & 15) >> 2);
        #pragma unroll
        for (int r = 0; r < 4; r++) {
            long long gr = (long long)bb * 8 + (l >> 4) * 4 + r;
            hn[gr * 64 + uu] = hv[r];
            cn[gr * 64 + uu] = cs[r];
        }
    }
}

// ================= k3: std fill =================
__global__ __launch_bounds__(256) void k3_std(const float* __restrict__ logstd, float* __restrict__ out)
{
    float s0 = fmaxf(__expf(logstd[0]), 0.05f);
    float s1 = fmaxf(__expf(logstd[1]), 0.05f);
    long long i = (long long)blockIdx.x * 256 + threadIdx.x;
    float2 v = make_float2(s0, s1);
    reinterpret_cast<float2*>(out + 2 * BSn)[i] = v;
}

// ================= fallback: monolithic (R4 structure, default regalloc) =================
enum { F_BIAS = 11520 };
__global__ __launch_bounds__(512)
void k_fallback(
    const float* __restrict__ self_obs, const float* __restrict__ tm_obs,
    const float* __restrict__ en_obs, const float* __restrict__ cp_obs,
    const int* __restrict__ role_ids,
    const float* __restrict__ pe_w1, const float* __restrict__ pe_b1,
    const float* __restrict__ pe_w2, const float* __restrict__ pe_b2,
    const float* __restrict__ role_emb,
    const float* __restrict__ ee_w1, const float* __restrict__ ee_b1,
    const float* __restrict__ ee_w2, const float* __restrict__ ee_b2,
    const float* __restrict__ cb_w1, const float* __restrict__ cb_b1,
    const float* __restrict__ cb_w2, const float* __restrict__ cb_b2,
    const float* __restrict__ ih_w, const float* __restrict__ ih_b,
    const float* __restrict__ hh_w, const float* __restrict__ hh_b,
    const float* __restrict__ th_w, const float* __restrict__ th_b,
    const float* __restrict__ an_w, const float* __restrict__ an_b,
    const float* __restrict__ sh_w, const float* __restrict__ sh_b,
    const float* __restrict__ bo_w, const float* __restrict__ bo_b,
    const float* __restrict__ logstd, float* __restrict__ out)
{
    __shared__ __align__(16) unsigned int s_tile[Sn * 64];
    __shared__ __align__(16) unsigned int s_h32[32];
    __shared__ float s_g[192];
    __shared__ unsigned int s_hw[192];
    __shared__ float s_hb[8];

    const int t = threadIdx.x;
    const int b = blockIdx.x;

    for (int i = t; i < 768; i += 512) {
        int o = i / 12, m = i % 12, k0 = 2 * m, k1 = k0 + 1;
        float a = (k0 < 21) ? pe_w1[k0 * 64 + o] : 0.f;
        float c = (k1 < 21) ? pe_w1[k1 * 64 + o] : 0.f;
        s_tile[O_PE1 + i] = packh2(a, c);
    }
    for (int i = t; i < 2048; i += 512) {
        int o = i >> 5, m = i & 31;
        s_tile[O_PE2 + i] = packh2(pe_w2[(2 * m) * 64 + o], pe_w2[(2 * m + 1) * 64 + o]);
    }
    if (t < 256) {
        int i = t;
        int o = i >> 3, m = i & 7, k0 = 2 * m, k1 = k0 + 1;
        float a = (k0 < 13) ? ee_w1[k0 * 32 + o] : 0.f;
        float c = (k1 < 13) ? ee_w1[k1 * 32 + o] : 0.f;
        s_tile[O_EE1 + i] = packh2(a, c);
    } else {
        int i = t - 256;
        int o = i >> 4, m = i & 15;
        s_tile[O_EE2 + i] = packh2(ee_w2[(2 * m) * 16 + o], ee_w2[(2 * m + 1) * 16 + o]);
    }
    for (int i = t; i < 4096; i += 512) {
        int o = i >> 5, m = i & 31, k0 = 2 * m, k1 = k0 + 1;
        float a = (k0 < 63) ? cb_w1[k0 * 128 + o] : 0.f;
        float c = (k1 < 63) ? cb_w1[k1 * 128 + o] : 0.f;
        s_tile[O_CB1 + i] = packh2(a, c);
    }
    for (int i = t; i < 4096; i += 512) {
        int o = i >> 6, m = i & 63;
        s_tile[O_CB2 + i] = packh2(cb_w2[(2 * m) * 64 + o], cb_w2[(2 * m + 1) * 64 + o]);
    }
    float* bias = (float*)(s_tile + F_BIAS);
    if (t < 64) bias[t] = pe_b1[t];
    if (t < 64) bias[64 + t] = pe_b2[t];
    if (t < 32) bias[128 + t] = ee_b1[t];
    if (t < 16) bias[160 + t] = ee_b2[t];
    if (t < 128) bias[176 + t] = cb_b1[t];
    if (t < 64) bias[304 + t] = cb_b2[t];
    if (t < 32) bias[368 + t] = role_emb[t];
    if (t < 32)        s_hw[t]        = packh2(th_w[2 * t], th_w[2 * t + 1]);
    else if (t < 64)  { int m = t - 32;  s_hw[32 + m]  = packh2(an_w[2 * m], an_w[2 * m + 1]); }
    else if (t < 96)  { int m = t - 64;  s_hw[64 + m]  = packh2(sh_w[4 * m], sh_w[4 * m + 2]); }
    else if (t < 128) { int m = t - 96;  s_hw[96 + m]  = packh2(sh_w[4 * m + 1], sh_w[4 * m + 3]); }
    else if (t < 160) { int m = t - 128; s_hw[128 + m] = packh2(bo_w[4 * m], bo_w[4 * m + 2]); }
    else if (t < 192) { int m = t - 160; s_hw[160 + m] = packh2(bo_w[4 * m + 1], bo_w[4 * m + 3]); }
    if (t == 0) {
        s_hb[0] = th_b[0]; s_hb[1] = an_b[0];
        s_hb[2] = sh_b[0]; s_hb[3] = sh_b[1];
        s_hb[4] = bo_b[0]; s_hb[5] = bo_b[1];
        s_hb[6] = fmaxf(__expf(logstd[0]), 0.05f);
        s_hb[7] = fmaxf(__expf(logstd[1]), 0.05f);
    }
    if (t < 32) s_h32[t] = 0u;
    __syncthreads();

    {
        const int s = t >> 1;
        const int e = t & 1;
        const long long row = (long long)b * Sn + s;
        unsigned int cpp[32];
        if (e == 0) {
            float lat[32];
            #pragma unroll 1
            for (int src = 0; src < 3; src++) {
                const float* xp = (src == 0) ? (tm_obs + row * 13) : (en_obs + row * 26 + (src - 1) * 13);
                unsigned int xpr[8];
                #pragma unroll
                for (int m = 0; m < 8; m++) {
                    int k0 = 2 * m, k1 = k0 + 1;
                    xpr[m] = packh2((k0 < 13) ? xp[k0] : 0.f, (k1 < 13) ? xp[k1] : 0.f);
                }
                unsigned int e1[16];
                #pragma unroll
                for (int o2 = 0; o2 < 16; o2++) {
                    float a0 = bias[128 + 2 * o2], a1 = bias[128 + 2 * o2 + 1];
                    const unsigned int* w0 = s_tile + O_EE1 + (2 * o2) * 8;
                    #pragma unroll
                    for (int m = 0; m < 8; m++) { a0 = dot2(xpr[m], w0[m], a0); a1 = dot2(xpr[m], w0[8 + m], a1); }
                    e1[o2] = packh2(fmaxf(a0, 0.f), fmaxf(a1, 0.f));
                }
                #pragma unroll
                for (int o = 0; o < 16; o++) {
                    float a0 = bias[160 + o];
                    const unsigned int* w0 = s_tile + O_EE2 + o * 16;
                    #pragma unroll
                    for (int m = 0; m < 16; m++) a0 = dot2(e1[m], w0[m], a0);
                    if (src == 0) lat[o] = a0;
                    else if (src == 1) lat[16 + o] = a0;
                    else lat[16 + o] = fmaxf(lat[16 + o], a0);
                }
            }
            const float* sp = self_obs + row * 15;
            const int rid = role_ids[row];
            const float* rvec = bias + 368 + rid * 16;
            #pragma unroll
            for (int m = 0; m < 32; m++) {
                int k0 = 2 * m, k1 = k0 + 1;
                float a = (k0 < 15) ? sp[k0] : (k0 < 31) ? lat[k0 - 15] : (k0 < 47) ? lat[16 + k0 - 31] : rvec[k0 - 47];
                float c = (k1 < 15) ? sp[k1] : (k1 < 31) ? lat[k1 - 15] : (k1 < 47) ? lat[16 + k1 - 31]
                                                                       : (k1 < 63) ? rvec[k1 - 47] : 0.f;
                cpp[m] = packh2(a, c);
            }
        }
        #pragma unroll
        for (int m = 0; m < 32; m++) {
            unsigned int v = __shfl_xor(cpp[m], 1);
            if (e) cpp[m] = v;
        }
        unsigned int c1h[32];
        #pragma unroll
        for (int o2 = 0; o2 < 32; o2++) {
            const int o2g = e * 32 + o2;
            float a0 = bias[176 + 2 * o2g], a1 = bias[176 + 2 * o2g + 1];
            const unsigned int* w0 = s_tile + O_CB1 + (2 * o2g) * 32;
            #pragma unroll
            for (int m = 0; m < 32; m++) { a0 = dot2(cpp[m], w0[m], a0); a1 = dot2(cpp[m], w0[32 + m], a1); }
            c1h[o2] = packh2(fmaxf(a0, 0.f), fmaxf(a1, 0.f));
        }
        unsigned int c1o[32];
        #pragma unroll
        for (int m = 0; m < 32; m++) c1o[m] = __shfl_xor(c1h[m], 1);
        unsigned int resc[16];
        {
            const int ob = e * 32;
            const int tb = 32 - ob;
            #pragma unroll
            for (int o2 = 0; o2 < 16; o2++) {
                const int o2g = e * 16 + o2;
                float a0 = bias[304 + 2 * o2g], a1 = bias[304 + 2 * o2g + 1];
                const unsigned int* w0 = s_tile + O_CB2 + (2 * o2g) * 64;
                #pragma unroll
                for (int m = 0; m < 32; m++) { a0 = dot2(c1h[m], w0[ob + m], a0); a1 = dot2(c1h[m], w0[64 + ob + m], a1); }
                #pragma unroll
                for (int m = 0; m < 32; m++) { a0 = dot2(c1o[m], w0[tb + m], a0); a1 = dot2(c1o[m], w0[64 + tb + m], a1); }
                resc[o2] = packh2(fmaxf(a0, 0.f), fmaxf(a1, 0.f));
            }
        }
        unsigned int resp[32];
        if (e == 1) {
            unsigned int inp[12];
            {
                const float* sp = self_obs + row * 15;
                const float* cp = cp_obs + row * 6;
                #pragma unroll
                for (int m = 0; m < 12; m++) {
                    int k0 = 2 * m, k1 = k0 + 1;
                    float a = (k0 < 15) ? sp[k0] : ((k0 < 21) ? cp[k0 - 15] : 0.f);
                    float c = (k1 < 15) ? sp[k1] : ((k1 < 21) ? cp[k1 - 15] : 0.f);
                    inp[m] = packh2(a, c);
                }
            }
            unsigned int r1p[32];
            #pragma unroll
            for (int o2 = 0; o2 < 32; o2++) {
                float a0 = bias[2 * o2], a1 = bias[2 * o2 + 1];
                const unsigned int* w0 = s_tile + O_PE1 + (2 * o2) * 12;
                #pragma unroll
                for (int m = 0; m < 12; m++) { a0 = dot2(inp[m], w0[m], a0); a1 = dot2(inp[m], w0[12 + m], a1); }
                r1p[o2] = packh2(fmaxf(a0, 0.f), fmaxf(a1, 0.f));
            }
            #pragma unroll
            for (int o2 = 0; o2 < 32; o2++) {
                float a0 = bias[64 + 2 * o2], a1 = bias[64 + 2 * o2 + 1];
                const unsigned int* w0 = s_tile + O_PE2 + (2 * o2) * 32;
                #pragma unroll
                for (int m = 0; m < 32; m++) { a0 = dot2(r1p[m], w0[m], a0); a1 = dot2(r1p[m], w0[32 + m], a1); }
                resp[o2] = packh2(fmaxf(a0, 0.f), fmaxf(a1, 0.f));
            }
        }
        __syncthreads();
        uint4* rt4 = reinterpret_cast<uint4*>(s_tile + s * 64);
        if (e == 0) {
            #pragma unroll
            for (int q = 0; q < 4; q++)
                rt4[8 + q] = make_uint4(resc[4 * q], resc[4 * q + 1], resc[4 * q + 2], resc[4 * q + 3]);
        } else {
            #pragma unroll
            for (int q = 0; q < 8; q++)
                rt4[q] = make_uint4(resp[4 * q], resp[4 * q + 1], resp[4 * q + 2], resp[4 * q + 3]);
            #pragma unroll
            for (int q = 0; q < 4; q++)
                rt4[12 + q] = make_uint4(resc[4 * q], resc[4 * q + 1], resc[4 * q + 2], resc[4 * q + 3]);
        }
    }

    const int g = t >> 1;
    const int e = t & 1;
    unsigned int wih[32], whh[16];
    #pragma unroll
    for (int j = 0; j < 32; j++) {
        int m = e * 32 + j;
        wih[j] = packh2(ih_w[(2 * m) * 256 + g], ih_w[(2 * m + 1) * 256 + g]);
    }
    #pragma unroll
    for (int j = 0; j < 16; j++) {
        int m = e * 16 + j;
        whh[j] = packh2(hh_w[(2 * m) * 256 + g], hh_w[(2 * m + 1) * 256 + g]);
    }
    const float bias_t = (e == 0) ? (ih_b[g] + hh_b[g]) : 0.f;
    __syncthreads();

    const int grp = g >> 6;
    float c = 0.f, h = 0.f, i_act = 0.f;
    #pragma unroll 1
    for (int s = 0; s < Sn; s++) {
        float acc = bias_t;
        const uint4* rq = reinterpret_cast<const uint4*>(s_tile + s * 64) + e * 8;
        #pragma unroll
        for (int q = 0; q < 8; q++) {
            uint4 rv = rq[q];
            acc = dot2(rv.x, wih[4 * q + 0], acc);
            acc = dot2(rv.y, wih[4 * q + 1], acc);
            acc = dot2(rv.z, wih[4 * q + 2], acc);
            acc = dot2(rv.w, wih[4 * q + 3], acc);
        }
        const uint4* hq = reinterpret_cast<const uint4*>(s_h32) + e * 4;
        #pragma unroll
        for (int q = 0; q < 4; q++) {
            uint4 hvv = hq[q];
            acc = dot2(hvv.x, whh[4 * q + 0], acc);
            acc = dot2(hvv.y, whh[4 * q + 1], acc);
            acc = dot2(hvv.z, whh[4 * q + 2], acc);
            acc = dot2(hvv.w, whh[4 * q + 3], acc);
        }
        float tot = acc + __shfl_xor(acc, 1);
        if (e == 0) {
            float act = (grp == 2) ? tanhf_(tot) : sigmoidf_(tot);
            if (grp == 0) i_act = act; else s_g[g - 64] = act;
        }
        __syncthreads();
        if (e == 0 && g < 64) {
            float f_ = s_g[g], g_ = s_g[64 + g], o_ = s_g[128 + g];
            c = f_ * c + i_act * g_;
            h = o_ * tanhf_(c);
            float hnext = __shfl_down(h, 2);
            if ((g & 1) == 0) {
                unsigned int hp = packh2(h, hnext);
                s_h32[g >> 1] = hp;
                s_tile[s * 64 + (((g >> 1) + s) & 31)] = hp;
            }
        }
        __syncthreads();
    }
    {
        const int w = t >> 6, lq = t & 63;
        const int m0 = (lq & 7) * 4;
        const int j0 = lq & 7;
        #pragma unroll 1
        for (int p = 0; p < 4; p++) {
            int s = w * 32 + p * 8 + (lq >> 3);
            float ath = 0.f, aan = 0.f, as0 = 0.f, as1 = 0.f, ab0 = 0.f, ab1 = 0.f;
            #pragma unroll
            for (int j = 0; j < 4; j++) {
                int m = m0 + j;
                unsigned int hvv = s_tile[s * 64 + ((m + s) & 31)];
                ath = dot2(hvv, s_hw[m], ath);
                aan = dot2(hvv, s_hw[32 + m], aan);
                as0 = dot2(hvv, s_hw[64 + m], as0);
                as1 = dot2(hvv, s_hw[96 + m], as1);
                ab0 = dot2(hvv, s_hw[128 + m], ab0);
                ab1 = dot2(hvv, s_hw[160 + m], ab1);
            }
            #pragma unroll
            for (int d = 1; d < 8; d <<= 1) {
                ath += __shfl_xor(ath, d); aan += __shfl_xor(aan, d);
                as0 += __shfl_xor(as0, d); as1 += __shfl_xor(as1, d);
                ab0 += __shfl_xor(ab0, d); ab1 += __shfl_xor(ab1, d);
            }
            long long row = (long long)b * Sn + s;
            if (j0 == 0)      out[row] = sigmoidf_(ath + s_hb[0]);
            else if (j0 == 1) out[BSn + row] = tanhf_(aan + s_hb[1]);
            else if (j0 == 2) out[2 * BSn + 2 * row] = s_hb[6];
            else if (j0 == 3) out[2 * BSn + 2 * row + 1] = s_hb[7];
            else if (j0 == 4) out[4 * BSn + 2 * row] = as0 + s_hb[2];
            else if (j0 == 5) out[4 * BSn + 2 * row + 1] = as1 + s_hb[3];
            else if (j0 == 6) out[6 * BSn + 2 * row] = ab0 + s_hb[4];
            else              out[6 * BSn + 2 * row + 1] = ab1 + s_hb[5];
        }
    }
    if (e == 0 && g < 64) {
        float* hn = out + 8 * BSn;
        float* cn = hn + (long long)Bn * 64;
        hn[(long long)b * 64 + g] = h;
        cn[(long long)b * 64 + g] = c;
    }
}

// ================= host =================
extern "C" void kernel_launch(void* const* d_in, const int* in_sizes, int n_in,
                              void* d_out, int out_size, void* d_ws, size_t ws_size,
                              hipStream_t stream)
{
    (void)in_sizes; (void)n_in; (void)out_size;
    float* out = (float*)d_out;
    const size_t X_BYTES = (size_t)BSn * 128 * 2;  // 134 MB f16

    if (d_ws != nullptr && ws_size >= X_BYTES) {
        unsigned int* Xg = (unsigned int*)d_ws;
        k1_encode<<<Bn, 512, 0, stream>>>(
            (const float*)d_in[0], (const float*)d_in[1], (const float*)d_in[2],
            (const float*)d_in[3], (const int*)d_in[4],
            (const float*)d_in[5], (const float*)d_in[6], (const float*)d_in[7], (const float*)d_in[8],
            (const float*)d_in[9],
            (const float*)d_in[10], (const float*)d_in[11], (const float*)d_in[12], (const float*)d_in[13],
            (const float*)d_in[14], (const float*)d_in[15], (const float*)d_in[16], (const float*)d_in[17],
            Xg);
        k2_lstm<<<Bn / 8, 1024, 0, stream>>>(
            (const float*)d_in[18], (const float*)d_in[19], (const float*)d_in[20], (const float*)d_in[21],
            (const float*)d_in[22], (const float*)d_in[23], (const float*)d_in[24], (const float*)d_in[25],
            (const float*)d_in[26], (const float*)d_in[27], (const float*)d_in[28], (const float*)d_in[29],
            Xg, out);
        k3_std<<<Bn, 256, 0, stream>>>((const float*)d_in[30], out);
    } else {
        k_fallback<<<Bn, 512, 0, stream>>>(
            (const float*)d_in[0], (const float*)d_in[1], (const float*)d_in[2],
            (const float*)d_in[3], (const int*)d_in[4],
            (const float*)d_in[5], (const float*)d_in[6], (const float*)d_in[7], (const float*)d_in[8],
            (const float*)d_in[9],
            (const float*)d_in[10], (const float*)d_in[11], (const float*)d_in[12], (const float*)d_in[13],
            (const float*)d_in[14], (const float*)d_in[15], (const float*)d_in[16], (const float*)d_in[17],
            (const float*)d_in[18], (const float*)d_in[19], (const float*)d_in[20], (const float*)d_in[21],
            (const float*)d_in[22], (const float*)d_in[23], (const float*)d_in[24], (const float*)d_in[25],
            (const float*)d_in[26], (const float*)d_in[27], (const float*)d_in[28], (const float*)d_in[29],
            (const float*)d_in[30], out);
    }
}

// Round 8
// 1463.617 us; speedup vs baseline: 4.3729x; 4.3729x over previous
//
#include <hip/hip_runtime.h>
#include <hip/hip_fp16.h>

#define DEVINL __device__ __forceinline__

static constexpr int Bn = 2048;
static constexpr int Sn = 256;
static constexpr long long BSn = (long long)Bn * Sn;  // 524288

typedef _Float16 h2v __attribute__((ext_vector_type(2)));
typedef _Float16 half8 __attribute__((ext_vector_type(8)));
typedef float floatx4 __attribute__((ext_vector_type(4)));

DEVINL float dot2(unsigned int a, unsigned int b, float c) {
#if __has_builtin(__builtin_amdgcn_fdot2)
    return __builtin_amdgcn_fdot2(__builtin_bit_cast(h2v, a), __builtin_bit_cast(h2v, b), c, false);
#else
    __half2 ha = __builtin_bit_cast(__half2, a);
    __half2 hb = __builtin_bit_cast(__half2, b);
    return c + __low2float(ha) * __low2float(hb) + __high2float(ha) * __high2float(hb);
#endif
}
DEVINL unsigned int packh2(float a, float b) {
    __half2 h = __floats2half2_rn(a, b);
    return __builtin_bit_cast(unsigned int, h);
}
DEVINL unsigned short f2h16(float f) { return __builtin_bit_cast(unsigned short, (_Float16)f); }
DEVINL float sigmoidf_(float x) { return 1.0f / (1.0f + __expf(-x)); }
DEVINL float tanhf_(float x) { return 2.0f / (1.0f + __expf(-2.0f * x)) - 1.0f; }

// encoder-weight LDS map (u32 offsets) — weights overlay, X rows overwrite after phase 0
enum {
    O_PE1 = 0,        // [64][12]  pe_w1^T pairs (21 pad 24)
    O_PE2 = 768,      // [64][32]  pe_w2^T pairs
    O_EE1 = 2816,     // [32][8]   ee_w1^T pairs (13 pad 16)
    O_EE2 = 3072,     // [16][16]  ee_w2^T pairs
    O_CB1 = 3328,     // [128][32] cb_w1^T pairs (63 pad 64)
    O_CB2 = 7424,     // [64][64]  cb_w2^T pairs
    O_BIAS = 11520    // 400 floats
};

// ================= k1: encoders -> X[BS][128] f16 (R3 sequential-liveness structure) =================
__global__ __launch_bounds__(256) void k1_encode(
    const float* __restrict__ self_obs, const float* __restrict__ tm_obs,
    const float* __restrict__ en_obs, const float* __restrict__ cp_obs,
    const int* __restrict__ role_ids,
    const float* __restrict__ pe_w1, const float* __restrict__ pe_b1,
    const float* __restrict__ pe_w2, const float* __restrict__ pe_b2,
    const float* __restrict__ role_emb,
    const float* __restrict__ ee_w1, const float* __restrict__ ee_b1,
    const float* __restrict__ ee_w2, const float* __restrict__ ee_b2,
    const float* __restrict__ cb_w1, const float* __restrict__ cb_b1,
    const float* __restrict__ cb_w2, const float* __restrict__ cb_b2,
    unsigned int* __restrict__ Xg)
{
    __shared__ __align__(16) unsigned int s_tile[Sn * 64];  // 64 KB: weights, then X-row tile
    const int t = threadIdx.x;
    const int b = blockIdx.x;

    // ---------------- weight staging (f32 -> f16 pairs, transposed+padded) ----------------
    for (int i = t; i < 768; i += 256) {
        int o = i / 12, m = i % 12, k0 = 2 * m, k1 = k0 + 1;
        float a = (k0 < 21) ? pe_w1[k0 * 64 + o] : 0.f;
        float c = (k1 < 21) ? pe_w1[k1 * 64 + o] : 0.f;
        s_tile[O_PE1 + i] = packh2(a, c);
    }
    for (int i = t; i < 2048; i += 256) {
        int o = i >> 5, m = i & 31;
        s_tile[O_PE2 + i] = packh2(pe_w2[(2 * m) * 64 + o], pe_w2[(2 * m + 1) * 64 + o]);
    }
    {
        int i = t;
        int o = i >> 3, m = i & 7, k0 = 2 * m, k1 = k0 + 1;
        float a = (k0 < 13) ? ee_w1[k0 * 32 + o] : 0.f;
        float c = (k1 < 13) ? ee_w1[k1 * 32 + o] : 0.f;
        s_tile[O_EE1 + i] = packh2(a, c);
    }
    {
        int i = t;
        int o = i >> 4, m = i & 15;
        s_tile[O_EE2 + i] = packh2(ee_w2[(2 * m) * 16 + o], ee_w2[(2 * m + 1) * 16 + o]);
    }
    for (int i = t; i < 4096; i += 256) {
        int o = i >> 5, m = i & 31, k0 = 2 * m, k1 = k0 + 1;
        float a = (k0 < 63) ? cb_w1[k0 * 128 + o] : 0.f;
        float c = (k1 < 63) ? cb_w1[k1 * 128 + o] : 0.f;
        s_tile[O_CB1 + i] = packh2(a, c);
    }
    for (int i = t; i < 4096; i += 256) {
        int o = i >> 6, m = i & 63;
        s_tile[O_CB2 + i] = packh2(cb_w2[(2 * m) * 64 + o], cb_w2[(2 * m + 1) * 64 + o]);
    }
    float* bias = (float*)(s_tile + O_BIAS);
    if (t < 64) bias[t] = pe_b1[t];
    if (t < 64) bias[64 + t] = pe_b2[t];
    if (t < 32) bias[128 + t] = ee_b1[t];
    if (t < 16) bias[160 + t] = ee_b2[t];
    if (t < 128) bias[176 + t] = cb_b1[t];
    if (t < 64) bias[304 + t] = cb_b2[t];
    if (t < 32) bias[368 + t] = role_emb[t];
    __syncthreads();

    // ---------------- phase 0: thread t handles step s=t (sequential liveness) ----------------
    {
        const long long row = (long long)b * Sn + t;
        // entity encoders: teammate -> lat[0..15], enemy max -> lat[16..31]
        float lat[32];
        #pragma unroll 1
        for (int src = 0; src < 3; src++) {
            const float* xp = (src == 0) ? (tm_obs + row * 13) : (en_obs + row * 26 + (src - 1) * 13);
            unsigned int xpr[8];
            #pragma unroll
            for (int m = 0; m < 8; m++) {
                int k0 = 2 * m, k1 = k0 + 1;
                xpr[m] = packh2((k0 < 13) ? xp[k0] : 0.f, (k1 < 13) ? xp[k1] : 0.f);
            }
            unsigned int e1[16];
            #pragma unroll
            for (int o2 = 0; o2 < 16; o2++) {
                float a0 = bias[128 + 2 * o2], a1 = bias[128 + 2 * o2 + 1];
                const unsigned int* w0 = s_tile + O_EE1 + (2 * o2) * 8;
                #pragma unroll
                for (int m = 0; m < 8; m++) { a0 = dot2(xpr[m], w0[m], a0); a1 = dot2(xpr[m], w0[8 + m], a1); }
                e1[o2] = packh2(fmaxf(a0, 0.f), fmaxf(a1, 0.f));
            }
            #pragma unroll
            for (int o = 0; o < 16; o++) {
                float a0 = bias[160 + o];
                const unsigned int* w0 = s_tile + O_EE2 + o * 16;
                #pragma unroll
                for (int m = 0; m < 16; m++) a0 = dot2(e1[m], w0[m], a0);
                if (src == 0) lat[o] = a0;
                else if (src == 1) lat[16 + o] = a0;
                else lat[16 + o] = fmaxf(lat[16 + o], a0);
            }
        }
        // command input pack: self(15) | tm(16) | en(16) | role(16) = 63 (pad 64)
        unsigned int cpp[32];
        {
            const float* sp = self_obs + row * 15;
            const int rid = role_ids[row];
            const float* rvec = bias + 368 + rid * 16;
            #pragma unroll
            for (int m = 0; m < 32; m++) {
                int k0 = 2 * m, k1 = k0 + 1;
                float a = (k0 < 15) ? sp[k0] : (k0 < 31) ? lat[k0 - 15] : (k0 < 47) ? lat[16 + k0 - 31] : rvec[k0 - 47];
                float c = (k1 < 15) ? sp[k1] : (k1 < 31) ? lat[k1 - 15] : (k1 < 47) ? lat[16 + k1 - 31]
                                                                       : (k1 < 63) ? rvec[k1 - 47] : 0.f;
                cpp[m] = packh2(a, c);
            }
        }
        // cmd L1 (63->128 relu)
        unsigned int c1[64];
        #pragma unroll
        for (int o2 = 0; o2 < 64; o2++) {
            float a0 = bias[176 + 2 * o2], a1 = bias[176 + 2 * o2 + 1];
            const unsigned int* w0 = s_tile + O_CB1 + (2 * o2) * 32;
            #pragma unroll
            for (int m = 0; m < 32; m++) { a0 = dot2(cpp[m], w0[m], a0); a1 = dot2(cpp[m], w0[32 + m], a1); }
            c1[o2] = packh2(fmaxf(a0, 0.f), fmaxf(a1, 0.f));
        }
        // cmd L2 (128->64 relu) -> resc
        unsigned int resc[32];
        #pragma unroll
        for (int o2 = 0; o2 < 32; o2++) {
            float a0 = bias[304 + 2 * o2], a1 = bias[304 + 2 * o2 + 1];
            const unsigned int* w0 = s_tile + O_CB2 + (2 * o2) * 64;
            #pragma unroll
            for (int m = 0; m < 64; m++) { a0 = dot2(c1[m], w0[m], a0); a1 = dot2(c1[m], w0[64 + m], a1); }
            resc[o2] = packh2(fmaxf(a0, 0.f), fmaxf(a1, 0.f));
        }
        // pilot input pack (reload self/cp)
        unsigned int inp[12];
        {
            const float* sp = self_obs + row * 15;
            const float* cp = cp_obs + row * 6;
            #pragma unroll
            for (int m = 0; m < 12; m++) {
                int k0 = 2 * m, k1 = k0 + 1;
                float a = (k0 < 15) ? sp[k0] : ((k0 < 21) ? cp[k0 - 15] : 0.f);
                float c = (k1 < 15) ? sp[k1] : ((k1 < 21) ? cp[k1 - 15] : 0.f);
                inp[m] = packh2(a, c);
            }
        }
        // pilot L1 (21->64 relu)
        unsigned int r1p[32];
        #pragma unroll
        for (int o2 = 0; o2 < 32; o2++) {
            float a0 = bias[2 * o2], a1 = bias[2 * o2 + 1];
            const unsigned int* w0 = s_tile + O_PE1 + (2 * o2) * 12;
            #pragma unroll
            for (int m = 0; m < 12; m++) { a0 = dot2(inp[m], w0[m], a0); a1 = dot2(inp[m], w0[12 + m], a1); }
            r1p[o2] = packh2(fmaxf(a0, 0.f), fmaxf(a1, 0.f));
        }
        // pilot L2 (64->64 relu) -> resp
        unsigned int resp[32];
        #pragma unroll
        for (int o2 = 0; o2 < 32; o2++) {
            float a0 = bias[64 + 2 * o2], a1 = bias[64 + 2 * o2 + 1];
            const unsigned int* w0 = s_tile + O_PE2 + (2 * o2) * 32;
            #pragma unroll
            for (int m = 0; m < 32; m++) { a0 = dot2(r1p[m], w0[m], a0); a1 = dot2(r1p[m], w0[32 + m], a1); }
            resp[o2] = packh2(fmaxf(a0, 0.f), fmaxf(a1, 0.f));
        }
        __syncthreads();  // all weight reads done
        // X row into tile (over dead weights): [pilot 32 u32 | cmd 32 u32]
        uint4* rt4 = reinterpret_cast<uint4*>(s_tile + t * 64);
        #pragma unroll
        for (int q = 0; q < 8; q++)
            rt4[q] = make_uint4(resp[4 * q], resp[4 * q + 1], resp[4 * q + 2], resp[4 * q + 3]);
        #pragma unroll
        for (int q = 0; q < 8; q++)
            rt4[8 + q] = make_uint4(resc[4 * q], resc[4 * q + 1], resc[4 * q + 2], resc[4 * q + 3]);
    }
    __syncthreads();
    // coalesced tile -> global copy (rows share layout with k2 reader)
    {
        const uint4* st4 = reinterpret_cast<const uint4*>(s_tile);
        uint4* xg4 = reinterpret_cast<uint4*>(Xg + (long long)b * Sn * 64);
        #pragma unroll
        for (int rep = 0; rep < 16; rep++) {
            int i = rep * 256 + t;
            xg4[i] = st4[i];
        }
    }
}

// ================= k2: batch-tiled MFMA LSTM (8 rows/block) =================
DEVINL void store_heads(float v0, float v1, float v2, float v3, int lane, int bb, int spos,
                        const float* s_misc, float* __restrict__ out)
{
    const int hc = lane & 15;
    const int rgrp = lane >> 4;
    if (hc >= 6 || rgrp >= 2) return;
    float vv[4] = {v0, v1, v2, v3};
    #pragma unroll
    for (int r = 0; r < 4; r++) {
        long long gr = (long long)bb * 8 + rgrp * 4 + r;
        long long idx = gr * Sn + spos;
        float v = vv[r];
        if (hc == 0)      out[idx] = sigmoidf_(v + s_misc[0]);
        else if (hc == 1) out[BSn + idx] = tanhf_(v + s_misc[1]);
        else if (hc == 2) out[4 * BSn + 2 * idx] = v + s_misc[2];
        else if (hc == 3) out[4 * BSn + 2 * idx + 1] = v + s_misc[3];
        else if (hc == 4) out[6 * BSn + 2 * idx] = v + s_misc[4];
        else              out[6 * BSn + 2 * idx + 1] = v + s_misc[5];
    }
}

__global__ __launch_bounds__(1024) void k2_lstm(
    const float* __restrict__ ih_w, const float* __restrict__ ih_b,
    const float* __restrict__ hh_w, const float* __restrict__ hh_b,
    const float* __restrict__ th_w, const float* __restrict__ th_b,
    const float* __restrict__ an_w, const float* __restrict__ an_b,
    const float* __restrict__ sh_w, const float* __restrict__ sh_b,
    const float* __restrict__ bo_w, const float* __restrict__ bo_b,
    const unsigned int* __restrict__ Xg, float* __restrict__ out)
{
    __shared__ __align__(16) unsigned short s_h[16][72];     // h (rows 8-15 zero)
    __shared__ __align__(16) unsigned short s_x[2][16][136]; // X dbuf (rows 8-15 zero)
    __shared__ float s_misc[8];

    const int t = threadIdx.x;
    const int bb = blockIdx.x;        // rows 8bb..8bb+7
    const int l = t & 63;
    const int w = t >> 6;             // wave 0..15

    {
        unsigned int* hz = (unsigned int*)&s_h[0][0];
        for (int i = t; i < 576; i += 1024) hz[i] = 0;
        unsigned int* xz = (unsigned int*)&s_x[0][0][0];
        for (int i = t; i < 2176; i += 1024) xz[i] = 0;
    }
    if (t == 0) {
        s_misc[0] = th_b[0]; s_misc[1] = an_b[0];
        s_misc[2] = sh_b[0]; s_misc[3] = sh_b[1];
        s_misc[4] = bo_b[0]; s_misc[5] = bo_b[1];
    }
    // weight fragments: wave w owns cols 16w..16w+15 (gate-interleaved: col = 4u+gt)
    const int col = w * 16 + (l & 15);
    const int origc = (col & 3) * 64 + (col >> 2);
    const int kof = (l >> 4) * 8;
    half8 bx[4], bh[2];
    #pragma unroll
    for (int kt = 0; kt < 4; kt++) {
        half8 v;
        #pragma unroll
        for (int j = 0; j < 8; j++) v[j] = (_Float16)ih_w[(kt * 32 + kof + j) * 256 + origc];
        bx[kt] = v;
    }
    #pragma unroll
    for (int kt = 0; kt < 2; kt++) {
        half8 v;
        #pragma unroll
        for (int j = 0; j < 8; j++) v[j] = (_Float16)hh_w[(kt * 32 + kof + j) * 256 + origc];
        bh[kt] = v;
    }
    const float bias_c = ih_b[origc] + hh_b[origc];
    half8 bhd[2];
    if (w == 15) {
        const int hc = l & 15;
        #pragma unroll
        for (int kt = 0; kt < 2; kt++) {
            half8 v;
            #pragma unroll
            for (int j = 0; j < 8; j++) {
                int k = kt * 32 + kof + j;
                float wv = 0.f;
                if (hc == 0) wv = th_w[k];
                else if (hc == 1) wv = an_w[k];
                else if (hc == 2) wv = sh_w[2 * k];
                else if (hc == 3) wv = sh_w[2 * k + 1];
                else if (hc == 4) wv = bo_w[2 * k];
                else if (hc == 5) wv = bo_w[2 * k + 1];
                v[j] = (_Float16)wv;
            }
            bhd[kt] = v;
        }
    }
    __syncthreads();
    const long long xrow0 = (long long)bb * 8 * Sn;
    if (t < 256) {
        int r = t >> 5, seg = t & 31;
        const unsigned int* src = Xg + (xrow0 + (long long)r * Sn + 0) * 64 + seg * 2;
        unsigned int v0 = src[0], v1 = src[1];
        unsigned int* dst = (unsigned int*)&s_x[0][r][seg * 4];
        dst[0] = v0; dst[1] = v1;
    }
    __syncthreads();

    float cs[4] = {0.f, 0.f, 0.f, 0.f};
    float hv[4] = {0.f, 0.f, 0.f, 0.f};
    const int gt = l & 3;
    const int arow = l & 15;
    int cur = 0;

    #pragma unroll 1
    for (int s = 0; s < Sn; s++) {
        unsigned int p0 = 0, p1 = 0;
        const bool pf = (t < 256) && (s + 1 < Sn);
        if (pf) {
            int r = t >> 5, seg = t & 31;
            const unsigned int* src = Xg + (xrow0 + (long long)r * Sn + (s + 1)) * 64 + seg * 2;
            p0 = src[0]; p1 = src[1];
        }
        half8 xa[4], ha[2];
        #pragma unroll
        for (int kt = 0; kt < 4; kt++) xa[kt] = *(const half8*)&s_x[cur][arow][kt * 32 + kof];
        #pragma unroll
        for (int kt = 0; kt < 2; kt++) ha[kt] = *(const half8*)&s_h[arow][kt * 32 + kof];
        floatx4 acc = {bias_c, bias_c, bias_c, bias_c};
        #pragma unroll
        for (int kt = 0; kt < 4; kt++) acc = __builtin_amdgcn_mfma_f32_16x16x32_f16(xa[kt], bx[kt], acc, 0, 0, 0);
        #pragma unroll
        for (int kt = 0; kt < 2; kt++) acc = __builtin_amdgcn_mfma_f32_16x16x32_f16(ha[kt], bh[kt], acc, 0, 0, 0);
        if (w == 15) {
            floatx4 hacc = {0.f, 0.f, 0.f, 0.f};
            hacc = __builtin_amdgcn_mfma_f32_16x16x32_f16(ha[0], bhd[0], hacc, 0, 0, 0);
            hacc = __builtin_amdgcn_mfma_f32_16x16x32_f16(ha[1], bhd[1], hacc, 0, 0, 0);
            if (s >= 1) store_heads(hacc[0], hacc[1], hacc[2], hacc[3], l, bb, s - 1, s_misc, out);
        }
        float av[4], x1[4], x2[4], x3[4];
        #pragma unroll
        for (int r = 0; r < 4; r++) av[r] = (gt == 2) ? tanhf_(acc[r]) : sigmoidf_(acc[r]);
        #pragma unroll
        for (int r = 0; r < 4; r++) {
            x1[r] = __shfl_xor(av[r], 1);
            x2[r] = __shfl_xor(av[r], 2);
            x3[r] = __shfl_xor(x1[r], 2);
        }
        #pragma unroll
        for (int r = 0; r < 4; r++) {
            cs[r] = x1[r] * cs[r] + av[r] * x2[r];
            hv[r] = x3[r] * tanhf_(cs[r]);
        }
        __syncthreads();
        if (gt == 0 && (l >> 4) < 2) {
            const int uu = w * 4 + ((l & 15) >> 2);
            #pragma unroll
            for (int r = 0; r < 4; r++) s_h[(l >> 4) * 4 + r][uu] = f2h16(hv[r]);
        }
        if (pf) {
            int r = t >> 5, seg = t & 31;
            unsigned int* dst = (unsigned int*)&s_x[cur ^ 1][r][seg * 4];
            dst[0] = p0; dst[1] = p1;
        }
        __syncthreads();
        cur ^= 1;
    }
    if (w == 15) {
        half8 ha0 = *(const half8*)&s_h[arow][kof];
        half8 ha1 = *(const half8*)&s_h[arow][32 + kof];
        floatx4 hacc = {0.f, 0.f, 0.f, 0.f};
        hacc = __builtin_amdgcn_mfma_f32_16x16x32_f16(ha0, bhd[0], hacc, 0, 0, 0);
        hacc = __builtin_amdgcn_mfma_f32_16x16x32_f16(ha1, bhd[1], hacc, 0, 0, 0);
        store_heads(hacc[0], hacc[1], hacc[2], hacc[3], l, bb, Sn - 1, s_misc, out);
    }
    if (gt == 0 && (l >> 4) < 2) {
        float* hn = out + 8 * BSn;
        float* cn = hn + (long long)Bn * 64;
        const int uu = w * 4 + ((l & 15) >> 2);
        #pragma unroll
        for (int r = 0; r < 4; r++) {
            long long gr = (long long)bb * 8 + (l >> 4) * 4 + r;
            hn[gr * 64 + uu] = hv[r];
            cn[gr * 64 + uu] = cs[r];
        }
    }
}

// ================= k3: std fill =================
__global__ __launch_bounds__(256) void k3_std(const float* __restrict__ logstd, float* __restrict__ out)
{
    float s0 = fmaxf(__expf(logstd[0]), 0.05f);
    float s1 = fmaxf(__expf(logstd[1]), 0.05f);
    long long i = (long long)blockIdx.x * 256 + threadIdx.x;
    float2 v = make_float2(s0, s1);
    reinterpret_cast<float2*>(out + 2 * BSn)[i] = v;
}

// ================= fallback: monolithic (R3 structure) =================
__global__ __launch_bounds__(256)
void k_fallback(
    const float* __restrict__ self_obs, const float* __restrict__ tm_obs,
    const float* __restrict__ en_obs, const float* __restrict__ cp_obs,
    const int* __restrict__ role_ids,
    const float* __restrict__ pe_w1, const float* __restrict__ pe_b1,
    const float* __restrict__ pe_w2, const float* __restrict__ pe_b2,
    const float* __restrict__ role_emb,
    const float* __restrict__ ee_w1, const float* __restrict__ ee_b1,
    const float* __restrict__ ee_w2, const float* __restrict__ ee_b2,
    const float* __restrict__ cb_w1, const float* __restrict__ cb_b1,
    const float* __restrict__ cb_w2, const float* __restrict__ cb_b2,
    const float* __restrict__ ih_w, const float* __restrict__ ih_b,
    const float* __restrict__ hh_w, const float* __restrict__ hh_b,
    const float* __restrict__ th_w, const float* __restrict__ th_b,
    const float* __restrict__ an_w, const float* __restrict__ an_b,
    const float* __restrict__ sh_w, const float* __restrict__ sh_b,
    const float* __restrict__ bo_w, const float* __restrict__ bo_b,
    const float* __restrict__ logstd, float* __restrict__ out)
{
    __shared__ __align__(16) unsigned int s_tile[Sn * 64];
    __shared__ __align__(16) unsigned int s_h32[32];
    __shared__ float s_g[192];
    __shared__ unsigned int s_hw[192];
    __shared__ float s_hb[8];

    const int t = threadIdx.x;
    const int b = blockIdx.x;

    for (int i = t; i < 768; i += 256) {
        int o = i / 12, m = i % 12, k0 = 2 * m, k1 = k0 + 1;
        float a = (k0 < 21) ? pe_w1[k0 * 64 + o] : 0.f;
        float c = (k1 < 21) ? pe_w1[k1 * 64 + o] : 0.f;
        s_tile[O_PE1 + i] = packh2(a, c);
    }
    for (int i = t; i < 2048; i += 256) {
        int o = i >> 5, m = i & 31;
        s_tile[O_PE2 + i] = packh2(pe_w2[(2 * m) * 64 + o], pe_w2[(2 * m + 1) * 64 + o]);
    }
    {
        int i = t;
        int o = i >> 3, m = i & 7, k0 = 2 * m, k1 = k0 + 1;
        float a = (k0 < 13) ? ee_w1[k0 * 32 + o] : 0.f;
        float c = (k1 < 13) ? ee_w1[k1 * 32 + o] : 0.f;
        s_tile[O_EE1 + i] = packh2(a, c);
    }
    {
        int i = t;
        int o = i >> 4, m = i & 15;
        s_tile[O_EE2 + i] = packh2(ee_w2[(2 * m) * 16 + o], ee_w2[(2 * m + 1) * 16 + o]);
    }
    for (int i = t; i < 4096; i += 256) {
        int o = i >> 5, m = i & 31, k0 = 2 * m, k1 = k0 + 1;
        float a = (k0 < 63) ? cb_w1[k0 * 128 + o] : 0.f;
        float c = (k1 < 63) ? cb_w1[k1 * 128 + o] : 0.f;
        s_tile[O_CB1 + i] = packh2(a, c);
    }
    for (int i = t; i < 4096; i += 256) {
        int o = i >> 6, m = i & 63;
        s_tile[O_CB2 + i] = packh2(cb_w2[(2 * m) * 64 + o], cb_w2[(2 * m + 1) * 64 + o]);
    }
    float* bias = (float*)(s_tile + O_BIAS);
    if (t < 64) bias[t] = pe_b1[t];
    if (t < 64) bias[64 + t] = pe_b2[t];
    if (t < 32) bias[128 + t] = ee_b1[t];
    if (t < 16) bias[160 + t] = ee_b2[t];
    if (t < 128) bias[176 + t] = cb_b1[t];
    if (t < 64) bias[304 + t] = cb_b2[t];
    if (t < 32) bias[368 + t] = role_emb[t];
    if (t < 32)        s_hw[t]        = packh2(th_w[2 * t], th_w[2 * t + 1]);
    else if (t < 64)  { int m = t - 32;  s_hw[32 + m]  = packh2(an_w[2 * m], an_w[2 * m + 1]); }
    else if (t < 96)  { int m = t - 64;  s_hw[64 + m]  = packh2(sh_w[4 * m], sh_w[4 * m + 2]); }
    else if (t < 128) { int m = t - 96;  s_hw[96 + m]  = packh2(sh_w[4 * m + 1], sh_w[4 * m + 3]); }
    else if (t < 160) { int m = t - 128; s_hw[128 + m] = packh2(bo_w[4 * m], bo_w[4 * m + 2]); }
    else if (t < 192) { int m = t - 160; s_hw[160 + m] = packh2(bo_w[4 * m + 1], bo_w[4 * m + 3]); }
    if (t == 0) {
        s_hb[0] = th_b[0]; s_hb[1] = an_b[0];
        s_hb[2] = sh_b[0]; s_hb[3] = sh_b[1];
        s_hb[4] = bo_b[0]; s_hb[5] = bo_b[1];
        s_hb[6] = fmaxf(__expf(logstd[0]), 0.05f);
        s_hb[7] = fmaxf(__expf(logstd[1]), 0.05f);
    }
    if (t < 32) s_h32[t] = 0u;
    __syncthreads();

    {
        const long long row = (long long)b * Sn + t;
        float lat[32];
        #pragma unroll 1
        for (int src = 0; src < 3; src++) {
            const float* xp = (src == 0) ? (tm_obs + row * 13) : (en_obs + row * 26 + (src - 1) * 13);
            unsigned int xpr[8];
            #pragma unroll
            for (int m = 0; m < 8; m++) {
                int k0 = 2 * m, k1 = k0 + 1;
                xpr[m] = packh2((k0 < 13) ? xp[k0] : 0.f, (k1 < 13) ? xp[k1] : 0.f);
            }
            unsigned int e1[16];
            #pragma unroll
            for (int o2 = 0; o2 < 16; o2++) {
                float a0 = bias[128 + 2 * o2], a1 = bias[128 + 2 * o2 + 1];
                const unsigned int* w0 = s_tile + O_EE1 + (2 * o2) * 8;
                #pragma unroll
                for (int m = 0; m < 8; m++) { a0 = dot2(xpr[m], w0[m], a0); a1 = dot2(xpr[m], w0[8 + m], a1); }
                e1[o2] = packh2(fmaxf(a0, 0.f), fmaxf(a1, 0.f));
            }
            #pragma unroll
            for (int o = 0; o < 16; o++) {
                float a0 = bias[160 + o];
                const unsigned int* w0 = s_tile + O_EE2 + o * 16;
                #pragma unroll
                for (int m = 0; m < 16; m++) a0 = dot2(e1[m], w0[m], a0);
                if (src == 0) lat[o] = a0;
                else if (src == 1) lat[16 + o] = a0;
                else lat[16 + o] = fmaxf(lat[16 + o], a0);
            }
        }
        unsigned int cpp[32];
        {
            const float* sp = self_obs + row * 15;
            const int rid = role_ids[row];
            const float* rvec = bias + 368 + rid * 16;
            #pragma unroll
            for (int m = 0; m < 32; m++) {
                int k0 = 2 * m, k1 = k0 + 1;
                float a = (k0 < 15) ? sp[k0] : (k0 < 31) ? lat[k0 - 15] : (k0 < 47) ? lat[16 + k0 - 31] : rvec[k0 - 47];
                float c = (k1 < 15) ? sp[k1] : (k1 < 31) ? lat[k1 - 15] : (k1 < 47) ? lat[16 + k1 - 31]
                                                                       : (k1 < 63) ? rvec[k1 - 47] : 0.f;
                cpp[m] = packh2(a, c);
            }
        }
        unsigned int c1[64];
        #pragma unroll
        for (int o2 = 0; o2 < 64; o2++) {
            float a0 = bias[176 + 2 * o2], a1 = bias[176 + 2 * o2 + 1];
            const unsigned int* w0 = s_tile + O_CB1 + (2 * o2) * 32;
            #pragma unroll
            for (int m = 0; m < 32; m++) { a0 = dot2(cpp[m], w0[m], a0); a1 = dot2(cpp[m], w0[32 + m], a1); }
            c1[o2] = packh2(fmaxf(a0, 0.f), fmaxf(a1, 0.f));
        }
        unsigned int resc[32];
        #pragma unroll
        for (int o2 = 0; o2 < 32; o2++) {
            float a0 = bias[304 + 2 * o2], a1 = bias[304 + 2 * o2 + 1];
            const unsigned int* w0 = s_tile + O_CB2 + (2 * o2) * 64;
            #pragma unroll
            for (int m = 0; m < 64; m++) { a0 = dot2(c1[m], w0[m], a0); a1 = dot2(c1[m], w0[64 + m], a1); }
            resc[o2] = packh2(fmaxf(a0, 0.f), fmaxf(a1, 0.f));
        }
        unsigned int inp[12];
        {
            const float* sp = self_obs + row * 15;
            const float* cp = cp_obs + row * 6;
            #pragma unroll
            for (int m = 0; m < 12; m++) {
                int k0 = 2 * m, k1 = k0 + 1;
                float a = (k0 < 15) ? sp[k0] : ((k0 < 21) ? cp[k0 - 15] : 0.f);
                float c = (k1 < 15) ? sp[k1] : ((k1 < 21) ? cp[k1 - 15] : 0.f);
                inp[m] = packh2(a, c);
            }
        }
        unsigned int r1p[32];
        #pragma unroll
        for (int o2 = 0; o2 < 32; o2++) {
            float a0 = bias[2 * o2], a1 = bias[2 * o2 + 1];
            const unsigned int* w0 = s_tile + O_PE1 + (2 * o2) * 12;
            #pragma unroll
            for (int m = 0; m < 12; m++) { a0 = dot2(inp[m], w0[m], a0); a1 = dot2(inp[m], w0[12 + m], a1); }
            r1p[o2] = packh2(fmaxf(a0, 0.f), fmaxf(a1, 0.f));
        }
        unsigned int resp[32];
        #pragma unroll
        for (int o2 = 0; o2 < 32; o2++) {
            float a0 = bias[64 + 2 * o2], a1 = bias[64 + 2 * o2 + 1];
            const unsigned int* w0 = s_tile + O_PE2 + (2 * o2) * 32;
            #pragma unroll
            for (int m = 0; m < 32; m++) { a0 = dot2(r1p[m], w0[m], a0); a1 = dot2(r1p[m], w0[32 + m], a1); }
            resp[o2] = packh2(fmaxf(a0, 0.f), fmaxf(a1, 0.f));
        }
        __syncthreads();
        uint4* rt4 = reinterpret_cast<uint4*>(s_tile + t * 64);
        #pragma unroll
        for (int q = 0; q < 8; q++)
            rt4[q] = make_uint4(resp[4 * q], resp[4 * q + 1], resp[4 * q + 2], resp[4 * q + 3]);
        #pragma unroll
        for (int q = 0; q < 8; q++)
            rt4[8 + q] = make_uint4(resc[4 * q], resc[4 * q + 1], resc[4 * q + 2], resc[4 * q + 3]);
    }

    unsigned int wih[64], whh[32];
    #pragma unroll
    for (int m = 0; m < 64; m++) wih[m] = packh2(ih_w[(2 * m) * 256 + t], ih_w[(2 * m + 1) * 256 + t]);
    #pragma unroll
    for (int m = 0; m < 32; m++) whh[m] = packh2(hh_w[(2 * m) * 256 + t], hh_w[(2 * m + 1) * 256 + t]);
    const float bias_t = ih_b[t] + hh_b[t];
    __syncthreads();

    const int grp = t >> 6;
    const int u = t & 63;
    float c = 0.f, h = 0.f, i_act = 0.f;
    #pragma unroll 1
    for (int s = 0; s < Sn; s++) {
        float acc = bias_t;
        const uint4* rq = reinterpret_cast<const uint4*>(s_tile + s * 64);
        #pragma unroll
        for (int q = 0; q < 16; q++) {
            uint4 rv = rq[q];
            acc = dot2(rv.x, wih[4 * q + 0], acc);
            acc = dot2(rv.y, wih[4 * q + 1], acc);
            acc = dot2(rv.z, wih[4 * q + 2], acc);
            acc = dot2(rv.w, wih[4 * q + 3], acc);
        }
        const uint4* hq = reinterpret_cast<const uint4*>(s_h32);
        #pragma unroll
        for (int q = 0; q < 8; q++) {
            uint4 hvv = hq[q];
            acc = dot2(hvv.x, whh[4 * q + 0], acc);
            acc = dot2(hvv.y, whh[4 * q + 1], acc);
            acc = dot2(hvv.z, whh[4 * q + 2], acc);
            acc = dot2(hvv.w, whh[4 * q + 3], acc);
        }
        float act = (grp == 2) ? tanhf_(acc) : sigmoidf_(acc);
        if (grp == 0) i_act = act; else s_g[t - 64] = act;
        __syncthreads();
        if (t < 64) {
            float f_ = s_g[u], g_ = s_g[64 + u], o_ = s_g[128 + u];
            c = f_ * c + i_act * g_;
            h = o_ * tanhf_(c);
            float hnext = __shfl_down(h, 1);
            if ((u & 1) == 0) {
                unsigned int hp = packh2(h, hnext);
                s_h32[u >> 1] = hp;
                s_tile[s * 64 + (((u >> 1) + s) & 31)] = hp;
            }
        }
        __syncthreads();
    }
    {
        const int w = t >> 6, lq = t & 63;
        const int m0 = (lq & 7) * 4;
        const int j0 = lq & 7;
        #pragma unroll 1
        for (int p = 0; p < 8; p++) {
            int s = w * 64 + p * 8 + (lq >> 3);
            float ath = 0.f, aan = 0.f, as0 = 0.f, as1 = 0.f, ab0 = 0.f, ab1 = 0.f;
            #pragma unroll
            for (int j = 0; j < 4; j++) {
                int m = m0 + j;
                unsigned int hvv = s_tile[s * 64 + ((m + s) & 31)];
                ath = dot2(hvv, s_hw[m], ath);
                aan = dot2(hvv, s_hw[32 + m], aan);
                as0 = dot2(hvv, s_hw[64 + m], as0);
                as1 = dot2(hvv, s_hw[96 + m], as1);
                ab0 = dot2(hvv, s_hw[128 + m], ab0);
                ab1 = dot2(hvv, s_hw[160 + m], ab1);
            }
            #pragma unroll
            for (int d = 1; d < 8; d <<= 1) {
                ath += __shfl_xor(ath, d); aan += __shfl_xor(aan, d);
                as0 += __shfl_xor(as0, d); as1 += __shfl_xor(as1, d);
                ab0 += __shfl_xor(ab0, d); ab1 += __shfl_xor(ab1, d);
            }
            long long row = (long long)b * Sn + s;
            if (j0 == 0)      out[row] = sigmoidf_(ath + s_hb[0]);
            else if (j0 == 1) out[BSn + row] = tanhf_(aan + s_hb[1]);
            else if (j0 == 2) out[2 * BSn + 2 * row] = s_hb[6];
            else if (j0 == 3) out[2 * BSn + 2 * row + 1] = s_hb[7];
            else if (j0 == 4) out[4 * BSn + 2 * row] = as0 + s_hb[2];
            else if (j0 == 5) out[4 * BSn + 2 * row + 1] = as1 + s_hb[3];
            else if (j0 == 6) out[6 * BSn + 2 * row] = ab0 + s_hb[4];
            else              out[6 * BSn + 2 * row + 1] = ab1 + s_hb[5];
        }
    }
    if (t < 64) {
        float* hn = out + 8 * BSn;
        float* cn = hn + (long long)Bn * 64;
        hn[(long long)b * 64 + u] = h;
        cn[(long long)b * 64 + u] = c;
    }
}

// ================= host =================
extern "C" void kernel_launch(void* const* d_in, const int* in_sizes, int n_in,
                              void* d_out, int out_size, void* d_ws, size_t ws_size,
                              hipStream_t stream)
{
    (void)in_sizes; (void)n_in; (void)out_size;
    float* out = (float*)d_out;
    const size_t X_BYTES = (size_t)BSn * 128 * 2;  // 134 MB f16

    if (d_ws != nullptr && ws_size >= X_BYTES) {
        unsigned int* Xg = (unsigned int*)d_ws;
        k1_encode<<<Bn, 256, 0, stream>>>(
            (const float*)d_in[0], (const float*)d_in[1], (const float*)d_in[2],
            (const float*)d_in[3], (const int*)d_in[4],
            (const float*)d_in[5], (const float*)d_in[6], (const float*)d_in[7], (const float*)d_in[8],
            (const float*)d_in[9],
            (const float*)d_in[10], (const float*)d_in[11], (const float*)d_in[12], (const float*)d_in[13],
            (const float*)d_in[14], (const float*)d_in[15], (const float*)d_in[16], (const float*)d_in[17],
            Xg);
        k2_lstm<<<Bn / 8, 1024, 0, stream>>>(
            (const float*)d_in[18], (const float*)d_in[19], (const float*)d_in[20], (const float*)d_in[21],
            (const float*)d_in[22], (const float*)d_in[23], (const float*)d_in[24], (const float*)d_in[25],
            (const float*)d_in[26], (const float*)d_in[27], (const float*)d_in[28], (const float*)d_in[29],
            Xg, out);
        k3_std<<<Bn, 256, 0, stream>>>((const float*)d_in[30], out);
    } else {
        k_fallback<<<Bn, 256, 0, stream>>>(
            (const float*)d_in[0], (const float*)d_in[1], (const float*)d_in[2],
            (const float*)d_in[3], (const int*)d_in[4],
            (const float*)d_in[5], (const float*)d_in[6], (const float*)d_in[7], (const float*)d_in[8],
            (const float*)d_in[9],
            (const float*)d_in[10], (const float*)d_in[11], (const float*)d_in[12], (const float*)d_in[13],
            (const float*)d_in[14], (const float*)d_in[15], (const float*)d_in[16], (const float*)d_in[17],
            (const float*)d_in[18], (const float*)d_in[19], (const float*)d_in[20], (const float*)d_in[21],
            (const float*)d_in[22], (const float*)d_in[23], (const float*)d_in[24], (const float*)d_in[25],
            (const float*)d_in[26], (const float*)d_in[27], (const float*)d_in[28], (const float*)d_in[29],
            (const float*)d_in[30], out);
    }
}

// Round 9
// 1048.648 us; speedup vs baseline: 6.1034x; 1.3957x over previous
//
#include <hip/hip_runtime.h>
#include <hip/hip_fp16.h>

#define DEVINL __device__ __forceinline__

static constexpr int Bn = 2048;
static constexpr int Sn = 256;
static constexpr long long BSn = (long long)Bn * Sn;  // 524288

typedef _Float16 h2v __attribute__((ext_vector_type(2)));
typedef _Float16 half8 __attribute__((ext_vector_type(8)));
typedef float floatx4 __attribute__((ext_vector_type(4)));

DEVINL float dot2(unsigned int a, unsigned int b, float c) {
#if __has_builtin(__builtin_amdgcn_fdot2)
    return __builtin_amdgcn_fdot2(__builtin_bit_cast(h2v, a), __builtin_bit_cast(h2v, b), c, false);
#else
    __half2 ha = __builtin_bit_cast(__half2, a);
    __half2 hb = __builtin_bit_cast(__half2, b);
    return c + __low2float(ha) * __low2float(hb) + __high2float(ha) * __high2float(hb);
#endif
}
DEVINL float dot4(uint4 w, const unsigned int* x, float a) {
    a = dot2(x[0], w.x, a); a = dot2(x[1], w.y, a);
    a = dot2(x[2], w.z, a); a = dot2(x[3], w.w, a);
    return a;
}
DEVINL unsigned int packh2(float a, float b) {
    __half2 h = __floats2half2_rn(a, b);
    return __builtin_bit_cast(unsigned int, h);
}
DEVINL unsigned short f2h16(float f) { return __builtin_bit_cast(unsigned short, (_Float16)f); }
DEVINL float sigmoidf_(float x) { return 1.0f / (1.0f + __expf(-x)); }
DEVINL float tanhf_(float x) { return 2.0f / (1.0f + __expf(-2.0f * x)) - 1.0f; }

// encoder-weight LDS map (u32 offsets) — weights overlay, X rows overwrite after phase 0
enum {
    O_PE1 = 0,        // [64][12]  pe_w1^T pairs (21 pad 24)
    O_PE2 = 768,      // [64][32]  pe_w2^T pairs
    O_EE1 = 2816,     // [32][8]   ee_w1^T pairs (13 pad 16)
    O_EE2 = 3072,     // [16][16]  ee_w2^T pairs
    O_CB1 = 3328,     // [128][32] cb_w1^T pairs (63 pad 64)
    O_CB2 = 7424,     // [64][64]  cb_w2^T pairs
    O_BIAS = 11520    // 400 floats
};

// ================= k1: encoders -> X[BS][128] f16 (uint4 weight reads) =================
__global__ __launch_bounds__(256) void k1_encode(
    const float* __restrict__ self_obs, const float* __restrict__ tm_obs,
    const float* __restrict__ en_obs, const float* __restrict__ cp_obs,
    const int* __restrict__ role_ids,
    const float* __restrict__ pe_w1, const float* __restrict__ pe_b1,
    const float* __restrict__ pe_w2, const float* __restrict__ pe_b2,
    const float* __restrict__ role_emb,
    const float* __restrict__ ee_w1, const float* __restrict__ ee_b1,
    const float* __restrict__ ee_w2, const float* __restrict__ ee_b2,
    const float* __restrict__ cb_w1, const float* __restrict__ cb_b1,
    const float* __restrict__ cb_w2, const float* __restrict__ cb_b2,
    unsigned int* __restrict__ Xg)
{
    __shared__ __align__(16) unsigned int s_tile[Sn * 64];  // 64 KB: weights, then X-row tile
    const int t = threadIdx.x;
    const int b = blockIdx.x;

    for (int i = t; i < 768; i += 256) {
        int o = i / 12, m = i % 12, k0 = 2 * m, k1 = k0 + 1;
        float a = (k0 < 21) ? pe_w1[k0 * 64 + o] : 0.f;
        float c = (k1 < 21) ? pe_w1[k1 * 64 + o] : 0.f;
        s_tile[O_PE1 + i] = packh2(a, c);
    }
    for (int i = t; i < 2048; i += 256) {
        int o = i >> 5, m = i & 31;
        s_tile[O_PE2 + i] = packh2(pe_w2[(2 * m) * 64 + o], pe_w2[(2 * m + 1) * 64 + o]);
    }
    {
        int i = t;
        int o = i >> 3, m = i & 7, k0 = 2 * m, k1 = k0 + 1;
        float a = (k0 < 13) ? ee_w1[k0 * 32 + o] : 0.f;
        float c = (k1 < 13) ? ee_w1[k1 * 32 + o] : 0.f;
        s_tile[O_EE1 + i] = packh2(a, c);
    }
    {
        int i = t;
        int o = i >> 4, m = i & 15;
        s_tile[O_EE2 + i] = packh2(ee_w2[(2 * m) * 16 + o], ee_w2[(2 * m + 1) * 16 + o]);
    }
    for (int i = t; i < 4096; i += 256) {
        int o = i >> 5, m = i & 31, k0 = 2 * m, k1 = k0 + 1;
        float a = (k0 < 63) ? cb_w1[k0 * 128 + o] : 0.f;
        float c = (k1 < 63) ? cb_w1[k1 * 128 + o] : 0.f;
        s_tile[O_CB1 + i] = packh2(a, c);
    }
    for (int i = t; i < 4096; i += 256) {
        int o = i >> 6, m = i & 63;
        s_tile[O_CB2 + i] = packh2(cb_w2[(2 * m) * 64 + o], cb_w2[(2 * m + 1) * 64 + o]);
    }
    float* bias = (float*)(s_tile + O_BIAS);
    if (t < 64) bias[t] = pe_b1[t];
    if (t < 64) bias[64 + t] = pe_b2[t];
    if (t < 32) bias[128 + t] = ee_b1[t];
    if (t < 16) bias[160 + t] = ee_b2[t];
    if (t < 128) bias[176 + t] = cb_b1[t];
    if (t < 64) bias[304 + t] = cb_b2[t];
    if (t < 32) bias[368 + t] = role_emb[t];
    __syncthreads();

    {
        const long long row = (long long)b * Sn + t;
        // entity encoders: teammate -> lat[0..15], enemy max -> lat[16..31]
        float lat[32];
        #pragma unroll 1
        for (int src = 0; src < 3; src++) {
            const float* xp = (src == 0) ? (tm_obs + row * 13) : (en_obs + row * 26 + (src - 1) * 13);
            unsigned int xpr[8];
            #pragma unroll
            for (int m = 0; m < 8; m++) {
                int k0 = 2 * m, k1 = k0 + 1;
                xpr[m] = packh2((k0 < 13) ? xp[k0] : 0.f, (k1 < 13) ? xp[k1] : 0.f);
            }
            unsigned int e1[16];
            #pragma unroll
            for (int o2 = 0; o2 < 16; o2++) {
                float a0 = bias[128 + 2 * o2], a1 = bias[128 + 2 * o2 + 1];
                const uint4* w4 = (const uint4*)(s_tile + O_EE1 + (2 * o2) * 8);
                a0 = dot4(w4[0], xpr, a0); a0 = dot4(w4[1], xpr + 4, a0);
                a1 = dot4(w4[2], xpr, a1); a1 = dot4(w4[3], xpr + 4, a1);
                e1[o2] = packh2(fmaxf(a0, 0.f), fmaxf(a1, 0.f));
            }
            #pragma unroll
            for (int o = 0; o < 16; o++) {
                float a0 = bias[160 + o];
                const uint4* w4 = (const uint4*)(s_tile + O_EE2 + o * 16);
                #pragma unroll
                for (int q = 0; q < 4; q++) a0 = dot4(w4[q], e1 + 4 * q, a0);
                if (src == 0) lat[o] = a0;
                else if (src == 1) lat[16 + o] = a0;
                else lat[16 + o] = fmaxf(lat[16 + o], a0);
            }
        }
        // command input pack
        unsigned int cpp[32];
        {
            const float* sp = self_obs + row * 15;
            const int rid = role_ids[row];
            const float* rvec = bias + 368 + rid * 16;
            #pragma unroll
            for (int m = 0; m < 32; m++) {
                int k0 = 2 * m, k1 = k0 + 1;
                float a = (k0 < 15) ? sp[k0] : (k0 < 31) ? lat[k0 - 15] : (k0 < 47) ? lat[16 + k0 - 31] : rvec[k0 - 47];
                float c = (k1 < 15) ? sp[k1] : (k1 < 31) ? lat[k1 - 15] : (k1 < 47) ? lat[16 + k1 - 31]
                                                                       : (k1 < 63) ? rvec[k1 - 47] : 0.f;
                cpp[m] = packh2(a, c);
            }
        }
        // cmd L1 (63->128 relu)
        unsigned int c1[64];
        #pragma unroll
        for (int o2 = 0; o2 < 64; o2++) {
            float a0 = bias[176 + 2 * o2], a1 = bias[176 + 2 * o2 + 1];
            const uint4* w4 = (const uint4*)(s_tile + O_CB1 + (2 * o2) * 32);
            #pragma unroll
            for (int q = 0; q < 8; q++) a0 = dot4(w4[q], cpp + 4 * q, a0);
            #pragma unroll
            for (int q = 0; q < 8; q++) a1 = dot4(w4[8 + q], cpp + 4 * q, a1);
            c1[o2] = packh2(fmaxf(a0, 0.f), fmaxf(a1, 0.f));
        }
        // cmd L2 (128->64 relu)
        unsigned int resc[32];
        #pragma unroll
        for (int o2 = 0; o2 < 32; o2++) {
            float a0 = bias[304 + 2 * o2], a1 = bias[304 + 2 * o2 + 1];
            const uint4* w4 = (const uint4*)(s_tile + O_CB2 + (2 * o2) * 64);
            #pragma unroll
            for (int q = 0; q < 16; q++) a0 = dot4(w4[q], c1 + 4 * q, a0);
            #pragma unroll
            for (int q = 0; q < 16; q++) a1 = dot4(w4[16 + q], c1 + 4 * q, a1);
            resc[o2] = packh2(fmaxf(a0, 0.f), fmaxf(a1, 0.f));
        }
        // pilot input pack
        unsigned int inp[12];
        {
            const float* sp = self_obs + row * 15;
            const float* cp = cp_obs + row * 6;
            #pragma unroll
            for (int m = 0; m < 12; m++) {
                int k0 = 2 * m, k1 = k0 + 1;
                float a = (k0 < 15) ? sp[k0] : ((k0 < 21) ? cp[k0 - 15] : 0.f);
                float c = (k1 < 15) ? sp[k1] : ((k1 < 21) ? cp[k1 - 15] : 0.f);
                inp[m] = packh2(a, c);
            }
        }
        // pilot L1 (21->64 relu)
        unsigned int r1p[32];
        #pragma unroll
        for (int o2 = 0; o2 < 32; o2++) {
            float a0 = bias[2 * o2], a1 = bias[2 * o2 + 1];
            const uint4* w4 = (const uint4*)(s_tile + O_PE1 + (2 * o2) * 12);
            #pragma unroll
            for (int q = 0; q < 3; q++) a0 = dot4(w4[q], inp + 4 * q, a0);
            #pragma unroll
            for (int q = 0; q < 3; q++) a1 = dot4(w4[3 + q], inp + 4 * q, a1);
            r1p[o2] = packh2(fmaxf(a0, 0.f), fmaxf(a1, 0.f));
        }
        // pilot L2 (64->64 relu)
        unsigned int resp[32];
        #pragma unroll
        for (int o2 = 0; o2 < 32; o2++) {
            float a0 = bias[64 + 2 * o2], a1 = bias[64 + 2 * o2 + 1];
            const uint4* w4 = (const uint4*)(s_tile + O_PE2 + (2 * o2) * 32);
            #pragma unroll
            for (int q = 0; q < 8; q++) a0 = dot4(w4[q], r1p + 4 * q, a0);
            #pragma unroll
            for (int q = 0; q < 8; q++) a1 = dot4(w4[8 + q], r1p + 4 * q, a1);
            resp[o2] = packh2(fmaxf(a0, 0.f), fmaxf(a1, 0.f));
        }
        __syncthreads();
        uint4* rt4 = reinterpret_cast<uint4*>(s_tile + t * 64);
        #pragma unroll
        for (int q = 0; q < 8; q++)
            rt4[q] = make_uint4(resp[4 * q], resp[4 * q + 1], resp[4 * q + 2], resp[4 * q + 3]);
        #pragma unroll
        for (int q = 0; q < 8; q++)
            rt4[8 + q] = make_uint4(resc[4 * q], resc[4 * q + 1], resc[4 * q + 2], resc[4 * q + 3]);
    }
    __syncthreads();
    {
        const uint4* st4 = reinterpret_cast<const uint4*>(s_tile);
        uint4* xg4 = reinterpret_cast<uint4*>(Xg + (long long)b * Sn * 64);
        #pragma unroll
        for (int rep = 0; rep < 16; rep++) {
            int i = rep * 256 + t;
            xg4[i] = st4[i];
        }
    }
}

// ================= k2: 8-wave MFMA LSTM, chunked staging, no shuffles =================
__global__ __launch_bounds__(512) void k2_lstm(
    const float* __restrict__ ih_w, const float* __restrict__ ih_b,
    const float* __restrict__ hh_w, const float* __restrict__ hh_b,
    const unsigned int* __restrict__ Xg, unsigned short* __restrict__ hseq,
    float* __restrict__ out)
{
    __shared__ __align__(16) unsigned short s_x[2][4][16][136];  // 34 KB: X dbuf, 4 steps/chunk
    __shared__ __align__(16) unsigned short s_h[16][72];         // h (rows 8-15 stay zero)
    __shared__ __align__(16) float s_g[8][256];                  // raw gates per step

    const int t = threadIdx.x;
    const int bb = blockIdx.x;        // batch rows 8bb..8bb+7
    const int l = t & 63;
    const int w = t >> 6;             // wave 0..7

    {   // zero s_x (both buffers) and s_h
        unsigned int* z = (unsigned int*)&s_x[0][0][0][0];
        for (int i = t; i < 8704; i += 512) z[i] = 0;
        unsigned int* z2 = (unsigned int*)&s_h[0][0];
        for (int i = t; i < 576; i += 512) z2[i] = 0;
    }

    // B-fragments: wave w owns gate-interleaved cols [32w, 32w+32) (col = 4u+gt)
    const int kof = (l >> 4) * 8;
    half8 bx[2][4], bh[2][2];
    float biasv[2];
    #pragma unroll
    for (int ct = 0; ct < 2; ct++) {
        const int col = w * 32 + ct * 16 + (l & 15);
        const int origc = (col & 3) * 64 + (col >> 2);
        #pragma unroll
        for (int kt = 0; kt < 4; kt++) {
            half8 v;
            #pragma unroll
            for (int j = 0; j < 8; j++) v[j] = (_Float16)ih_w[(kt * 32 + kof + j) * 256 + origc];
            bx[ct][kt] = v;
        }
        #pragma unroll
        for (int kt = 0; kt < 2; kt++) {
            half8 v;
            #pragma unroll
            for (int j = 0; j < 8; j++) v[j] = (_Float16)hh_w[(kt * 32 + kof + j) * 256 + origc];
            bh[ct][kt] = v;
        }
        biasv[ct] = ih_b[origc] + hh_b[origc];
    }

    // chunk staging mapping: 512 thr x uint4 = 8 KB = 4 steps x 8 rows x 256 B
    const int sl_ld = t >> 7;          // 0..3
    const int r_ld = (t >> 4) & 7;     // 0..7
    const int seg = t & 15;            // 0..15
    const long long gb0 = (long long)bb * 8;
    uint4 p;

    __syncthreads();  // zeros visible
    {   // chunk 0: load + write
        const unsigned int* src = Xg + ((gb0 + r_ld) * Sn + sl_ld) * 64 + seg * 4;
        p = *(const uint4*)src;
        *(uint4*)((unsigned int*)&s_x[0][sl_ld][r_ld][0] + seg * 4) = p;
    }
    __syncthreads();
    {   // chunk 1: load into regs
        const unsigned int* src = Xg + ((gb0 + r_ld) * Sn + (4 + sl_ld)) * 64 + seg * 4;
        p = *(const uint4*)src;
    }

    const int uq = t & 63;   // update-thread unit
    const int rq = t >> 6;   // update-thread row (0..7)
    const int arow = l & 15;
    float cst = 0.f, hst = 0.f;

    #pragma unroll 1
    for (int c = 0; c < 64; c++) {
        const int buf = c & 1;
        #pragma unroll 1
        for (int sl = 0; sl < 4; sl++) {
            // A-fragments
            half8 xa0 = *(const half8*)&s_x[buf][sl][arow][kof];
            half8 xa1 = *(const half8*)&s_x[buf][sl][arow][32 + kof];
            half8 xa2 = *(const half8*)&s_x[buf][sl][arow][64 + kof];
            half8 xa3 = *(const half8*)&s_x[buf][sl][arow][96 + kof];
            half8 hA0 = *(const half8*)&s_h[arow][kof];
            half8 hA1 = *(const half8*)&s_h[arow][32 + kof];
            // gates = X@Wih + h@Whh + b (raw)
            floatx4 acc0 = {biasv[0], biasv[0], biasv[0], biasv[0]};
            floatx4 acc1 = {biasv[1], biasv[1], biasv[1], biasv[1]};
            acc0 = __builtin_amdgcn_mfma_f32_16x16x32_f16(xa0, bx[0][0], acc0, 0, 0, 0);
            acc1 = __builtin_amdgcn_mfma_f32_16x16x32_f16(xa0, bx[1][0], acc1, 0, 0, 0);
            acc0 = __builtin_amdgcn_mfma_f32_16x16x32_f16(xa1, bx[0][1], acc0, 0, 0, 0);
            acc1 = __builtin_amdgcn_mfma_f32_16x16x32_f16(xa1, bx[1][1], acc1, 0, 0, 0);
            acc0 = __builtin_amdgcn_mfma_f32_16x16x32_f16(xa2, bx[0][2], acc0, 0, 0, 0);
            acc1 = __builtin_amdgcn_mfma_f32_16x16x32_f16(xa2, bx[1][2], acc1, 0, 0, 0);
            acc0 = __builtin_amdgcn_mfma_f32_16x16x32_f16(xa3, bx[0][3], acc0, 0, 0, 0);
            acc1 = __builtin_amdgcn_mfma_f32_16x16x32_f16(xa3, bx[1][3], acc1, 0, 0, 0);
            acc0 = __builtin_amdgcn_mfma_f32_16x16x32_f16(hA0, bh[0][0], acc0, 0, 0, 0);
            acc1 = __builtin_amdgcn_mfma_f32_16x16x32_f16(hA0, bh[1][0], acc1, 0, 0, 0);
            acc0 = __builtin_amdgcn_mfma_f32_16x16x32_f16(hA1, bh[0][1], acc0, 0, 0, 0);
            acc1 = __builtin_amdgcn_mfma_f32_16x16x32_f16(hA1, bh[1][1], acc1, 0, 0, 0);
            // raw gates -> s_g (rows 0..7 live in lanes l>>4 < 2)
            if ((l >> 4) < 2) {
                const int rbase = (l >> 4) * 4;
                const int c0 = w * 32 + (l & 15);
                #pragma unroll
                for (int rr = 0; rr < 4; rr++) s_g[rbase + rr][c0] = acc0[rr];
                #pragma unroll
                for (int rr = 0; rr < 4; rr++) s_g[rbase + rr][c0 + 16] = acc1[rr];
            }
            __syncthreads();
            // cell update: thread (uq, rq) owns one (unit, row)
            {
                const float4 gv = *(const float4*)&s_g[rq][4 * uq];  // i,f,g,o
                float i_ = sigmoidf_(gv.x), f_ = sigmoidf_(gv.y);
                float g_ = tanhf_(gv.z), o_ = sigmoidf_(gv.w);
                cst = f_ * cst + i_ * g_;
                hst = o_ * tanhf_(cst);
                unsigned short h16 = f2h16(hst);
                s_h[rq][uq] = h16;
                hseq[((gb0 + rq) * Sn + (c * 4 + sl)) * 64 + uq] = h16;
            }
            if (sl == 3 && c < 63)
                *(uint4*)((unsigned int*)&s_x[buf ^ 1][sl_ld][r_ld][0] + seg * 4) = p;
            __syncthreads();
        }
        if (c < 62) {   // issue loads for chunk c+2 (in flight across all of chunk c+1)
            const unsigned int* src = Xg + ((gb0 + r_ld) * Sn + ((c + 2) * 4 + sl_ld)) * 64 + seg * 4;
            p = *(const uint4*)src;
        }
    }
    // hn / cn
    float* hn = out + 8 * BSn;
    float* cn = hn + (long long)Bn * 64;
    hn[(gb0 + rq) * 64 + uq] = hst;
    cn[(gb0 + rq) * 64 + uq] = cst;
}

// ================= k4: heads (MFMA over hseq) + std fill =================
__global__ __launch_bounds__(256) void k4_heads(
    const unsigned short* __restrict__ hseq,
    const float* __restrict__ th_w, const float* __restrict__ th_b,
    const float* __restrict__ an_w, const float* __restrict__ an_b,
    const float* __restrict__ sh_w, const float* __restrict__ sh_b,
    const float* __restrict__ bo_w, const float* __restrict__ bo_b,
    const float* __restrict__ logstd, float* __restrict__ out)
{
    const int t = threadIdx.x, l = t & 63, w = t >> 6;
    const long long row0 = (long long)blockIdx.x * 64 + w * 16;
    const int hc = l & 15;
    const int kof = (l >> 4) * 8;
    half8 bhd0, bhd1;
    #pragma unroll
    for (int kt = 0; kt < 2; kt++) {
        half8 v;
        #pragma unroll
        for (int j = 0; j < 8; j++) {
            int k = kt * 32 + kof + j;
            float wv = 0.f;
            if (hc == 0) wv = th_w[k];
            else if (hc == 1) wv = an_w[k];
            else if (hc == 2) wv = sh_w[2 * k];
            else if (hc == 3) wv = sh_w[2 * k + 1];
            else if (hc == 4) wv = bo_w[2 * k];
            else if (hc == 5) wv = bo_w[2 * k + 1];
            v[j] = (_Float16)wv;
        }
        if (kt == 0) bhd0 = v; else bhd1 = v;
    }
    float bias = 0.f;
    if (hc == 0) bias = th_b[0];
    else if (hc == 1) bias = an_b[0];
    else if (hc == 2) bias = sh_b[0];
    else if (hc == 3) bias = sh_b[1];
    else if (hc == 4) bias = bo_b[0];
    else if (hc == 5) bias = bo_b[1];
    const unsigned short* hp = hseq + (row0 + (l & 15)) * 64;
    half8 a0 = *(const half8*)(hp + kof);
    half8 a1 = *(const half8*)(hp + 32 + kof);
    floatx4 acc = {bias, bias, bias, bias};
    acc = __builtin_amdgcn_mfma_f32_16x16x32_f16(a0, bhd0, acc, 0, 0, 0);
    acc = __builtin_amdgcn_mfma_f32_16x16x32_f16(a1, bhd1, acc, 0, 0, 0);
    float s0 = fmaxf(__expf(logstd[0]), 0.05f);
    float s1 = fmaxf(__expf(logstd[1]), 0.05f);
    #pragma unroll
    for (int rr = 0; rr < 4; rr++) {
        long long row = row0 + (l >> 4) * 4 + rr;
        float v = acc[rr];
        if (hc == 0)      out[row] = sigmoidf_(v);
        else if (hc == 1) out[BSn + row] = tanhf_(v);
        else if (hc == 2) out[4 * BSn + 2 * row] = v;
        else if (hc == 3) out[4 * BSn + 2 * row + 1] = v;
        else if (hc == 4) out[6 * BSn + 2 * row] = v;
        else if (hc == 5) out[6 * BSn + 2 * row + 1] = v;
        else if (hc == 6) out[2 * BSn + 2 * row] = s0;
        else if (hc == 7) out[2 * BSn + 2 * row + 1] = s1;
    }
}

// ================= fallback: monolithic (R3 structure, proven @1454us) =================
__global__ __launch_bounds__(256)
void k_fallback(
    const float* __restrict__ self_obs, const float* __restrict__ tm_obs,
    const float* __restrict__ en_obs, const float* __restrict__ cp_obs,
    const int* __restrict__ role_ids,
    const float* __restrict__ pe_w1, const float* __restrict__ pe_b1,
    const float* __restrict__ pe_w2, const float* __restrict__ pe_b2,
    const float* __restrict__ role_emb,
    const float* __restrict__ ee_w1, const float* __restrict__ ee_b1,
    const float* __restrict__ ee_w2, const float* __restrict__ ee_b2,
    const float* __restrict__ cb_w1, const float* __restrict__ cb_b1,
    const float* __restrict__ cb_w2, const float* __restrict__ cb_b2,
    const float* __restrict__ ih_w, const float* __restrict__ ih_b,
    const float* __restrict__ hh_w, const float* __restrict__ hh_b,
    const float* __restrict__ th_w, const float* __restrict__ th_b,
    const float* __restrict__ an_w, const float* __restrict__ an_b,
    const float* __restrict__ sh_w, const float* __restrict__ sh_b,
    const float* __restrict__ bo_w, const float* __restrict__ bo_b,
    const float* __restrict__ logstd, float* __restrict__ out)
{
    __shared__ __align__(16) unsigned int s_tile[Sn * 64];
    __shared__ __align__(16) unsigned int s_h32[32];
    __shared__ float s_g[192];
    __shared__ unsigned int s_hw[192];
    __shared__ float s_hb[8];

    const int t = threadIdx.x;
    const int b = blockIdx.x;

    for (int i = t; i < 768; i += 256) {
        int o = i / 12, m = i % 12, k0 = 2 * m, k1 = k0 + 1;
        float a = (k0 < 21) ? pe_w1[k0 * 64 + o] : 0.f;
        float c = (k1 < 21) ? pe_w1[k1 * 64 + o] : 0.f;
        s_tile[O_PE1 + i] = packh2(a, c);
    }
    for (int i = t; i < 2048; i += 256) {
        int o = i >> 5, m = i & 31;
        s_tile[O_PE2 + i] = packh2(pe_w2[(2 * m) * 64 + o], pe_w2[(2 * m + 1) * 64 + o]);
    }
    {
        int i = t;
        int o = i >> 3, m = i & 7, k0 = 2 * m, k1 = k0 + 1;
        float a = (k0 < 13) ? ee_w1[k0 * 32 + o] : 0.f;
        float c = (k1 < 13) ? ee_w1[k1 * 32 + o] : 0.f;
        s_tile[O_EE1 + i] = packh2(a, c);
    }
    {
        int i = t;
        int o = i >> 4, m = i & 15;
        s_tile[O_EE2 + i] = packh2(ee_w2[(2 * m) * 16 + o], ee_w2[(2 * m + 1) * 16 + o]);
    }
    for (int i = t; i < 4096; i += 256) {
        int o = i >> 5, m = i & 31, k0 = 2 * m, k1 = k0 + 1;
        float a = (k0 < 63) ? cb_w1[k0 * 128 + o] : 0.f;
        float c = (k1 < 63) ? cb_w1[k1 * 128 + o] : 0.f;
        s_tile[O_CB1 + i] = packh2(a, c);
    }
    for (int i = t; i < 4096; i += 256) {
        int o = i >> 6, m = i & 63;
        s_tile[O_CB2 + i] = packh2(cb_w2[(2 * m) * 64 + o], cb_w2[(2 * m + 1) * 64 + o]);
    }
    float* bias = (float*)(s_tile + O_BIAS);
    if (t < 64) bias[t] = pe_b1[t];
    if (t < 64) bias[64 + t] = pe_b2[t];
    if (t < 32) bias[128 + t] = ee_b1[t];
    if (t < 16) bias[160 + t] = ee_b2[t];
    if (t < 128) bias[176 + t] = cb_b1[t];
    if (t < 64) bias[304 + t] = cb_b2[t];
    if (t < 32) bias[368 + t] = role_emb[t];
    if (t < 32)        s_hw[t]        = packh2(th_w[2 * t], th_w[2 * t + 1]);
    else if (t < 64)  { int m = t - 32;  s_hw[32 + m]  = packh2(an_w[2 * m], an_w[2 * m + 1]); }
    else if (t < 96)  { int m = t - 64;  s_hw[64 + m]  = packh2(sh_w[4 * m], sh_w[4 * m + 2]); }
    else if (t < 128) { int m = t - 96;  s_hw[96 + m]  = packh2(sh_w[4 * m + 1], sh_w[4 * m + 3]); }
    else if (t < 160) { int m = t - 128; s_hw[128 + m] = packh2(bo_w[4 * m], bo_w[4 * m + 2]); }
    else if (t < 192) { int m = t - 160; s_hw[160 + m] = packh2(bo_w[4 * m + 1], bo_w[4 * m + 3]); }
    if (t == 0) {
        s_hb[0] = th_b[0]; s_hb[1] = an_b[0];
        s_hb[2] = sh_b[0]; s_hb[3] = sh_b[1];
        s_hb[4] = bo_b[0]; s_hb[5] = bo_b[1];
        s_hb[6] = fmaxf(__expf(logstd[0]), 0.05f);
        s_hb[7] = fmaxf(__expf(logstd[1]), 0.05f);
    }
    if (t < 32) s_h32[t] = 0u;
    __syncthreads();

    {
        const long long row = (long long)b * Sn + t;
        float lat[32];
        #pragma unroll 1
        for (int src = 0; src < 3; src++) {
            const float* xp = (src == 0) ? (tm_obs + row * 13) : (en_obs + row * 26 + (src - 1) * 13);
            unsigned int xpr[8];
            #pragma unroll
            for (int m = 0; m < 8; m++) {
                int k0 = 2 * m, k1 = k0 + 1;
                xpr[m] = packh2((k0 < 13) ? xp[k0] : 0.f, (k1 < 13) ? xp[k1] : 0.f);
            }
            unsigned int e1[16];
            #pragma unroll
            for (int o2 = 0; o2 < 16; o2++) {
                float a0 = bias[128 + 2 * o2], a1 = bias[128 + 2 * o2 + 1];
                const unsigned int* w0 = s_tile + O_EE1 + (2 * o2) * 8;
                #pragma unroll
                for (int m = 0; m < 8; m++) { a0 = dot2(xpr[m], w0[m], a0); a1 = dot2(xpr[m], w0[8 + m], a1); }
                e1[o2] = packh2(fmaxf(a0, 0.f), fmaxf(a1, 0.f));
            }
            #pragma unroll
            for (int o = 0; o < 16; o++) {
                float a0 = bias[160 + o];
                const unsigned int* w0 = s_tile + O_EE2 + o * 16;
                #pragma unroll
                for (int m = 0; m < 16; m++) a0 = dot2(e1[m], w0[m], a0);
                if (src == 0) lat[o] = a0;
                else if (src == 1) lat[16 + o] = a0;
                else lat[16 + o] = fmaxf(lat[16 + o], a0);
            }
        }
        unsigned int cpp[32];
        {
            const float* sp = self_obs + row * 15;
            const int rid = role_ids[row];
            const float* rvec = bias + 368 + rid * 16;
            #pragma unroll
            for (int m = 0; m < 32; m++) {
                int k0 = 2 * m, k1 = k0 + 1;
                float a = (k0 < 15) ? sp[k0] : (k0 < 31) ? lat[k0 - 15] : (k0 < 47) ? lat[16 + k0 - 31] : rvec[k0 - 47];
                float c = (k1 < 15) ? sp[k1] : (k1 < 31) ? lat[k1 - 15] : (k1 < 47) ? lat[16 + k1 - 31]
                                                                       : (k1 < 63) ? rvec[k1 - 47] : 0.f;
                cpp[m] = packh2(a, c);
            }
        }
        unsigned int c1[64];
        #pragma unroll
        for (int o2 = 0; o2 < 64; o2++) {
            float a0 = bias[176 + 2 * o2], a1 = bias[176 + 2 * o2 + 1];
            const unsigned int* w0 = s_tile + O_CB1 + (2 * o2) * 32;
            #pragma unroll
            for (int m = 0; m < 32; m++) { a0 = dot2(cpp[m], w0[m], a0); a1 = dot2(cpp[m], w0[32 + m], a1); }
            c1[o2] = packh2(fmaxf(a0, 0.f), fmaxf(a1, 0.f));
        }
        unsigned int resc[32];
        #pragma unroll
        for (int o2 = 0; o2 < 32; o2++) {
            float a0 = bias[304 + 2 * o2], a1 = bias[304 + 2 * o2 + 1];
            const unsigned int* w0 = s_tile + O_CB2 + (2 * o2) * 64;
            #pragma unroll
            for (int m = 0; m < 64; m++) { a0 = dot2(c1[m], w0[m], a0); a1 = dot2(c1[m], w0[64 + m], a1); }
            resc[o2] = packh2(fmaxf(a0, 0.f), fmaxf(a1, 0.f));
        }
        unsigned int inp[12];
        {
            const float* sp = self_obs + row * 15;
            const float* cp = cp_obs + row * 6;
            #pragma unroll
            for (int m = 0; m < 12; m++) {
                int k0 = 2 * m, k1 = k0 + 1;
                float a = (k0 < 15) ? sp[k0] : ((k0 < 21) ? cp[k0 - 15] : 0.f);
                float c = (k1 < 15) ? sp[k1] : ((k1 < 21) ? cp[k1 - 15] : 0.f);
                inp[m] = packh2(a, c);
            }
        }
        unsigned int r1p[32];
        #pragma unroll
        for (int o2 = 0; o2 < 32; o2++) {
            float a0 = bias[2 * o2], a1 = bias[2 * o2 + 1];
            const unsigned int* w0 = s_tile + O_PE1 + (2 * o2) * 12;
            #pragma unroll
            for (int m = 0; m < 12; m++) { a0 = dot2(inp[m], w0[m], a0); a1 = dot2(inp[m], w0[12 + m], a1); }
            r1p[o2] = packh2(fmaxf(a0, 0.f), fmaxf(a1, 0.f));
        }
        unsigned int resp[32];
        #pragma unroll
        for (int o2 = 0; o2 < 32; o2++) {
            float a0 = bias[64 + 2 * o2], a1 = bias[64 + 2 * o2 + 1];
            const unsigned int* w0 = s_tile + O_PE2 + (2 * o2) * 32;
            #pragma unroll
            for (int m = 0; m < 32; m++) { a0 = dot2(r1p[m], w0[m], a0); a1 = dot2(r1p[m], w0[32 + m], a1); }
            resp[o2] = packh2(fmaxf(a0, 0.f), fmaxf(a1, 0.f));
        }
        __syncthreads();
        uint4* rt4 = reinterpret_cast<uint4*>(s_tile + t * 64);
        #pragma unroll
        for (int q = 0; q < 8; q++)
            rt4[q] = make_uint4(resp[4 * q], resp[4 * q + 1], resp[4 * q + 2], resp[4 * q + 3]);
        #pragma unroll
        for (int q = 0; q < 8; q++)
            rt4[8 + q] = make_uint4(resc[4 * q], resc[4 * q + 1], resc[4 * q + 2], resc[4 * q + 3]);
    }

    unsigned int wih[64], whh[32];
    #pragma unroll
    for (int m = 0; m < 64; m++) wih[m] = packh2(ih_w[(2 * m) * 256 + t], ih_w[(2 * m + 1) * 256 + t]);
    #pragma unroll
    for (int m = 0; m < 32; m++) whh[m] = packh2(hh_w[(2 * m) * 256 + t], hh_w[(2 * m + 1) * 256 + t]);
    const float bias_t = ih_b[t] + hh_b[t];
    __syncthreads();

    const int grp = t >> 6;
    const int u = t & 63;
    float c = 0.f, h = 0.f, i_act = 0.f;
    #pragma unroll 1
    for (int s = 0; s < Sn; s++) {
        float acc = bias_t;
        const uint4* rq = reinterpret_cast<const uint4*>(s_tile + s * 64);
        #pragma unroll
        for (int q = 0; q < 16; q++) {
            uint4 rv = rq[q];
            acc = dot2(rv.x, wih[4 * q + 0], acc);
            acc = dot2(rv.y, wih[4 * q + 1], acc);
            acc = dot2(rv.z, wih[4 * q + 2], acc);
            acc = dot2(rv.w, wih[4 * q + 3], acc);
        }
        const uint4* hq = reinterpret_cast<const uint4*>(s_h32);
        #pragma unroll
        for (int q = 0; q < 8; q++) {
            uint4 hvv = hq[q];
            acc = dot2(hvv.x, whh[4 * q + 0], acc);
            acc = dot2(hvv.y, whh[4 * q + 1], acc);
            acc = dot2(hvv.z, whh[4 * q + 2], acc);
            acc = dot2(hvv.w, whh[4 * q + 3], acc);
        }
        float act = (grp == 2) ? tanhf_(acc) : sigmoidf_(acc);
        if (grp == 0) i_act = act; else s_g[t - 64] = act;
        __syncthreads();
        if (t < 64) {
            float f_ = s_g[u], g_ = s_g[64 + u], o_ = s_g[128 + u];
            c = f_ * c + i_act * g_;
            h = o_ * tanhf_(c);
            float hnext = __shfl_down(h, 1);
            if ((u & 1) == 0) {
                unsigned int hp = packh2(h, hnext);
                s_h32[u >> 1] = hp;
                s_tile[s * 64 + (((u >> 1) + s) & 31)] = hp;
            }
        }
        __syncthreads();
    }
    {
        const int w = t >> 6, lq = t & 63;
        const int m0 = (lq & 7) * 4;
        const int j0 = lq & 7;
        #pragma unroll 1
        for (int p = 0; p < 8; p++) {
            int s = w * 64 + p * 8 + (lq >> 3);
            float ath = 0.f, aan = 0.f, as0 = 0.f, as1 = 0.f, ab0 = 0.f, ab1 = 0.f;
            #pragma unroll
            for (int j = 0; j < 4; j++) {
                int m = m0 + j;
                unsigned int hvv = s_tile[s * 64 + ((m + s) & 31)];
                ath = dot2(hvv, s_hw[m], ath);
                aan = dot2(hvv, s_hw[32 + m], aan);
                as0 = dot2(hvv, s_hw[64 + m], as0);
                as1 = dot2(hvv, s_hw[96 + m], as1);
                ab0 = dot2(hvv, s_hw[128 + m], ab0);
                ab1 = dot2(hvv, s_hw[160 + m], ab1);
            }
            #pragma unroll
            for (int d = 1; d < 8; d <<= 1) {
                ath += __shfl_xor(ath, d); aan += __shfl_xor(aan, d);
                as0 += __shfl_xor(as0, d); as1 += __shfl_xor(as1, d);
                ab0 += __shfl_xor(ab0, d); ab1 += __shfl_xor(ab1, d);
            }
            long long row = (long long)b * Sn + s;
            if (j0 == 0)      out[row] = sigmoidf_(ath + s_hb[0]);
            else if (j0 == 1) out[BSn + row] = tanhf_(aan + s_hb[1]);
            else if (j0 == 2) out[2 * BSn + 2 * row] = s_hb[6];
            else if (j0 == 3) out[2 * BSn + 2 * row + 1] = s_hb[7];
            else if (j0 == 4) out[4 * BSn + 2 * row] = as0 + s_hb[2];
            else if (j0 == 5) out[4 * BSn + 2 * row + 1] = as1 + s_hb[3];
            else if (j0 == 6) out[6 * BSn + 2 * row] = ab0 + s_hb[4];
            else              out[6 * BSn + 2 * row + 1] = ab1 + s_hb[5];
        }
    }
    if (t < 64) {
        float* hn = out + 8 * BSn;
        float* cn = hn + (long long)Bn * 64;
        hn[(long long)b * 64 + u] = h;
        cn[(long long)b * 64 + u] = c;
    }
}

// ================= host =================
extern "C" void kernel_launch(void* const* d_in, const int* in_sizes, int n_in,
                              void* d_out, int out_size, void* d_ws, size_t ws_size,
                              hipStream_t stream)
{
    (void)in_sizes; (void)n_in; (void)out_size;
    float* out = (float*)d_out;
    const size_t X_BYTES = (size_t)BSn * 64 * 4;  // 134 MB (f16 pairs as u32)
    const size_t H_BYTES = (size_t)BSn * 64 * 2;  // 67 MB hseq f16

    if (d_ws != nullptr && ws_size >= X_BYTES + H_BYTES) {
        unsigned int* Xg = (unsigned int*)d_ws;
        unsigned short* hseq = (unsigned short*)((char*)d_ws + X_BYTES);
        k1_encode<<<Bn, 256, 0, stream>>>(
            (const float*)d_in[0], (const float*)d_in[1], (const float*)d_in[2],
            (const float*)d_in[3], (const int*)d_in[4],
            (const float*)d_in[5], (const float*)d_in[6], (const float*)d_in[7], (const float*)d_in[8],
            (const float*)d_in[9],
            (const float*)d_in[10], (const float*)d_in[11], (const float*)d_in[12], (const float*)d_in[13],
            (const float*)d_in[14], (const float*)d_in[15], (const float*)d_in[16], (const float*)d_in[17],
            Xg);
        k2_lstm<<<Bn / 8, 512, 0, stream>>>(
            (const float*)d_in[18], (const float*)d_in[19], (const float*)d_in[20], (const float*)d_in[21],
            Xg, hseq, out);
        k4_heads<<<(int)(BSn / 64), 256, 0, stream>>>(
            hseq,
            (const float*)d_in[22], (const float*)d_in[23], (const float*)d_in[24], (const float*)d_in[25],
            (const float*)d_in[26], (const float*)d_in[27], (const float*)d_in[28], (const float*)d_in[29],
            (const float*)d_in[30], out);
    } else {
        k_fallback<<<Bn, 256, 0, stream>>>(
            (const float*)d_in[0], (const float*)d_in[1], (const float*)d_in[2],
            (const float*)d_in[3], (const int*)d_in[4],
            (const float*)d_in[5], (const float*)d_in[6], (const float*)d_in[7], (const float*)d_in[8],
            (const float*)d_in[9],
            (const float*)d_in[10], (const float*)d_in[11], (const float*)d_in[12], (const float*)d_in[13],
            (const float*)d_in[14], (const float*)d_in[15], (const float*)d_in[16], (const float*)d_in[17],
            (const float*)d_in[18], (const float*)d_in[19], (const float*)d_in[20], (const float*)d_in[21],
            (const float*)d_in[22], (const float*)d_in[23], (const float*)d_in[24], (const float*)d_in[25],
            (const float*)d_in[26], (const float*)d_in[27], (const float*)d_in[28], (const float*)d_in[29],
            (const float*)d_in[30], out);
    }
}

// Round 10
// 485.348 us; speedup vs baseline: 13.1871x; 2.1606x over previous
//
#include <hip/hip_runtime.h>
#include <hip/hip_fp16.h>

#define DEVINL __device__ __forceinline__

static constexpr int Bn = 2048;
static constexpr int Sn = 256;
static constexpr long long BSn = (long long)Bn * Sn;  // 524288

typedef _Float16 h2v __attribute__((ext_vector_type(2)));
typedef _Float16 half8 __attribute__((ext_vector_type(8)));
typedef float floatx4 __attribute__((ext_vector_type(4)));

DEVINL float dot2(unsigned int a, unsigned int b, float c) {
#if __has_builtin(__builtin_amdgcn_fdot2)
    return __builtin_amdgcn_fdot2(__builtin_bit_cast(h2v, a), __builtin_bit_cast(h2v, b), c, false);
#else
    __half2 ha = __builtin_bit_cast(__half2, a);
    __half2 hb = __builtin_bit_cast(__half2, b);
    return c + __low2float(ha) * __low2float(hb) + __high2float(ha) * __high2float(hb);
#endif
}
DEVINL unsigned int packh2(float a, float b) {
    __half2 h = __floats2half2_rn(a, b);
    return __builtin_bit_cast(unsigned int, h);
}
DEVINL unsigned short f2h16(float f) { return __builtin_bit_cast(unsigned short, (_Float16)f); }
DEVINL float sigmoidf_(float x) { return 1.0f / (1.0f + __expf(-x)); }
DEVINL float tanhf_(float x) { return 2.0f / (1.0f + __expf(-2.0f * x)) - 1.0f; }

// ================= k1: MFMA encoders -> X[BS][128] f16 =================
// 64 rows/block. LDS carve (bytes):
//   0      s_ew   entity weights (592 u32 = 2368)
//   2368   s_cin  [64][72] f16 cmd input      (9216)
//   11584  s_pin  [64][40] f16 pilot input    (5120)
//   16704  s_mid  [64][136] f16 L1 outputs    (17408)  [overlaid by s_lat [64][3][17] f32 in phase E]
//   34112  s_xout [64][128] f16 X chunk       (16384)
//   total 50496 -> 3 blocks/CU
__global__ __launch_bounds__(256) void k1_encode(
    const float* __restrict__ self_obs, const float* __restrict__ tm_obs,
    const float* __restrict__ en_obs, const float* __restrict__ cp_obs,
    const int* __restrict__ role_ids,
    const float* __restrict__ pe_w1, const float* __restrict__ pe_b1,
    const float* __restrict__ pe_w2, const float* __restrict__ pe_b2,
    const float* __restrict__ role_emb,
    const float* __restrict__ ee_w1, const float* __restrict__ ee_b1,
    const float* __restrict__ ee_w2, const float* __restrict__ ee_b2,
    const float* __restrict__ cb_w1, const float* __restrict__ cb_b1,
    const float* __restrict__ cb_w2, const float* __restrict__ cb_b2,
    unsigned int* __restrict__ Xg)
{
    __shared__ __align__(16) unsigned char s_raw[50496];
    unsigned int* s_ew = (unsigned int*)s_raw;
    float* eb = (float*)(s_ew + 512);                       // 80 floats: ee_b1|ee_b2|role
    unsigned short* s_cin = (unsigned short*)(s_raw + 2368);
    unsigned short* s_pin = (unsigned short*)(s_raw + 11584);
    unsigned short* s_mid = (unsigned short*)(s_raw + 16704);
    unsigned short* s_xout = (unsigned short*)(s_raw + 34112);
    float* s_lat = (float*)(s_raw + 16704);                 // overlay on s_mid

    const int t = threadIdx.x;
    const int l = t & 63, w = t >> 6;
    const long long row0 = (long long)blockIdx.x * 64;

    // ---- entity weights + biases to LDS ----
    {
        int o = t >> 3, m = t & 7, k0 = 2 * m, k1 = k0 + 1;
        s_ew[t] = packh2(k0 < 13 ? ee_w1[k0 * 32 + o] : 0.f, k1 < 13 ? ee_w1[k1 * 32 + o] : 0.f);
        int o2 = t >> 4, m2 = t & 15;
        s_ew[256 + t] = packh2(ee_w2[(2 * m2) * 16 + o2], ee_w2[(2 * m2 + 1) * 16 + o2]);
    }
    if (t < 32) eb[t] = ee_b1[t];
    else if (t < 48) eb[t] = ee_b2[t - 32];
    else if (t < 80) eb[t] = role_emb[t - 48];

    // ---- B-fragments + biases in registers (k2-validated convention) ----
    const int kof = (l >> 4) * 8;
    const int c16 = w * 16 + (l & 15);
    half8 bL1[2][2], bL2[4], bP1, bP2[2];
    float bsL1[2], bsL2, bsP1, bsP2;
    #pragma unroll
    for (int ct = 0; ct < 2; ct++) {
        int col = w * 32 + ct * 16 + (l & 15);
        #pragma unroll
        for (int kt = 0; kt < 2; kt++) {
            half8 v;
            #pragma unroll
            for (int j = 0; j < 8; j++) { int k = kt * 32 + kof + j; v[j] = (k < 63) ? (_Float16)cb_w1[k * 128 + col] : (_Float16)0.f; }
            bL1[ct][kt] = v;
        }
        bsL1[ct] = cb_b1[col];
    }
    #pragma unroll
    for (int kt = 0; kt < 4; kt++) {
        half8 v;
        #pragma unroll
        for (int j = 0; j < 8; j++) v[j] = (_Float16)cb_w2[(kt * 32 + kof + j) * 64 + c16];
        bL2[kt] = v;
    }
    bsL2 = cb_b2[c16];
    {
        half8 v;
        #pragma unroll
        for (int j = 0; j < 8; j++) { int k = kof + j; v[j] = (k < 21) ? (_Float16)pe_w1[k * 64 + c16] : (_Float16)0.f; }
        bP1 = v;
        bsP1 = pe_b1[c16];
    }
    #pragma unroll
    for (int kt = 0; kt < 2; kt++) {
        half8 v;
        #pragma unroll
        for (int j = 0; j < 8; j++) v[j] = (_Float16)pe_w2[(kt * 32 + kof + j) * 64 + c16];
        bP2[kt] = v;
    }
    bsP2 = pe_b2[c16];
    __syncthreads();

    // ---- phase E: entity encoders (sub 0..2) + pilot pack (sub 3) ----
    const int r = t >> 2, sub = t & 3;
    const long long grow = row0 + r;
    float selfv[15]; int rid = 0;
    if (sub == 3) {
        const float* sp = self_obs + grow * 15;
        #pragma unroll
        for (int k = 0; k < 15; k++) selfv[k] = sp[k];
        rid = role_ids[grow];
        float cpv[6];
        const float* cp = cp_obs + grow * 6;
        #pragma unroll
        for (int k = 0; k < 6; k++) cpv[k] = cp[k];
        unsigned int* prow = (unsigned int*)(s_pin + r * 40);
        #pragma unroll
        for (int m = 0; m < 16; m++) {
            int k0 = 2 * m, k1 = k0 + 1;
            float a = (k0 < 15) ? selfv[k0] : (k0 < 21 ? cpv[k0 - 15] : 0.f);
            float c = (k1 < 15) ? selfv[k1] : (k1 < 21 ? cpv[k1 - 15] : 0.f);
            prow[m] = packh2(a, c);
        }
    } else {
        const float* xp = (sub == 0) ? (tm_obs + grow * 13) : (en_obs + grow * 26 + (sub - 1) * 13);
        unsigned int xpr[8];
        #pragma unroll
        for (int m = 0; m < 8; m++) {
            int k0 = 2 * m, k1 = k0 + 1;
            xpr[m] = packh2(k0 < 13 ? xp[k0] : 0.f, k1 < 13 ? xp[k1] : 0.f);
        }
        unsigned int e1[16];
        #pragma unroll
        for (int o2 = 0; o2 < 16; o2++) {
            float a0 = eb[2 * o2], a1 = eb[2 * o2 + 1];
            const unsigned int* w0 = s_ew + (2 * o2) * 8;
            #pragma unroll
            for (int m = 0; m < 8; m++) { a0 = dot2(xpr[m], w0[m], a0); a1 = dot2(xpr[m], w0[8 + m], a1); }
            e1[o2] = packh2(fmaxf(a0, 0.f), fmaxf(a1, 0.f));
        }
        #pragma unroll
        for (int o = 0; o < 16; o++) {
            float a0 = eb[32 + o];
            const unsigned int* w0 = s_ew + 256 + o * 16;
            #pragma unroll
            for (int m = 0; m < 16; m++) a0 = dot2(e1[m], w0[m], a0);
            s_lat[(r * 3 + sub) * 17 + o] = a0;   // no relu on entity L2
        }
    }
    __syncthreads();
    if (sub == 3) {
        float latm[32];
        #pragma unroll
        for (int o = 0; o < 16; o++) latm[o] = s_lat[(r * 3) * 17 + o];
        #pragma unroll
        for (int o = 0; o < 16; o++) latm[16 + o] = fmaxf(s_lat[(r * 3 + 1) * 17 + o], s_lat[(r * 3 + 2) * 17 + o]);
        const float* rvec = eb + 48 + rid * 16;
        unsigned int* crow = (unsigned int*)(s_cin + r * 72);
        #pragma unroll
        for (int m = 0; m < 32; m++) {
            int k0 = 2 * m, k1 = k0 + 1;
            float a = (k0 < 15) ? selfv[k0] : (k0 < 31) ? latm[k0 - 15] : (k0 < 47) ? latm[16 + k0 - 31] : rvec[k0 - 47];
            float c = (k1 < 15) ? selfv[k1] : (k1 < 31) ? latm[k1 - 15] : (k1 < 47) ? latm[16 + k1 - 31]
                                                                       : (k1 < 63) ? rvec[k1 - 47] : 0.f;
            crow[m] = packh2(a, c);
        }
    }
    __syncthreads();

    const int arow = l & 15;
    const int crow0 = (l >> 4) * 4;
    // ---- G1: cmd L1 (63->128 relu) -> s_mid ----
    #pragma unroll 1
    for (int rt = 0; rt < 4; rt++) {
        half8 a0 = *(const half8*)(s_cin + (rt * 16 + arow) * 72 + kof);
        half8 a1 = *(const half8*)(s_cin + (rt * 16 + arow) * 72 + 32 + kof);
        #pragma unroll
        for (int ct = 0; ct < 2; ct++) {
            floatx4 acc = {bsL1[ct], bsL1[ct], bsL1[ct], bsL1[ct]};
            acc = __builtin_amdgcn_mfma_f32_16x16x32_f16(a0, bL1[ct][0], acc, 0, 0, 0);
            acc = __builtin_amdgcn_mfma_f32_16x16x32_f16(a1, bL1[ct][1], acc, 0, 0, 0);
            int col = w * 32 + ct * 16 + (l & 15);
            #pragma unroll
            for (int rr = 0; rr < 4; rr++)
                s_mid[(rt * 16 + crow0 + rr) * 136 + col] = f2h16(fmaxf(acc[rr], 0.f));
        }
    }
    __syncthreads();
    // ---- G2: cmd L2 (128->64 relu) -> s_xout cols 64..127 ----
    #pragma unroll 1
    for (int rt = 0; rt < 4; rt++) {
        floatx4 acc = {bsL2, bsL2, bsL2, bsL2};
        #pragma unroll
        for (int kt = 0; kt < 4; kt++) {
            half8 a = *(const half8*)(s_mid + (rt * 16 + arow) * 136 + kt * 32 + kof);
            acc = __builtin_amdgcn_mfma_f32_16x16x32_f16(a, bL2[kt], acc, 0, 0, 0);
        }
        #pragma unroll
        for (int rr = 0; rr < 4; rr++)
            s_xout[(rt * 16 + crow0 + rr) * 128 + 64 + c16] = f2h16(fmaxf(acc[rr], 0.f));
    }
    __syncthreads();
    // ---- G3: pilot L1 (21->64 relu) -> s_mid cols 0..63 ----
    #pragma unroll 1
    for (int rt = 0; rt < 4; rt++) {
        half8 a = *(const half8*)(s_pin + (rt * 16 + arow) * 40 + kof);
        floatx4 acc = {bsP1, bsP1, bsP1, bsP1};
        acc = __builtin_amdgcn_mfma_f32_16x16x32_f16(a, bP1, acc, 0, 0, 0);
        #pragma unroll
        for (int rr = 0; rr < 4; rr++)
            s_mid[(rt * 16 + crow0 + rr) * 136 + c16] = f2h16(fmaxf(acc[rr], 0.f));
    }
    __syncthreads();
    // ---- G4: pilot L2 (64->64 relu) -> s_xout cols 0..63 ----
    #pragma unroll 1
    for (int rt = 0; rt < 4; rt++) {
        floatx4 acc = {bsP2, bsP2, bsP2, bsP2};
        #pragma unroll
        for (int kt = 0; kt < 2; kt++) {
            half8 a = *(const half8*)(s_mid + (rt * 16 + arow) * 136 + kt * 32 + kof);
            acc = __builtin_amdgcn_mfma_f32_16x16x32_f16(a, bP2[kt], acc, 0, 0, 0);
        }
        #pragma unroll
        for (int rr = 0; rr < 4; rr++)
            s_xout[(rt * 16 + crow0 + rr) * 128 + c16] = f2h16(fmaxf(acc[rr], 0.f));
    }
    __syncthreads();
    // ---- coalesced copy to Xg ----
    {
        const uint4* st4 = (const uint4*)s_xout;
        uint4* xg4 = (uint4*)(Xg + row0 * 64);
        #pragma unroll
        for (int rep = 0; rep < 4; rep++) xg4[rep * 256 + t] = st4[rep * 256 + t];
    }
}

// ================= k2: 8-wave MFMA LSTM, chunked staging (R9, proven) =================
__global__ __launch_bounds__(512) void k2_lstm(
    const float* __restrict__ ih_w, const float* __restrict__ ih_b,
    const float* __restrict__ hh_w, const float* __restrict__ hh_b,
    const unsigned int* __restrict__ Xg, unsigned short* __restrict__ hseq,
    float* __restrict__ out)
{
    __shared__ __align__(16) unsigned short s_x[2][4][16][136];
    __shared__ __align__(16) unsigned short s_h[16][72];
    __shared__ __align__(16) float s_g[8][256];

    const int t = threadIdx.x;
    const int bb = blockIdx.x;
    const int l = t & 63;
    const int w = t >> 6;

    {
        unsigned int* z = (unsigned int*)&s_x[0][0][0][0];
        for (int i = t; i < 8704; i += 512) z[i] = 0;
        unsigned int* z2 = (unsigned int*)&s_h[0][0];
        for (int i = t; i < 576; i += 512) z2[i] = 0;
    }

    const int kof = (l >> 4) * 8;
    half8 bx[2][4], bh[2][2];
    float biasv[2];
    #pragma unroll
    for (int ct = 0; ct < 2; ct++) {
        const int col = w * 32 + ct * 16 + (l & 15);
        const int origc = (col & 3) * 64 + (col >> 2);
        #pragma unroll
        for (int kt = 0; kt < 4; kt++) {
            half8 v;
            #pragma unroll
            for (int j = 0; j < 8; j++) v[j] = (_Float16)ih_w[(kt * 32 + kof + j) * 256 + origc];
            bx[ct][kt] = v;
        }
        #pragma unroll
        for (int kt = 0; kt < 2; kt++) {
            half8 v;
            #pragma unroll
            for (int j = 0; j < 8; j++) v[j] = (_Float16)hh_w[(kt * 32 + kof + j) * 256 + origc];
            bh[ct][kt] = v;
        }
        biasv[ct] = ih_b[origc] + hh_b[origc];
    }

    const int sl_ld = t >> 7;
    const int r_ld = (t >> 4) & 7;
    const int seg = t & 15;
    const long long gb0 = (long long)bb * 8;
    uint4 p;

    __syncthreads();
    {
        const unsigned int* src = Xg + ((gb0 + r_ld) * Sn + sl_ld) * 64 + seg * 4;
        p = *(const uint4*)src;
        *(uint4*)((unsigned int*)&s_x[0][sl_ld][r_ld][0] + seg * 4) = p;
    }
    __syncthreads();
    {
        const unsigned int* src = Xg + ((gb0 + r_ld) * Sn + (4 + sl_ld)) * 64 + seg * 4;
        p = *(const uint4*)src;
    }

    const int uq = t & 63;
    const int rq = t >> 6;
    const int arow = l & 15;
    float cst = 0.f, hst = 0.f;

    #pragma unroll 1
    for (int c = 0; c < 64; c++) {
        const int buf = c & 1;
        #pragma unroll 1
        for (int sl = 0; sl < 4; sl++) {
            half8 xa0 = *(const half8*)&s_x[buf][sl][arow][kof];
            half8 xa1 = *(const half8*)&s_x[buf][sl][arow][32 + kof];
            half8 xa2 = *(const half8*)&s_x[buf][sl][arow][64 + kof];
            half8 xa3 = *(const half8*)&s_x[buf][sl][arow][96 + kof];
            half8 hA0 = *(const half8*)&s_h[arow][kof];
            half8 hA1 = *(const half8*)&s_h[arow][32 + kof];
            floatx4 acc0 = {biasv[0], biasv[0], biasv[0], biasv[0]};
            floatx4 acc1 = {biasv[1], biasv[1], biasv[1], biasv[1]};
            acc0 = __builtin_amdgcn_mfma_f32_16x16x32_f16(xa0, bx[0][0], acc0, 0, 0, 0);
            acc1 = __builtin_amdgcn_mfma_f32_16x16x32_f16(xa0, bx[1][0], acc1, 0, 0, 0);
            acc0 = __builtin_amdgcn_mfma_f32_16x16x32_f16(xa1, bx[0][1], acc0, 0, 0, 0);
            acc1 = __builtin_amdgcn_mfma_f32_16x16x32_f16(xa1, bx[1][1], acc1, 0, 0, 0);
            acc0 = __builtin_amdgcn_mfma_f32_16x16x32_f16(xa2, bx[0][2], acc0, 0, 0, 0);
            acc1 = __builtin_amdgcn_mfma_f32_16x16x32_f16(xa2, bx[1][2], acc1, 0, 0, 0);
            acc0 = __builtin_amdgcn_mfma_f32_16x16x32_f16(xa3, bx[0][3], acc0, 0, 0, 0);
            acc1 = __builtin_amdgcn_mfma_f32_16x16x32_f16(xa3, bx[1][3], acc1, 0, 0, 0);
            acc0 = __builtin_amdgcn_mfma_f32_16x16x32_f16(hA0, bh[0][0], acc0, 0, 0, 0);
            acc1 = __builtin_amdgcn_mfma_f32_16x16x32_f16(hA0, bh[1][0], acc1, 0, 0, 0);
            acc0 = __builtin_amdgcn_mfma_f32_16x16x32_f16(hA1, bh[0][1], acc0, 0, 0, 0);
            acc1 = __builtin_amdgcn_mfma_f32_16x16x32_f16(hA1, bh[1][1], acc1, 0, 0, 0);
            if ((l >> 4) < 2) {
                const int rbase = (l >> 4) * 4;
                const int c0 = w * 32 + (l & 15);
                #pragma unroll
                for (int rr = 0; rr < 4; rr++) s_g[rbase + rr][c0] = acc0[rr];
                #pragma unroll
                for (int rr = 0; rr < 4; rr++) s_g[rbase + rr][c0 + 16] = acc1[rr];
            }
            __syncthreads();
            {
                const float4 gv = *(const float4*)&s_g[rq][4 * uq];
                float i_ = sigmoidf_(gv.x), f_ = sigmoidf_(gv.y);
                float g_ = tanhf_(gv.z), o_ = sigmoidf_(gv.w);
                cst = f_ * cst + i_ * g_;
                hst = o_ * tanhf_(cst);
                unsigned short h16 = f2h16(hst);
                s_h[rq][uq] = h16;
                hseq[((gb0 + rq) * Sn + (c * 4 + sl)) * 64 + uq] = h16;
            }
            if (sl == 3 && c < 63)
                *(uint4*)((unsigned int*)&s_x[buf ^ 1][sl_ld][r_ld][0] + seg * 4) = p;
            __syncthreads();
        }
        if (c < 62) {
            const unsigned int* src = Xg + ((gb0 + r_ld) * Sn + ((c + 2) * 4 + sl_ld)) * 64 + seg * 4;
            p = *(const uint4*)src;
        }
    }
    float* hn = out + 8 * BSn;
    float* cn = hn + (long long)Bn * 64;
    hn[(gb0 + rq) * 64 + uq] = hst;
    cn[(gb0 + rq) * 64 + uq] = cst;
}

// ================= k4: heads (MFMA over hseq) + std fill (R9, proven) =================
__global__ __launch_bounds__(256) void k4_heads(
    const unsigned short* __restrict__ hseq,
    const float* __restrict__ th_w, const float* __restrict__ th_b,
    const float* __restrict__ an_w, const float* __restrict__ an_b,
    const float* __restrict__ sh_w, const float* __restrict__ sh_b,
    const float* __restrict__ bo_w, const float* __restrict__ bo_b,
    const float* __restrict__ logstd, float* __restrict__ out)
{
    const int t = threadIdx.x, l = t & 63, w = t >> 6;
    const long long row0 = (long long)blockIdx.x * 64 + w * 16;
    const int hc = l & 15;
    const int kof = (l >> 4) * 8;
    half8 bhd0, bhd1;
    #pragma unroll
    for (int kt = 0; kt < 2; kt++) {
        half8 v;
        #pragma unroll
        for (int j = 0; j < 8; j++) {
            int k = kt * 32 + kof + j;
            float wv = 0.f;
            if (hc == 0) wv = th_w[k];
            else if (hc == 1) wv = an_w[k];
            else if (hc == 2) wv = sh_w[2 * k];
            else if (hc == 3) wv = sh_w[2 * k + 1];
            else if (hc == 4) wv = bo_w[2 * k];
            else if (hc == 5) wv = bo_w[2 * k + 1];
            v[j] = (_Float16)wv;
        }
        if (kt == 0) bhd0 = v; else bhd1 = v;
    }
    float bias = 0.f;
    if (hc == 0) bias = th_b[0];
    else if (hc == 1) bias = an_b[0];
    else if (hc == 2) bias = sh_b[0];
    else if (hc == 3) bias = sh_b[1];
    else if (hc == 4) bias = bo_b[0];
    else if (hc == 5) bias = bo_b[1];
    const unsigned short* hp = hseq + (row0 + (l & 15)) * 64;
    half8 a0 = *(const half8*)(hp + kof);
    half8 a1 = *(const half8*)(hp + 32 + kof);
    floatx4 acc = {bias, bias, bias, bias};
    acc = __builtin_amdgcn_mfma_f32_16x16x32_f16(a0, bhd0, acc, 0, 0, 0);
    acc = __builtin_amdgcn_mfma_f32_16x16x32_f16(a1, bhd1, acc, 0, 0, 0);
    float s0 = fmaxf(__expf(logstd[0]), 0.05f);
    float s1 = fmaxf(__expf(logstd[1]), 0.05f);
    #pragma unroll
    for (int rr = 0; rr < 4; rr++) {
        long long row = row0 + (l >> 4) * 4 + rr;
        float v = acc[rr];
        if (hc == 0)      out[row] = sigmoidf_(v);
        else if (hc == 1) out[BSn + row] = tanhf_(v);
        else if (hc == 2) out[4 * BSn + 2 * row] = v;
        else if (hc == 3) out[4 * BSn + 2 * row + 1] = v;
        else if (hc == 4) out[6 * BSn + 2 * row] = v;
        else if (hc == 5) out[6 * BSn + 2 * row + 1] = v;
        else if (hc == 6) out[2 * BSn + 2 * row] = s0;
        else if (hc == 7) out[2 * BSn + 2 * row + 1] = s1;
    }
}

// ================= fallback: monolithic (R3 structure, proven @1454us) =================
enum {
    O_PE1 = 0, O_PE2 = 768, O_EE1 = 2816, O_EE2 = 3072,
    O_CB1 = 3328, O_CB2 = 7424, O_BIAS = 11520
};
__global__ __launch_bounds__(256)
void k_fallback(
    const float* __restrict__ self_obs, const float* __restrict__ tm_obs,
    const float* __restrict__ en_obs, const float* __restrict__ cp_obs,
    const int* __restrict__ role_ids,
    const float* __restrict__ pe_w1, const float* __restrict__ pe_b1,
    const float* __restrict__ pe_w2, const float* __restrict__ pe_b2,
    const float* __restrict__ role_emb,
    const float* __restrict__ ee_w1, const float* __restrict__ ee_b1,
    const float* __restrict__ ee_w2, const float* __restrict__ ee_b2,
    const float* __restrict__ cb_w1, const float* __restrict__ cb_b1,
    const float* __restrict__ cb_w2, const float* __restrict__ cb_b2,
    const float* __restrict__ ih_w, const float* __restrict__ ih_b,
    const float* __restrict__ hh_w, const float* __restrict__ hh_b,
    const float* __restrict__ th_w, const float* __restrict__ th_b,
    const float* __restrict__ an_w, const float* __restrict__ an_b,
    const float* __restrict__ sh_w, const float* __restrict__ sh_b,
    const float* __restrict__ bo_w, const float* __restrict__ bo_b,
    const float* __restrict__ logstd, float* __restrict__ out)
{
    __shared__ __align__(16) unsigned int s_tile[Sn * 64];
    __shared__ __align__(16) unsigned int s_h32[32];
    __shared__ float s_g[192];
    __shared__ unsigned int s_hw[192];
    __shared__ float s_hb[8];

    const int t = threadIdx.x;
    const int b = blockIdx.x;

    for (int i = t; i < 768; i += 256) {
        int o = i / 12, m = i % 12, k0 = 2 * m, k1 = k0 + 1;
        float a = (k0 < 21) ? pe_w1[k0 * 64 + o] : 0.f;
        float c = (k1 < 21) ? pe_w1[k1 * 64 + o] : 0.f;
        s_tile[O_PE1 + i] = packh2(a, c);
    }
    for (int i = t; i < 2048; i += 256) {
        int o = i >> 5, m = i & 31;
        s_tile[O_PE2 + i] = packh2(pe_w2[(2 * m) * 64 + o], pe_w2[(2 * m + 1) * 64 + o]);
    }
    {
        int i = t;
        int o = i >> 3, m = i & 7, k0 = 2 * m, k1 = k0 + 1;
        float a = (k0 < 13) ? ee_w1[k0 * 32 + o] : 0.f;
        float c = (k1 < 13) ? ee_w1[k1 * 32 + o] : 0.f;
        s_tile[O_EE1 + i] = packh2(a, c);
    }
    {
        int i = t;
        int o = i >> 4, m = i & 15;
        s_tile[O_EE2 + i] = packh2(ee_w2[(2 * m) * 16 + o], ee_w2[(2 * m + 1) * 16 + o]);
    }
    for (int i = t; i < 4096; i += 256) {
        int o = i >> 5, m = i & 31, k0 = 2 * m, k1 = k0 + 1;
        float a = (k0 < 63) ? cb_w1[k0 * 128 + o] : 0.f;
        float c = (k1 < 63) ? cb_w1[k1 * 128 + o] : 0.f;
        s_tile[O_CB1 + i] = packh2(a, c);
    }
    for (int i = t; i < 4096; i += 256) {
        int o = i >> 6, m = i & 63;
        s_tile[O_CB2 + i] = packh2(cb_w2[(2 * m) * 64 + o], cb_w2[(2 * m + 1) * 64 + o]);
    }
    float* bias = (float*)(s_tile + O_BIAS);
    if (t < 64) bias[t] = pe_b1[t];
    if (t < 64) bias[64 + t] = pe_b2[t];
    if (t < 32) bias[128 + t] = ee_b1[t];
    if (t < 16) bias[160 + t] = ee_b2[t];
    if (t < 128) bias[176 + t] = cb_b1[t];
    if (t < 64) bias[304 + t] = cb_b2[t];
    if (t < 32) bias[368 + t] = role_emb[t];
    if (t < 32)        s_hw[t]        = packh2(th_w[2 * t], th_w[2 * t + 1]);
    else if (t < 64)  { int m = t - 32;  s_hw[32 + m]  = packh2(an_w[2 * m], an_w[2 * m + 1]); }
    else if (t < 96)  { int m = t - 64;  s_hw[64 + m]  = packh2(sh_w[4 * m], sh_w[4 * m + 2]); }
    else if (t < 128) { int m = t - 96;  s_hw[96 + m]  = packh2(sh_w[4 * m + 1], sh_w[4 * m + 3]); }
    else if (t < 160) { int m = t - 128; s_hw[128 + m] = packh2(bo_w[4 * m], bo_w[4 * m + 2]); }
    else if (t < 192) { int m = t - 160; s_hw[160 + m] = packh2(bo_w[4 * m + 1], bo_w[4 * m + 3]); }
    if (t == 0) {
        s_hb[0] = th_b[0]; s_hb[1] = an_b[0];
        s_hb[2] = sh_b[0]; s_hb[3] = sh_b[1];
        s_hb[4] = bo_b[0]; s_hb[5] = bo_b[1];
        s_hb[6] = fmaxf(__expf(logstd[0]), 0.05f);
        s_hb[7] = fmaxf(__expf(logstd[1]), 0.05f);
    }
    if (t < 32) s_h32[t] = 0u;
    __syncthreads();

    {
        const long long row = (long long)b * Sn + t;
        float lat[32];
        #pragma unroll 1
        for (int src = 0; src < 3; src++) {
            const float* xp = (src == 0) ? (tm_obs + row * 13) : (en_obs + row * 26 + (src - 1) * 13);
            unsigned int xpr[8];
            #pragma unroll
            for (int m = 0; m < 8; m++) {
                int k0 = 2 * m, k1 = k0 + 1;
                xpr[m] = packh2((k0 < 13) ? xp[k0] : 0.f, (k1 < 13) ? xp[k1] : 0.f);
            }
            unsigned int e1[16];
            #pragma unroll
            for (int o2 = 0; o2 < 16; o2++) {
                float a0 = bias[128 + 2 * o2], a1 = bias[128 + 2 * o2 + 1];
                const unsigned int* w0 = s_tile + O_EE1 + (2 * o2) * 8;
                #pragma unroll
                for (int m = 0; m < 8; m++) { a0 = dot2(xpr[m], w0[m], a0); a1 = dot2(xpr[m], w0[8 + m], a1); }
                e1[o2] = packh2(fmaxf(a0, 0.f), fmaxf(a1, 0.f));
            }
            #pragma unroll
            for (int o = 0; o < 16; o++) {
                float a0 = bias[160 + o];
                const unsigned int* w0 = s_tile + O_EE2 + o * 16;
                #pragma unroll
                for (int m = 0; m < 16; m++) a0 = dot2(e1[m], w0[m], a0);
                if (src == 0) lat[o] = a0;
                else if (src == 1) lat[16 + o] = a0;
                else lat[16 + o] = fmaxf(lat[16 + o], a0);
            }
        }
        unsigned int cpp[32];
        {
            const float* sp = self_obs + row * 15;
            const int rid = role_ids[row];
            const float* rvec = bias + 368 + rid * 16;
            #pragma unroll
            for (int m = 0; m < 32; m++) {
                int k0 = 2 * m, k1 = k0 + 1;
                float a = (k0 < 15) ? sp[k0] : (k0 < 31) ? lat[k0 - 15] : (k0 < 47) ? lat[16 + k0 - 31] : rvec[k0 - 47];
                float c = (k1 < 15) ? sp[k1] : (k1 < 31) ? lat[k1 - 15] : (k1 < 47) ? lat[16 + k1 - 31]
                                                                       : (k1 < 63) ? rvec[k1 - 47] : 0.f;
                cpp[m] = packh2(a, c);
            }
        }
        unsigned int c1[64];
        #pragma unroll
        for (int o2 = 0; o2 < 64; o2++) {
            float a0 = bias[176 + 2 * o2], a1 = bias[176 + 2 * o2 + 1];
            const unsigned int* w0 = s_tile + O_CB1 + (2 * o2) * 32;
            #pragma unroll
            for (int m = 0; m < 32; m++) { a0 = dot2(cpp[m], w0[m], a0); a1 = dot2(cpp[m], w0[32 + m], a1); }
            c1[o2] = packh2(fmaxf(a0, 0.f), fmaxf(a1, 0.f));
        }
        unsigned int resc[32];
        #pragma unroll
        for (int o2 = 0; o2 < 32; o2++) {
            float a0 = bias[304 + 2 * o2], a1 = bias[304 + 2 * o2 + 1];
            const unsigned int* w0 = s_tile + O_CB2 + (2 * o2) * 64;
            #pragma unroll
            for (int m = 0; m < 64; m++) { a0 = dot2(c1[m], w0[m], a0); a1 = dot2(c1[m], w0[64 + m], a1); }
            resc[o2] = packh2(fmaxf(a0, 0.f), fmaxf(a1, 0.f));
        }
        unsigned int inp[12];
        {
            const float* sp = self_obs + row * 15;
            const float* cp = cp_obs + row * 6;
            #pragma unroll
            for (int m = 0; m < 12; m++) {
                int k0 = 2 * m, k1 = k0 + 1;
                float a = (k0 < 15) ? sp[k0] : ((k0 < 21) ? cp[k0 - 15] : 0.f);
                float c = (k1 < 15) ? sp[k1] : ((k1 < 21) ? cp[k1 - 15] : 0.f);
                inp[m] = packh2(a, c);
            }
        }
        unsigned int r1p[32];
        #pragma unroll
        for (int o2 = 0; o2 < 32; o2++) {
            float a0 = bias[2 * o2], a1 = bias[2 * o2 + 1];
            const unsigned int* w0 = s_tile + O_PE1 + (2 * o2) * 12;
            #pragma unroll
            for (int m = 0; m < 12; m++) { a0 = dot2(inp[m], w0[m], a0); a1 = dot2(inp[m], w0[12 + m], a1); }
            r1p[o2] = packh2(fmaxf(a0, 0.f), fmaxf(a1, 0.f));
        }
        unsigned int resp[32];
        #pragma unroll
        for (int o2 = 0; o2 < 32; o2++) {
            float a0 = bias[64 + 2 * o2], a1 = bias[64 + 2 * o2 + 1];
            const unsigned int* w0 = s_tile + O_PE2 + (2 * o2) * 32;
            #pragma unroll
            for (int m = 0; m < 32; m++) { a0 = dot2(r1p[m], w0[m], a0); a1 = dot2(r1p[m], w0[32 + m], a1); }
            resp[o2] = packh2(fmaxf(a0, 0.f), fmaxf(a1, 0.f));
        }
        __syncthreads();
        uint4* rt4 = reinterpret_cast<uint4*>(s_tile + t * 64);
        #pragma unroll
        for (int q = 0; q < 8; q++)
            rt4[q] = make_uint4(resp[4 * q], resp[4 * q + 1], resp[4 * q + 2], resp[4 * q + 3]);
        #pragma unroll
        for (int q = 0; q < 8; q++)
            rt4[8 + q] = make_uint4(resc[4 * q], resc[4 * q + 1], resc[4 * q + 2], resc[4 * q + 3]);
    }

    unsigned int wih[64], whh[32];
    #pragma unroll
    for (int m = 0; m < 64; m++) wih[m] = packh2(ih_w[(2 * m) * 256 + t], ih_w[(2 * m + 1) * 256 + t]);
    #pragma unroll
    for (int m = 0; m < 32; m++) whh[m] = packh2(hh_w[(2 * m) * 256 + t], hh_w[(2 * m + 1) * 256 + t]);
    const float bias_t = ih_b[t] + hh_b[t];
    __syncthreads();

    const int grp = t >> 6;
    const int u = t & 63;
    float c = 0.f, h = 0.f, i_act = 0.f;
    #pragma unroll 1
    for (int s = 0; s < Sn; s++) {
        float acc = bias_t;
        const uint4* rq = reinterpret_cast<const uint4*>(s_tile + s * 64);
        #pragma unroll
        for (int q = 0; q < 16; q++) {
            uint4 rv = rq[q];
            acc = dot2(rv.x, wih[4 * q + 0], acc);
            acc = dot2(rv.y, wih[4 * q + 1], acc);
            acc = dot2(rv.z, wih[4 * q + 2], acc);
            acc = dot2(rv.w, wih[4 * q + 3], acc);
        }
        const uint4* hq = reinterpret_cast<const uint4*>(s_h32);
        #pragma unroll
        for (int q = 0; q < 8; q++) {
            uint4 hvv = hq[q];
            acc = dot2(hvv.x, whh[4 * q + 0], acc);
            acc = dot2(hvv.y, whh[4 * q + 1], acc);
            acc = dot2(hvv.z, whh[4 * q + 2], acc);
            acc = dot2(hvv.w, whh[4 * q + 3], acc);
        }
        float act = (grp == 2) ? tanhf_(acc) : sigmoidf_(acc);
        if (grp == 0) i_act = act; else s_g[t - 64] = act;
        __syncthreads();
        if (t < 64) {
            float f_ = s_g[u], g_ = s_g[64 + u], o_ = s_g[128 + u];
            c = f_ * c + i_act * g_;
            h = o_ * tanhf_(c);
            float hnext = __shfl_down(h, 1);
            if ((u & 1) == 0) {
                unsigned int hp = packh2(h, hnext);
                s_h32[u >> 1] = hp;
                s_tile[s * 64 + (((u >> 1) + s) & 31)] = hp;
            }
        }
        __syncthreads();
    }
    {
        const int w = t >> 6, lq = t & 63;
        const int m0 = (lq & 7) * 4;
        const int j0 = lq & 7;
        #pragma unroll 1
        for (int p = 0; p < 8; p++) {
            int s = w * 64 + p * 8 + (lq >> 3);
            float ath = 0.f, aan = 0.f, as0 = 0.f, as1 = 0.f, ab0 = 0.f, ab1 = 0.f;
            #pragma unroll
            for (int j = 0; j < 4; j++) {
                int m = m0 + j;
                unsigned int hvv = s_tile[s * 64 + ((m + s) & 31)];
                ath = dot2(hvv, s_hw[m], ath);
                aan = dot2(hvv, s_hw[32 + m], aan);
                as0 = dot2(hvv, s_hw[64 + m], as0);
                as1 = dot2(hvv, s_hw[96 + m], as1);
                ab0 = dot2(hvv, s_hw[128 + m], ab0);
                ab1 = dot2(hvv, s_hw[160 + m], ab1);
            }
            #pragma unroll
            for (int d = 1; d < 8; d <<= 1) {
                ath += __shfl_xor(ath, d); aan += __shfl_xor(aan, d);
                as0 += __shfl_xor(as0, d); as1 += __shfl_xor(as1, d);
                ab0 += __shfl_xor(ab0, d); ab1 += __shfl_xor(ab1, d);
            }
            long long row = (long long)b * Sn + s;
            if (j0 == 0)      out[row] = sigmoidf_(ath + s_hb[0]);
            else if (j0 == 1) out[BSn + row] = tanhf_(aan + s_hb[1]);
            else if (j0 == 2) out[2 * BSn + 2 * row] = s_hb[6];
            else if (j0 == 3) out[2 * BSn + 2 * row + 1] = s_hb[7];
            else if (j0 == 4) out[4 * BSn + 2 * row] = as0 + s_hb[2];
            else if (j0 == 5) out[4 * BSn + 2 * row + 1] = as1 + s_hb[3];
            else if (j0 == 6) out[6 * BSn + 2 * row] = ab0 + s_hb[4];
            else              out[6 * BSn + 2 * row + 1] = ab1 + s_hb[5];
        }
    }
    if (t < 64) {
        float* hn = out + 8 * BSn;
        float* cn = hn + (long long)Bn * 64;
        hn[(long long)b * 64 + u] = h;
        cn[(long long)b * 64 + u] = c;
    }
}

// ================= host =================
extern "C" void kernel_launch(void* const* d_in, const int* in_sizes, int n_in,
                              void* d_out, int out_size, void* d_ws, size_t ws_size,
                              hipStream_t stream)
{
    (void)in_sizes; (void)n_in; (void)out_size;
    float* out = (float*)d_out;
    const size_t X_BYTES = (size_t)BSn * 64 * 4;  // 134 MB (f16 pairs as u32)
    const size_t H_BYTES = (size_t)BSn * 64 * 2;  // 67 MB hseq f16

    if (d_ws != nullptr && ws_size >= X_BYTES + H_BYTES) {
        unsigned int* Xg = (unsigned int*)d_ws;
        unsigned short* hseq = (unsigned short*)((char*)d_ws + X_BYTES);
        k1_encode<<<(int)(BSn / 64), 256, 0, stream>>>(
            (const float*)d_in[0], (const float*)d_in[1], (const float*)d_in[2],
            (const float*)d_in[3], (const int*)d_in[4],
            (const float*)d_in[5], (const float*)d_in[6], (const float*)d_in[7], (const float*)d_in[8],
            (const float*)d_in[9],
            (const float*)d_in[10], (const float*)d_in[11], (const float*)d_in[12], (const float*)d_in[13],
            (const float*)d_in[14], (const float*)d_in[15], (const float*)d_in[16], (const float*)d_in[17],
            Xg);
        k2_lstm<<<Bn / 8, 512, 0, stream>>>(
            (const float*)d_in[18], (const float*)d_in[19], (const float*)d_in[20], (const float*)d_in[21],
            Xg, hseq, out);
        k4_heads<<<(int)(BSn / 64), 256, 0, stream>>>(
            hseq,
            (const float*)d_in[22], (const float*)d_in[23], (const float*)d_in[24], (const float*)d_in[25],
            (const float*)d_in[26], (const float*)d_in[27], (const float*)d_in[28], (const float*)d_in[29],
            (const float*)d_in[30], out);
    } else {
        k_fallback<<<Bn, 256, 0, stream>>>(
            (const float*)d_in[0], (const float*)d_in[1], (const float*)d_in[2],
            (const float*)d_in[3], (const int*)d_in[4],
            (const float*)d_in[5], (const float*)d_in[6], (const float*)d_in[7], (const float*)d_in[8],
            (const float*)d_in[9],
            (const float*)d_in[10], (const float*)d_in[11], (const float*)d_in[12], (const float*)d_in[13],
            (const float*)d_in[14], (const float*)d_in[15], (const float*)d_in[16], (const float*)d_in[17],
            (const float*)d_in[18], (const float*)d_in[19], (const float*)d_in[20], (const float*)d_in[21],
            (const float*)d_in[22], (const float*)d_in[23], (const float*)d_in[24], (const float*)d_in[25],
            (const float*)d_in[26], (const float*)d_in[27], (const float*)d_in[28], (const float*)d_in[29],
            (const float*)d_in[30], out);
    }
}

// Round 11
// 460.622 us; speedup vs baseline: 13.8949x; 1.0537x over previous
//
#include <hip/hip_runtime.h>
#include <hip/hip_fp16.h>

#define DEVINL __device__ __forceinline__

static constexpr int Bn = 2048;
static constexpr int Sn = 256;
static constexpr long long BSn = (long long)Bn * Sn;  // 524288

typedef _Float16 h2v __attribute__((ext_vector_type(2)));
typedef _Float16 half8 __attribute__((ext_vector_type(8)));
typedef float floatx4 __attribute__((ext_vector_type(4)));

DEVINL float dot2(unsigned int a, unsigned int b, float c) {
#if __has_builtin(__builtin_amdgcn_fdot2)
    return __builtin_amdgcn_fdot2(__builtin_bit_cast(h2v, a), __builtin_bit_cast(h2v, b), c, false);
#else
    __half2 ha = __builtin_bit_cast(__half2, a);
    __half2 hb = __builtin_bit_cast(__half2, b);
    return c + __low2float(ha) * __low2float(hb) + __high2float(ha) * __high2float(hb);
#endif
}
DEVINL unsigned int packh2(float a, float b) {
    __half2 h = __floats2half2_rn(a, b);
    return __builtin_bit_cast(unsigned int, h);
}
DEVINL unsigned short f2h16(float f) { return __builtin_bit_cast(unsigned short, (_Float16)f); }
DEVINL float sigmoidf_(float x) { return 1.0f / (1.0f + __expf(-x)); }
DEVINL float tanhf_(float x) { return 2.0f / (1.0f + __expf(-2.0f * x)) - 1.0f; }

// ================= k1: MFMA encoders -> X[BS][128] f16 (R10, proven) =================
__global__ __launch_bounds__(256) void k1_encode(
    const float* __restrict__ self_obs, const float* __restrict__ tm_obs,
    const float* __restrict__ en_obs, const float* __restrict__ cp_obs,
    const int* __restrict__ role_ids,
    const float* __restrict__ pe_w1, const float* __restrict__ pe_b1,
    const float* __restrict__ pe_w2, const float* __restrict__ pe_b2,
    const float* __restrict__ role_emb,
    const float* __restrict__ ee_w1, const float* __restrict__ ee_b1,
    const float* __restrict__ ee_w2, const float* __restrict__ ee_b2,
    const float* __restrict__ cb_w1, const float* __restrict__ cb_b1,
    const float* __restrict__ cb_w2, const float* __restrict__ cb_b2,
    unsigned int* __restrict__ Xg)
{
    __shared__ __align__(16) unsigned char s_raw[50496];
    unsigned int* s_ew = (unsigned int*)s_raw;
    float* eb = (float*)(s_ew + 512);
    unsigned short* s_cin = (unsigned short*)(s_raw + 2368);
    unsigned short* s_pin = (unsigned short*)(s_raw + 11584);
    unsigned short* s_mid = (unsigned short*)(s_raw + 16704);
    unsigned short* s_xout = (unsigned short*)(s_raw + 34112);
    float* s_lat = (float*)(s_raw + 16704);

    const int t = threadIdx.x;
    const int l = t & 63, w = t >> 6;
    const long long row0 = (long long)blockIdx.x * 64;

    {
        int o = t >> 3, m = t & 7, k0 = 2 * m, k1 = k0 + 1;
        s_ew[t] = packh2(k0 < 13 ? ee_w1[k0 * 32 + o] : 0.f, k1 < 13 ? ee_w1[k1 * 32 + o] : 0.f);
        int o2 = t >> 4, m2 = t & 15;
        s_ew[256 + t] = packh2(ee_w2[(2 * m2) * 16 + o2], ee_w2[(2 * m2 + 1) * 16 + o2]);
    }
    if (t < 32) eb[t] = ee_b1[t];
    else if (t < 48) eb[t] = ee_b2[t - 32];
    else if (t < 80) eb[t] = role_emb[t - 48];

    const int kof = (l >> 4) * 8;
    const int c16 = w * 16 + (l & 15);
    half8 bL1[2][2], bL2[4], bP1, bP2[2];
    float bsL1[2], bsL2, bsP1, bsP2;
    #pragma unroll
    for (int ct = 0; ct < 2; ct++) {
        int col = w * 32 + ct * 16 + (l & 15);
        #pragma unroll
        for (int kt = 0; kt < 2; kt++) {
            half8 v;
            #pragma unroll
            for (int j = 0; j < 8; j++) { int k = kt * 32 + kof + j; v[j] = (k < 63) ? (_Float16)cb_w1[k * 128 + col] : (_Float16)0.f; }
            bL1[ct][kt] = v;
        }
        bsL1[ct] = cb_b1[col];
    }
    #pragma unroll
    for (int kt = 0; kt < 4; kt++) {
        half8 v;
        #pragma unroll
        for (int j = 0; j < 8; j++) v[j] = (_Float16)cb_w2[(kt * 32 + kof + j) * 64 + c16];
        bL2[kt] = v;
    }
    bsL2 = cb_b2[c16];
    {
        half8 v;
        #pragma unroll
        for (int j = 0; j < 8; j++) { int k = kof + j; v[j] = (k < 21) ? (_Float16)pe_w1[k * 64 + c16] : (_Float16)0.f; }
        bP1 = v;
        bsP1 = pe_b1[c16];
    }
    #pragma unroll
    for (int kt = 0; kt < 2; kt++) {
        half8 v;
        #pragma unroll
        for (int j = 0; j < 8; j++) v[j] = (_Float16)pe_w2[(kt * 32 + kof + j) * 64 + c16];
        bP2[kt] = v;
    }
    bsP2 = pe_b2[c16];
    __syncthreads();

    const int r = t >> 2, sub = t & 3;
    const long long grow = row0 + r;
    float selfv[15]; int rid = 0;
    if (sub == 3) {
        const float* sp = self_obs + grow * 15;
        #pragma unroll
        for (int k = 0; k < 15; k++) selfv[k] = sp[k];
        rid = role_ids[grow];
        float cpv[6];
        const float* cp = cp_obs + grow * 6;
        #pragma unroll
        for (int k = 0; k < 6; k++) cpv[k] = cp[k];
        unsigned int* prow = (unsigned int*)(s_pin + r * 40);
        #pragma unroll
        for (int m = 0; m < 16; m++) {
            int k0 = 2 * m, k1 = k0 + 1;
            float a = (k0 < 15) ? selfv[k0] : (k0 < 21 ? cpv[k0 - 15] : 0.f);
            float c = (k1 < 15) ? selfv[k1] : (k1 < 21 ? cpv[k1 - 15] : 0.f);
            prow[m] = packh2(a, c);
        }
    } else {
        const float* xp = (sub == 0) ? (tm_obs + grow * 13) : (en_obs + grow * 26 + (sub - 1) * 13);
        unsigned int xpr[8];
        #pragma unroll
        for (int m = 0; m < 8; m++) {
            int k0 = 2 * m, k1 = k0 + 1;
            xpr[m] = packh2(k0 < 13 ? xp[k0] : 0.f, k1 < 13 ? xp[k1] : 0.f);
        }
        unsigned int e1[16];
        #pragma unroll
        for (int o2 = 0; o2 < 16; o2++) {
            float a0 = eb[2 * o2], a1 = eb[2 * o2 + 1];
            const unsigned int* w0 = s_ew + (2 * o2) * 8;
            #pragma unroll
            for (int m = 0; m < 8; m++) { a0 = dot2(xpr[m], w0[m], a0); a1 = dot2(xpr[m], w0[8 + m], a1); }
            e1[o2] = packh2(fmaxf(a0, 0.f), fmaxf(a1, 0.f));
        }
        #pragma unroll
        for (int o = 0; o < 16; o++) {
            float a0 = eb[32 + o];
            const unsigned int* w0 = s_ew + 256 + o * 16;
            #pragma unroll
            for (int m = 0; m < 16; m++) a0 = dot2(e1[m], w0[m], a0);
            s_lat[(r * 3 + sub) * 17 + o] = a0;
        }
    }
    __syncthreads();
    if (sub == 3) {
        float latm[32];
        #pragma unroll
        for (int o = 0; o < 16; o++) latm[o] = s_lat[(r * 3) * 17 + o];
        #pragma unroll
        for (int o = 0; o < 16; o++) latm[16 + o] = fmaxf(s_lat[(r * 3 + 1) * 17 + o], s_lat[(r * 3 + 2) * 17 + o]);
        const float* rvec = eb + 48 + rid * 16;
        unsigned int* crow = (unsigned int*)(s_cin + r * 72);
        #pragma unroll
        for (int m = 0; m < 32; m++) {
            int k0 = 2 * m, k1 = k0 + 1;
            float a = (k0 < 15) ? selfv[k0] : (k0 < 31) ? latm[k0 - 15] : (k0 < 47) ? latm[16 + k0 - 31] : rvec[k0 - 47];
            float c = (k1 < 15) ? selfv[k1] : (k1 < 31) ? latm[k1 - 15] : (k1 < 47) ? latm[16 + k1 - 31]
                                                                       : (k1 < 63) ? rvec[k1 - 47] : 0.f;
            crow[m] = packh2(a, c);
        }
    }
    __syncthreads();

    const int arow = l & 15;
    const int crow0 = (l >> 4) * 4;
    #pragma unroll 1
    for (int rt = 0; rt < 4; rt++) {
        half8 a0 = *(const half8*)(s_cin + (rt * 16 + arow) * 72 + kof);
        half8 a1 = *(const half8*)(s_cin + (rt * 16 + arow) * 72 + 32 + kof);
        #pragma unroll
        for (int ct = 0; ct < 2; ct++) {
            floatx4 acc = {bsL1[ct], bsL1[ct], bsL1[ct], bsL1[ct]};
            acc = __builtin_amdgcn_mfma_f32_16x16x32_f16(a0, bL1[ct][0], acc, 0, 0, 0);
            acc = __builtin_amdgcn_mfma_f32_16x16x32_f16(a1, bL1[ct][1], acc, 0, 0, 0);
            int col = w * 32 + ct * 16 + (l & 15);
            #pragma unroll
            for (int rr = 0; rr < 4; rr++)
                s_mid[(rt * 16 + crow0 + rr) * 136 + col] = f2h16(fmaxf(acc[rr], 0.f));
        }
    }
    __syncthreads();
    #pragma unroll 1
    for (int rt = 0; rt < 4; rt++) {
        floatx4 acc = {bsL2, bsL2, bsL2, bsL2};
        #pragma unroll
        for (int kt = 0; kt < 4; kt++) {
            half8 a = *(const half8*)(s_mid + (rt * 16 + arow) * 136 + kt * 32 + kof);
            acc = __builtin_amdgcn_mfma_f32_16x16x32_f16(a, bL2[kt], acc, 0, 0, 0);
        }
        #pragma unroll
        for (int rr = 0; rr < 4; rr++)
            s_xout[(rt * 16 + crow0 + rr) * 128 + 64 + c16] = f2h16(fmaxf(acc[rr], 0.f));
    }
    __syncthreads();
    #pragma unroll 1
    for (int rt = 0; rt < 4; rt++) {
        half8 a = *(const half8*)(s_pin + (rt * 16 + arow) * 40 + kof);
        floatx4 acc = {bsP1, bsP1, bsP1, bsP1};
        acc = __builtin_amdgcn_mfma_f32_16x16x32_f16(a, bP1, acc, 0, 0, 0);
        #pragma unroll
        for (int rr = 0; rr < 4; rr++)
            s_mid[(rt * 16 + crow0 + rr) * 136 + c16] = f2h16(fmaxf(acc[rr], 0.f));
    }
    __syncthreads();
    #pragma unroll 1
    for (int rt = 0; rt < 4; rt++) {
        floatx4 acc = {bsP2, bsP2, bsP2, bsP2};
        #pragma unroll
        for (int kt = 0; kt < 2; kt++) {
            half8 a = *(const half8*)(s_mid + (rt * 16 + arow) * 136 + kt * 32 + kof);
            acc = __builtin_amdgcn_mfma_f32_16x16x32_f16(a, bP2[kt], acc, 0, 0, 0);
        }
        #pragma unroll
        for (int rr = 0; rr < 4; rr++)
            s_xout[(rt * 16 + crow0 + rr) * 128 + c16] = f2h16(fmaxf(acc[rr], 0.f));
    }
    __syncthreads();
    {
        const uint4* st4 = (const uint4*)s_xout;
        uint4* xg4 = (uint4*)(Xg + row0 * 64);
        #pragma unroll
        for (int rep = 0; rep < 4; rep++) xg4[rep * 256 + t] = st4[rep * 256 + t];
    }
}

// ================= k2: MFMA LSTM — batched x-MFMAs per chunk, short serial window =================
__global__ __launch_bounds__(512) void k2_lstm(
    const float* __restrict__ ih_w, const float* __restrict__ ih_b,
    const float* __restrict__ hh_w, const float* __restrict__ hh_b,
    const unsigned int* __restrict__ Xg, unsigned short* __restrict__ hseq,
    float* __restrict__ out)
{
    __shared__ __align__(16) unsigned short s_x[2][4][16][136];
    __shared__ __align__(16) unsigned short s_h[16][72];
    __shared__ __align__(16) float s_g[8][256];

    const int t = threadIdx.x;
    const int bb = blockIdx.x;
    const int l = t & 63;
    const int w = t >> 6;

    {
        unsigned int* z = (unsigned int*)&s_x[0][0][0][0];
        for (int i = t; i < 8704; i += 512) z[i] = 0;
        unsigned int* z2 = (unsigned int*)&s_h[0][0];
        for (int i = t; i < 576; i += 512) z2[i] = 0;
    }

    const int kof = (l >> 4) * 8;
    half8 bx[2][4], bh[2][2];
    float biasv[2];
    #pragma unroll
    for (int ct = 0; ct < 2; ct++) {
        const int col = w * 32 + ct * 16 + (l & 15);
        const int origc = (col & 3) * 64 + (col >> 2);
        #pragma unroll
        for (int kt = 0; kt < 4; kt++) {
            half8 v;
            #pragma unroll
            for (int j = 0; j < 8; j++) v[j] = (_Float16)ih_w[(kt * 32 + kof + j) * 256 + origc];
            bx[ct][kt] = v;
        }
        #pragma unroll
        for (int kt = 0; kt < 2; kt++) {
            half8 v;
            #pragma unroll
            for (int j = 0; j < 8; j++) v[j] = (_Float16)hh_w[(kt * 32 + kof + j) * 256 + origc];
            bh[ct][kt] = v;
        }
        biasv[ct] = ih_b[origc] + hh_b[origc];
    }

    const int sl_ld = t >> 7;
    const int r_ld = (t >> 4) & 7;
    const int seg = t & 15;
    const long long gb0 = (long long)bb * 8;
    uint4 p;

    __syncthreads();
    {
        const unsigned int* src = Xg + ((gb0 + r_ld) * Sn + sl_ld) * 64 + seg * 4;
        p = *(const uint4*)src;
        *(uint4*)((unsigned int*)&s_x[0][sl_ld][r_ld][0] + seg * 4) = p;
    }
    __syncthreads();
    {
        const unsigned int* src = Xg + ((gb0 + r_ld) * Sn + (4 + sl_ld)) * 64 + seg * 4;
        p = *(const uint4*)src;
    }

    const int uq = t & 63;
    const int rq = t >> 6;
    const int arow = l & 15;
    float cst = 0.f, hst = 0.f;

    #pragma unroll 1
    for (int c = 0; c < 64; c++) {
        const int buf = c & 1;
        // ---- batched x-part: 32 independent MFMAs for the 4 steps of this chunk ----
        floatx4 wxa[4][2];
        #pragma unroll
        for (int sl = 0; sl < 4; sl++) {
            half8 xa0 = *(const half8*)&s_x[buf][sl][arow][kof];
            half8 xa1 = *(const half8*)&s_x[buf][sl][arow][32 + kof];
            half8 xa2 = *(const half8*)&s_x[buf][sl][arow][64 + kof];
            half8 xa3 = *(const half8*)&s_x[buf][sl][arow][96 + kof];
            floatx4 a0 = {biasv[0], biasv[0], biasv[0], biasv[0]};
            floatx4 a1 = {biasv[1], biasv[1], biasv[1], biasv[1]};
            a0 = __builtin_amdgcn_mfma_f32_16x16x32_f16(xa0, bx[0][0], a0, 0, 0, 0);
            a1 = __builtin_amdgcn_mfma_f32_16x16x32_f16(xa0, bx[1][0], a1, 0, 0, 0);
            a0 = __builtin_amdgcn_mfma_f32_16x16x32_f16(xa1, bx[0][1], a0, 0, 0, 0);
            a1 = __builtin_amdgcn_mfma_f32_16x16x32_f16(xa1, bx[1][1], a1, 0, 0, 0);
            a0 = __builtin_amdgcn_mfma_f32_16x16x32_f16(xa2, bx[0][2], a0, 0, 0, 0);
            a1 = __builtin_amdgcn_mfma_f32_16x16x32_f16(xa2, bx[1][2], a1, 0, 0, 0);
            a0 = __builtin_amdgcn_mfma_f32_16x16x32_f16(xa3, bx[0][3], a0, 0, 0, 0);
            a1 = __builtin_amdgcn_mfma_f32_16x16x32_f16(xa3, bx[1][3], a1, 0, 0, 0);
            wxa[sl][0] = a0;
            wxa[sl][1] = a1;
        }
        // ---- serial sub-loop: only the h-dependent work between barriers ----
        #pragma unroll
        for (int sl = 0; sl < 4; sl++) {
            half8 hA0 = *(const half8*)&s_h[arow][kof];
            half8 hA1 = *(const half8*)&s_h[arow][32 + kof];
            floatx4 acc0 = wxa[sl][0];
            floatx4 acc1 = wxa[sl][1];
            acc0 = __builtin_amdgcn_mfma_f32_16x16x32_f16(hA0, bh[0][0], acc0, 0, 0, 0);
            acc1 = __builtin_amdgcn_mfma_f32_16x16x32_f16(hA0, bh[1][0], acc1, 0, 0, 0);
            acc0 = __builtin_amdgcn_mfma_f32_16x16x32_f16(hA1, bh[0][1], acc0, 0, 0, 0);
            acc1 = __builtin_amdgcn_mfma_f32_16x16x32_f16(hA1, bh[1][1], acc1, 0, 0, 0);
            if ((l >> 4) < 2) {
                const int rbase = (l >> 4) * 4;
                const int c0 = w * 32 + (l & 15);
                #pragma unroll
                for (int rr = 0; rr < 4; rr++) s_g[rbase + rr][c0] = acc0[rr];
                #pragma unroll
                for (int rr = 0; rr < 4; rr++) s_g[rbase + rr][c0 + 16] = acc1[rr];
            }
            __syncthreads();
            {
                const float4 gv = *(const float4*)&s_g[rq][4 * uq];
                float i_ = sigmoidf_(gv.x), f_ = sigmoidf_(gv.y);
                float g_ = tanhf_(gv.z), o_ = sigmoidf_(gv.w);
                cst = f_ * cst + i_ * g_;
                hst = o_ * tanhf_(cst);
                unsigned short h16 = f2h16(hst);
                s_h[rq][uq] = h16;
                hseq[((gb0 + rq) * Sn + (c * 4 + sl)) * 64 + uq] = h16;
            }
            if (sl == 3 && c < 63)
                *(uint4*)((unsigned int*)&s_x[buf ^ 1][sl_ld][r_ld][0] + seg * 4) = p;
            __syncthreads();
        }
        if (c < 62) {
            const unsigned int* src = Xg + ((gb0 + r_ld) * Sn + ((c + 2) * 4 + sl_ld)) * 64 + seg * 4;
            p = *(const uint4*)src;
        }
    }
    float* hn = out + 8 * BSn;
    float* cn = hn + (long long)Bn * 64;
    hn[(gb0 + rq) * 64 + uq] = hst;
    cn[(gb0 + rq) * 64 + uq] = cst;
}

// ================= k4: heads (MFMA over hseq) + std fill (R9, proven) =================
__global__ __launch_bounds__(256) void k4_heads(
    const unsigned short* __restrict__ hseq,
    const float* __restrict__ th_w, const float* __restrict__ th_b,
    const float* __restrict__ an_w, const float* __restrict__ an_b,
    const float* __restrict__ sh_w, const float* __restrict__ sh_b,
    const float* __restrict__ bo_w, const float* __restrict__ bo_b,
    const float* __restrict__ logstd, float* __restrict__ out)
{
    const int t = threadIdx.x, l = t & 63, w = t >> 6;
    const long long row0 = (long long)blockIdx.x * 64 + w * 16;
    const int hc = l & 15;
    const int kof = (l >> 4) * 8;
    half8 bhd0, bhd1;
    #pragma unroll
    for (int kt = 0; kt < 2; kt++) {
        half8 v;
        #pragma unroll
        for (int j = 0; j < 8; j++) {
            int k = kt * 32 + kof + j;
            float wv = 0.f;
            if (hc == 0) wv = th_w[k];
            else if (hc == 1) wv = an_w[k];
            else if (hc == 2) wv = sh_w[2 * k];
            else if (hc == 3) wv = sh_w[2 * k + 1];
            else if (hc == 4) wv = bo_w[2 * k];
            else if (hc == 5) wv = bo_w[2 * k + 1];
            v[j] = (_Float16)wv;
        }
        if (kt == 0) bhd0 = v; else bhd1 = v;
    }
    float bias = 0.f;
    if (hc == 0) bias = th_b[0];
    else if (hc == 1) bias = an_b[0];
    else if (hc == 2) bias = sh_b[0];
    else if (hc == 3) bias = sh_b[1];
    else if (hc == 4) bias = bo_b[0];
    else if (hc == 5) bias = bo_b[1];
    const unsigned short* hp = hseq + (row0 + (l & 15)) * 64;
    half8 a0 = *(const half8*)(hp + kof);
    half8 a1 = *(const half8*)(hp + 32 + kof);
    floatx4 acc = {bias, bias, bias, bias};
    acc = __builtin_amdgcn_mfma_f32_16x16x32_f16(a0, bhd0, acc, 0, 0, 0);
    acc = __builtin_amdgcn_mfma_f32_16x16x32_f16(a1, bhd1, acc, 0, 0, 0);
    float s0 = fmaxf(__expf(logstd[0]), 0.05f);
    float s1 = fmaxf(__expf(logstd[1]), 0.05f);
    #pragma unroll
    for (int rr = 0; rr < 4; rr++) {
        long long row = row0 + (l >> 4) * 4 + rr;
        float v = acc[rr];
        if (hc == 0)      out[row] = sigmoidf_(v);
        else if (hc == 1) out[BSn + row] = tanhf_(v);
        else if (hc == 2) out[4 * BSn + 2 * row] = v;
        else if (hc == 3) out[4 * BSn + 2 * row + 1] = v;
        else if (hc == 4) out[6 * BSn + 2 * row] = v;
        else if (hc == 5) out[6 * BSn + 2 * row + 1] = v;
        else if (hc == 6) out[2 * BSn + 2 * row] = s0;
        else if (hc == 7) out[2 * BSn + 2 * row + 1] = s1;
    }
}

// ================= fallback: monolithic (R3 structure, proven @1454us) =================
enum {
    O_PE1 = 0, O_PE2 = 768, O_EE1 = 2816, O_EE2 = 3072,
    O_CB1 = 3328, O_CB2 = 7424, O_BIAS = 11520
};
__global__ __launch_bounds__(256)
void k_fallback(
    const float* __restrict__ self_obs, const float* __restrict__ tm_obs,
    const float* __restrict__ en_obs, const float* __restrict__ cp_obs,
    const int* __restrict__ role_ids,
    const float* __restrict__ pe_w1, const float* __restrict__ pe_b1,
    const float* __restrict__ pe_w2, const float* __restrict__ pe_b2,
    const float* __restrict__ role_emb,
    const float* __restrict__ ee_w1, const float* __restrict__ ee_b1,
    const float* __restrict__ ee_w2, const float* __restrict__ ee_b2,
    const float* __restrict__ cb_w1, const float* __restrict__ cb_b1,
    const float* __restrict__ cb_w2, const float* __restrict__ cb_b2,
    const float* __restrict__ ih_w, const float* __restrict__ ih_b,
    const float* __restrict__ hh_w, const float* __restrict__ hh_b,
    const float* __restrict__ th_w, const float* __restrict__ th_b,
    const float* __restrict__ an_w, const float* __restrict__ an_b,
    const float* __restrict__ sh_w, const float* __restrict__ sh_b,
    const float* __restrict__ bo_w, const float* __restrict__ bo_b,
    const float* __restrict__ logstd, float* __restrict__ out)
{
    __shared__ __align__(16) unsigned int s_tile[Sn * 64];
    __shared__ __align__(16) unsigned int s_h32[32];
    __shared__ float s_g[192];
    __shared__ unsigned int s_hw[192];
    __shared__ float s_hb[8];

    const int t = threadIdx.x;
    const int b = blockIdx.x;

    for (int i = t; i < 768; i += 256) {
        int o = i / 12, m = i % 12, k0 = 2 * m, k1 = k0 + 1;
        float a = (k0 < 21) ? pe_w1[k0 * 64 + o] : 0.f;
        float c = (k1 < 21) ? pe_w1[k1 * 64 + o] : 0.f;
        s_tile[O_PE1 + i] = packh2(a, c);
    }
    for (int i = t; i < 2048; i += 256) {
        int o = i >> 5, m = i & 31;
        s_tile[O_PE2 + i] = packh2(pe_w2[(2 * m) * 64 + o], pe_w2[(2 * m + 1) * 64 + o]);
    }
    {
        int i = t;
        int o = i >> 3, m = i & 7, k0 = 2 * m, k1 = k0 + 1;
        float a = (k0 < 13) ? ee_w1[k0 * 32 + o] : 0.f;
        float c = (k1 < 13) ? ee_w1[k1 * 32 + o] : 0.f;
        s_tile[O_EE1 + i] = packh2(a, c);
    }
    {
        int i = t;
        int o = i >> 4, m = i & 15;
        s_tile[O_EE2 + i] = packh2(ee_w2[(2 * m) * 16 + o], ee_w2[(2 * m + 1) * 16 + o]);
    }
    for (int i = t; i < 4096; i += 256) {
        int o = i >> 5, m = i & 31, k0 = 2 * m, k1 = k0 + 1;
        float a = (k0 < 63) ? cb_w1[k0 * 128 + o] : 0.f;
        float c = (k1 < 63) ? cb_w1[k1 * 128 + o] : 0.f;
        s_tile[O_CB1 + i] = packh2(a, c);
    }
    for (int i = t; i < 4096; i += 256) {
        int o = i >> 6, m = i & 63;
        s_tile[O_CB2 + i] = packh2(cb_w2[(2 * m) * 64 + o], cb_w2[(2 * m + 1) * 64 + o]);
    }
    float* bias = (float*)(s_tile + O_BIAS);
    if (t < 64) bias[t] = pe_b1[t];
    if (t < 64) bias[64 + t] = pe_b2[t];
    if (t < 32) bias[128 + t] = ee_b1[t];
    if (t < 16) bias[160 + t] = ee_b2[t];
    if (t < 128) bias[176 + t] = cb_b1[t];
    if (t < 64) bias[304 + t] = cb_b2[t];
    if (t < 32) bias[368 + t] = role_emb[t];
    if (t < 32)        s_hw[t]        = packh2(th_w[2 * t], th_w[2 * t + 1]);
    else if (t < 64)  { int m = t - 32;  s_hw[32 + m]  = packh2(an_w[2 * m], an_w[2 * m + 1]); }
    else if (t < 96)  { int m = t - 64;  s_hw[64 + m]  = packh2(sh_w[4 * m], sh_w[4 * m + 2]); }
    else if (t < 128) { int m = t - 96;  s_hw[96 + m]  = packh2(sh_w[4 * m + 1], sh_w[4 * m + 3]); }
    else if (t < 160) { int m = t - 128; s_hw[128 + m] = packh2(bo_w[4 * m], bo_w[4 * m + 2]); }
    else if (t < 192) { int m = t - 160; s_hw[160 + m] = packh2(bo_w[4 * m + 1], bo_w[4 * m + 3]); }
    if (t == 0) {
        s_hb[0] = th_b[0]; s_hb[1] = an_b[0];
        s_hb[2] = sh_b[0]; s_hb[3] = sh_b[1];
        s_hb[4] = bo_b[0]; s_hb[5] = bo_b[1];
        s_hb[6] = fmaxf(__expf(logstd[0]), 0.05f);
        s_hb[7] = fmaxf(__expf(logstd[1]), 0.05f);
    }
    if (t < 32) s_h32[t] = 0u;
    __syncthreads();

    {
        const long long row = (long long)b * Sn + t;
        float lat[32];
        #pragma unroll 1
        for (int src = 0; src < 3; src++) {
            const float* xp = (src == 0) ? (tm_obs + row * 13) : (en_obs + row * 26 + (src - 1) * 13);
            unsigned int xpr[8];
            #pragma unroll
            for (int m = 0; m < 8; m++) {
                int k0 = 2 * m, k1 = k0 + 1;
                xpr[m] = packh2((k0 < 13) ? xp[k0] : 0.f, (k1 < 13) ? xp[k1] : 0.f);
            }
            unsigned int e1[16];
            #pragma unroll
            for (int o2 = 0; o2 < 16; o2++) {
                float a0 = bias[128 + 2 * o2], a1 = bias[128 + 2 * o2 + 1];
                const unsigned int* w0 = s_tile + O_EE1 + (2 * o2) * 8;
                #pragma unroll
                for (int m = 0; m < 8; m++) { a0 = dot2(xpr[m], w0[m], a0); a1 = dot2(xpr[m], w0[8 + m], a1); }
                e1[o2] = packh2(fmaxf(a0, 0.f), fmaxf(a1, 0.f));
            }
            #pragma unroll
            for (int o = 0; o < 16; o++) {
                float a0 = bias[160 + o];
                const unsigned int* w0 = s_tile + O_EE2 + o * 16;
                #pragma unroll
                for (int m = 0; m < 16; m++) a0 = dot2(e1[m], w0[m], a0);
                if (src == 0) lat[o] = a0;
                else if (src == 1) lat[16 + o] = a0;
                else lat[16 + o] = fmaxf(lat[16 + o], a0);
            }
        }
        unsigned int cpp[32];
        {
            const float* sp = self_obs + row * 15;
            const int rid = role_ids[row];
            const float* rvec = bias + 368 + rid * 16;
            #pragma unroll
            for (int m = 0; m < 32; m++) {
                int k0 = 2 * m, k1 = k0 + 1;
                float a = (k0 < 15) ? sp[k0] : (k0 < 31) ? lat[k0 - 15] : (k0 < 47) ? lat[16 + k0 - 31] : rvec[k0 - 47];
                float c = (k1 < 15) ? sp[k1] : (k1 < 31) ? lat[k1 - 15] : (k1 < 47) ? lat[16 + k1 - 31]
                                                                       : (k1 < 63) ? rvec[k1 - 47] : 0.f;
                cpp[m] = packh2(a, c);
            }
        }
        unsigned int c1[64];
        #pragma unroll
        for (int o2 = 0; o2 < 64; o2++) {
            float a0 = bias[176 + 2 * o2], a1 = bias[176 + 2 * o2 + 1];
            const unsigned int* w0 = s_tile + O_CB1 + (2 * o2) * 32;
            #pragma unroll
            for (int m = 0; m < 32; m++) { a0 = dot2(cpp[m], w0[m], a0); a1 = dot2(cpp[m], w0[32 + m], a1); }
            c1[o2] = packh2(fmaxf(a0, 0.f), fmaxf(a1, 0.f));
        }
        unsigned int resc[32];
        #pragma unroll
        for (int o2 = 0; o2 < 32; o2++) {
            float a0 = bias[304 + 2 * o2], a1 = bias[304 + 2 * o2 + 1];
            const unsigned int* w0 = s_tile + O_CB2 + (2 * o2) * 64;
            #pragma unroll
            for (int m = 0; m < 64; m++) { a0 = dot2(c1[m], w0[m], a0); a1 = dot2(c1[m], w0[64 + m], a1); }
            resc[o2] = packh2(fmaxf(a0, 0.f), fmaxf(a1, 0.f));
        }
        unsigned int inp[12];
        {
            const float* sp = self_obs + row * 15;
            const float* cp = cp_obs + row * 6;
            #pragma unroll
            for (int m = 0; m < 12; m++) {
                int k0 = 2 * m, k1 = k0 + 1;
                float a = (k0 < 15) ? sp[k0] : ((k0 < 21) ? cp[k0 - 15] : 0.f);
                float c = (k1 < 15) ? sp[k1] : ((k1 < 21) ? cp[k1 - 15] : 0.f);
                inp[m] = packh2(a, c);
            }
        }
        unsigned int r1p[32];
        #pragma unroll
        for (int o2 = 0; o2 < 32; o2++) {
            float a0 = bias[2 * o2], a1 = bias[2 * o2 + 1];
            const unsigned int* w0 = s_tile + O_PE1 + (2 * o2) * 12;
            #pragma unroll
            for (int m = 0; m < 12; m++) { a0 = dot2(inp[m], w0[m], a0); a1 = dot2(inp[m], w0[12 + m], a1); }
            r1p[o2] = packh2(fmaxf(a0, 0.f), fmaxf(a1, 0.f));
        }
        unsigned int resp[32];
        #pragma unroll
        for (int o2 = 0; o2 < 32; o2++) {
            float a0 = bias[64 + 2 * o2], a1 = bias[64 + 2 * o2 + 1];
            const unsigned int* w0 = s_tile + O_PE2 + (2 * o2) * 32;
            #pragma unroll
            for (int m = 0; m < 32; m++) { a0 = dot2(r1p[m], w0[m], a0); a1 = dot2(r1p[m], w0[32 + m], a1); }
            resp[o2] = packh2(fmaxf(a0, 0.f), fmaxf(a1, 0.f));
        }
        __syncthreads();
        uint4* rt4 = reinterpret_cast<uint4*>(s_tile + t * 64);
        #pragma unroll
        for (int q = 0; q < 8; q++)
            rt4[q] = make_uint4(resp[4 * q], resp[4 * q + 1], resp[4 * q + 2], resp[4 * q + 3]);
        #pragma unroll
        for (int q = 0; q < 8; q++)
            rt4[8 + q] = make_uint4(resc[4 * q], resc[4 * q + 1], resc[4 * q + 2], resc[4 * q + 3]);
    }

    unsigned int wih[64], whh[32];
    #pragma unroll
    for (int m = 0; m < 64; m++) wih[m] = packh2(ih_w[(2 * m) * 256 + t], ih_w[(2 * m + 1) * 256 + t]);
    #pragma unroll
    for (int m = 0; m < 32; m++) whh[m] = packh2(hh_w[(2 * m) * 256 + t], hh_w[(2 * m + 1) * 256 + t]);
    const float bias_t = ih_b[t] + hh_b[t];
    __syncthreads();

    const int grp = t >> 6;
    const int u = t & 63;
    float c = 0.f, h = 0.f, i_act = 0.f;
    #pragma unroll 1
    for (int s = 0; s < Sn; s++) {
        float acc = bias_t;
        const uint4* rq = reinterpret_cast<const uint4*>(s_tile + s * 64);
        #pragma unroll
        for (int q = 0; q < 16; q++) {
            uint4 rv = rq[q];
            acc = dot2(rv.x, wih[4 * q + 0], acc);
            acc = dot2(rv.y, wih[4 * q + 1], acc);
            acc = dot2(rv.z, wih[4 * q + 2], acc);
            acc = dot2(rv.w, wih[4 * q + 3], acc);
        }
        const uint4* hq = reinterpret_cast<const uint4*>(s_h32);
        #pragma unroll
        for (int q = 0; q < 8; q++) {
            uint4 hvv = hq[q];
            acc = dot2(hvv.x, whh[4 * q + 0], acc);
            acc = dot2(hvv.y, whh[4 * q + 1], acc);
            acc = dot2(hvv.z, whh[4 * q + 2], acc);
            acc = dot2(hvv.w, whh[4 * q + 3], acc);
        }
        float act = (grp == 2) ? tanhf_(acc) : sigmoidf_(acc);
        if (grp == 0) i_act = act; else s_g[t - 64] = act;
        __syncthreads();
        if (t < 64) {
            float f_ = s_g[u], g_ = s_g[64 + u], o_ = s_g[128 + u];
            c = f_ * c + i_act * g_;
            h = o_ * tanhf_(c);
            float hnext = __shfl_down(h, 1);
            if ((u & 1) == 0) {
                unsigned int hp = packh2(h, hnext);
                s_h32[u >> 1] = hp;
                s_tile[s * 64 + (((u >> 1) + s) & 31)] = hp;
            }
        }
        __syncthreads();
    }
    {
        const int w = t >> 6, lq = t & 63;
        const int m0 = (lq & 7) * 4;
        const int j0 = lq & 7;
        #pragma unroll 1
        for (int p = 0; p < 8; p++) {
            int s = w * 64 + p * 8 + (lq >> 3);
            float ath = 0.f, aan = 0.f, as0 = 0.f, as1 = 0.f, ab0 = 0.f, ab1 = 0.f;
            #pragma unroll
            for (int j = 0; j < 4; j++) {
                int m = m0 + j;
                unsigned int hvv = s_tile[s * 64 + ((m + s) & 31)];
                ath = dot2(hvv, s_hw[m], ath);
                aan = dot2(hvv, s_hw[32 + m], aan);
                as0 = dot2(hvv, s_hw[64 + m], as0);
                as1 = dot2(hvv, s_hw[96 + m], as1);
                ab0 = dot2(hvv, s_hw[128 + m], ab0);
                ab1 = dot2(hvv, s_hw[160 + m], ab1);
            }
            #pragma unroll
            for (int d = 1; d < 8; d <<= 1) {
                ath += __shfl_xor(ath, d); aan += __shfl_xor(aan, d);
                as0 += __shfl_xor(as0, d); as1 += __shfl_xor(as1, d);
                ab0 += __shfl_xor(ab0, d); ab1 += __shfl_xor(ab1, d);
            }
            long long row = (long long)b * Sn + s;
            if (j0 == 0)      out[row] = sigmoidf_(ath + s_hb[0]);
            else if (j0 == 1) out[BSn + row] = tanhf_(aan + s_hb[1]);
            else if (j0 == 2) out[2 * BSn + 2 * row] = s_hb[6];
            else if (j0 == 3) out[2 * BSn + 2 * row + 1] = s_hb[7];
            else if (j0 == 4) out[4 * BSn + 2 * row] = as0 + s_hb[2];
            else if (j0 == 5) out[4 * BSn + 2 * row + 1] = as1 + s_hb[3];
            else if (j0 == 6) out[6 * BSn + 2 * row] = ab0 + s_hb[4];
            else              out[6 * BSn + 2 * row + 1] = ab1 + s_hb[5];
        }
    }
    if (t < 64) {
        float* hn = out + 8 * BSn;
        float* cn = hn + (long long)Bn * 64;
        hn[(long long)b * 64 + u] = h;
        cn[(long long)b * 64 + u] = c;
    }
}

// ================= host =================
extern "C" void kernel_launch(void* const* d_in, const int* in_sizes, int n_in,
                              void* d_out, int out_size, void* d_ws, size_t ws_size,
                              hipStream_t stream)
{
    (void)in_sizes; (void)n_in; (void)out_size;
    float* out = (float*)d_out;
    const size_t X_BYTES = (size_t)BSn * 64 * 4;  // 134 MB (f16 pairs as u32)
    const size_t H_BYTES = (size_t)BSn * 64 * 2;  // 67 MB hseq f16

    if (d_ws != nullptr && ws_size >= X_BYTES + H_BYTES) {
        unsigned int* Xg = (unsigned int*)d_ws;
        unsigned short* hseq = (unsigned short*)((char*)d_ws + X_BYTES);
        k1_encode<<<(int)(BSn / 64), 256, 0, stream>>>(
            (const float*)d_in[0], (const float*)d_in[1], (const float*)d_in[2],
            (const float*)d_in[3], (const int*)d_in[4],
            (const float*)d_in[5], (const float*)d_in[6], (const float*)d_in[7], (const float*)d_in[8],
            (const float*)d_in[9],
            (const float*)d_in[10], (const float*)d_in[11], (const float*)d_in[12], (const float*)d_in[13],
            (const float*)d_in[14], (const float*)d_in[15], (const float*)d_in[16], (const float*)d_in[17],
            Xg);
        k2_lstm<<<Bn / 8, 512, 0, stream>>>(
            (const float*)d_in[18], (const float*)d_in[19], (const float*)d_in[20], (const float*)d_in[21],
            Xg, hseq, out);
        k4_heads<<<(int)(BSn / 64), 256, 0, stream>>>(
            hseq,
            (const float*)d_in[22], (const float*)d_in[23], (const float*)d_in[24], (const float*)d_in[25],
            (const float*)d_in[26], (const float*)d_in[27], (const float*)d_in[28], (const float*)d_in[29],
            (const float*)d_in[30], out);
    } else {
        k_fallback<<<Bn, 256, 0, stream>>>(
            (const float*)d_in[0], (const float*)d_in[1], (const float*)d_in[2],
            (const float*)d_in[3], (const int*)d_in[4],
            (const float*)d_in[5], (const float*)d_in[6], (const float*)d_in[7], (const float*)d_in[8],
            (const float*)d_in[9],
            (const float*)d_in[10], (const float*)d_in[11], (const float*)d_in[12], (const float*)d_in[13],
            (const float*)d_in[14], (const float*)d_in[15], (const float*)d_in[16], (const float*)d_in[17],
            (const float*)d_in[18], (const float*)d_in[19], (const float*)d_in[20], (const float*)d_in[21],
            (const float*)d_in[22], (const float*)d_in[23], (const float*)d_in[24], (const float*)d_in[25],
            (const float*)d_in[26], (const float*)d_in[27], (const float*)d_in[28], (const float*)d_in[29],
            (const float*)d_in[30], out);
    }
}